// Round 5
// baseline (1366.634 us; speedup 1.0000x reference)
//
#include <hip/hip_runtime.h>
#include <math.h>

#define NN 100000
#define NE 1600000
#define INC 128
#define OC 64
#define ED 32

__device__ __forceinline__ float sigmoidf_(float z) {
    return 1.0f / (1.0f + __expf(-z));
}

// K0: fuse gate weights. Wf = We @ Wg_bot (32x64), hb = be @ Wg_bot (64).
extern "C" __global__ void __launch_bounds__(256)
k_wfuse(const float* __restrict__ We, const float* __restrict__ be,
        const float* __restrict__ Wg, float* __restrict__ Wf,
        float* __restrict__ hb) {
    int idx = blockIdx.x * 256 + threadIdx.x;
    if (idx < ED * OC) {
        int d = idx >> 6, j = idx & 63;
        float acc = 0.0f;
#pragma unroll
        for (int k = 0; k < OC; ++k)
            acc = fmaf(We[d * OC + k], Wg[(OC + k) * OC + j], acc);
        Wf[idx] = acc;
    } else if (idx < ED * OC + OC) {
        int j = idx - ED * OC;
        float acc = 0.0f;
#pragma unroll
        for (int k = 0; k < OC; ++k)
            acc = fmaf(be[k], Wg[(OC + k) * OC + j], acc);
        hb[j] = acc;
    }
}

// K1: y_l = x @ W_l
extern "C" __global__ void __launch_bounds__(256)
k_ylin(const float* __restrict__ x, const float* __restrict__ Wl,
       float* __restrict__ yl) {
    int i = blockIdx.x * 256 + threadIdx.x;
    if (i >= NN) return;
    float xr[INC];
    const float4* xp = reinterpret_cast<const float4*>(x + (size_t)i * INC);
#pragma unroll
    for (int k4 = 0; k4 < INC / 4; ++k4) {
        float4 v = xp[k4];
        xr[4 * k4 + 0] = v.x; xr[4 * k4 + 1] = v.y;
        xr[4 * k4 + 2] = v.z; xr[4 * k4 + 3] = v.w;
    }
    float* yp = yl + (size_t)i * OC;
#pragma unroll 1
    for (int j0 = 0; j0 < OC; j0 += 8) {
        float acc[8];
#pragma unroll
        for (int jj = 0; jj < 8; ++jj) acc[jj] = 0.0f;
#pragma unroll
        for (int k = 0; k < INC; ++k) {
            float xv = xr[k];
#pragma unroll
            for (int jj = 0; jj < 8; ++jj)
                acc[jj] = fmaf(xv, Wl[k * OC + j0 + jj], acc[jj]);
        }
#pragma unroll
        for (int jj = 0; jj < 8; ++jj) yp[j0 + jj] = acc[jj];
    }
}

// CSR build step 1: histogram of target nodes (int atomics).
extern "C" __global__ void __launch_bounds__(256)
k_hist(const int* __restrict__ colv, int* __restrict__ cnti) {
    int e = blockIdx.x * 256 + threadIdx.x;
    if (e >= NE) return;
    int cl = colv[e];
    cl = min(max(cl, 0), NN - 1);
    atomicAdd(&cnti[cl], 1);
}

// CSR build step 2a: per-block exclusive scan (1024 elems/block).
extern "C" __global__ void __launch_bounds__(1024)
k_scanA(const int* __restrict__ cnti, int* __restrict__ cur,
        int* __restrict__ bsum) {
    __shared__ int s[1024];
    int t = threadIdx.x;
    int idx = blockIdx.x * 1024 + t;
    int v = (idx < NN) ? cnti[idx] : 0;
    s[t] = v;
    __syncthreads();
#pragma unroll
    for (int off = 1; off < 1024; off <<= 1) {
        int tmp = (t >= off) ? s[t - off] : 0;
        __syncthreads();
        s[t] += tmp;
        __syncthreads();
    }
    if (idx < NN) cur[idx] = s[t] - v;  // exclusive within block
    if (t == 1023) bsum[blockIdx.x] = s[1023];
}

// CSR build step 2b: scan the 98 block sums (single block).
extern "C" __global__ void __launch_bounds__(128)
k_scanB(int* __restrict__ bsum) {
    __shared__ int s[128];
    int t = threadIdx.x;
    int v = (t < 98) ? bsum[t] : 0;
    s[t] = v;
    __syncthreads();
#pragma unroll
    for (int off = 1; off < 128; off <<= 1) {
        int tmp = (t >= off) ? s[t - off] : 0;
        __syncthreads();
        s[t] += tmp;
        __syncthreads();
    }
    if (t < 98) bsum[t] = s[t] - v;  // exclusive
}

// CSR build step 2c: add block offsets.
extern "C" __global__ void __launch_bounds__(1024)
k_scanC(int* __restrict__ cur, const int* __restrict__ bsum) {
    int idx = blockIdx.x * 1024 + threadIdx.x;
    if (idx < NN) cur[idx] += bsum[blockIdx.x];
}

// CSR build step 3: bucket edges by target; payload = (row<<32)|e so k_agg
// needs no rowv indirection and k_gate gets e directly.
// After this, cur[i] == end(i); start(i) = (i==0) ? 0 : cur[i-1].
extern "C" __global__ void __launch_bounds__(256)
k_bucket(const int* __restrict__ colv, const int* __restrict__ rowv,
         int* __restrict__ cur, unsigned long long* __restrict__ ec) {
    int e = blockIdx.x * 256 + threadIdx.x;
    if (e >= NE) return;
    int cl = colv[e];
    cl = min(max(cl, 0), NN - 1);
    int r = rowv[e];
    r = min(max(r, 0), NN - 1);
    int pos = atomicAdd(&cur[cl], 1);
    ec[pos] = ((unsigned long long)(unsigned)r << 32) | (unsigned)e;
}

// K2': mean-agg numerator, atomic-free. Wave per node, lane = channel;
// source row comes straight from the ec payload.
extern "C" __global__ void __launch_bounds__(256)
k_agg(const unsigned long long* __restrict__ ec, const int* __restrict__ cur,
      const float* __restrict__ yl, float* __restrict__ agg) {
    int i = blockIdx.x * 4 + (threadIdx.x >> 6);
    if (i >= NN) return;
    int c = threadIdx.x & 63;
    int start = (i == 0) ? 0 : cur[i - 1];
    int end = cur[i];
    float acc = 0.0f;
    int p = start;
    for (; p + 1 < end; p += 2) {
        int r0 = (int)(ec[p] >> 32);
        int r1 = (int)(ec[p + 1] >> 32);
        float v0 = yl[(size_t)r0 * OC + c];
        float v1 = yl[(size_t)r1 * OC + c];
        acc += v0;
        acc += v1;
    }
    if (p < end) {
        int r0 = (int)(ec[p] >> 32);
        acc += yl[(size_t)r0 * OC + c];
    }
    agg[(size_t)i * OC + c] = acc;
}

// K3: out_pre = agg/max(deg,1) + b_l + x @ W_r, in-place into agg.
extern "C" __global__ void __launch_bounds__(256)
k_outpre(const float* __restrict__ x, const float* __restrict__ Wr,
         const float* __restrict__ bl, const int* __restrict__ cur,
         float* __restrict__ agg) {
    int i = blockIdx.x * 256 + threadIdx.x;
    if (i >= NN) return;
    float xr[INC];
    const float4* xp = reinterpret_cast<const float4*>(x + (size_t)i * INC);
#pragma unroll
    for (int k4 = 0; k4 < INC / 4; ++k4) {
        float4 v = xp[k4];
        xr[4 * k4 + 0] = v.x; xr[4 * k4 + 1] = v.y;
        xr[4 * k4 + 2] = v.z; xr[4 * k4 + 3] = v.w;
    }
    int deg = cur[i] - ((i == 0) ? 0 : cur[i - 1]);
    float inv = 1.0f / fmaxf((float)deg, 1.0f);
    float* op = agg + (size_t)i * OC;
#pragma unroll 1
    for (int j0 = 0; j0 < OC; j0 += 8) {
        float acc[8];
#pragma unroll
        for (int jj = 0; jj < 8; ++jj)
            acc[jj] = fmaf(op[j0 + jj], inv, bl[j0 + jj]);
#pragma unroll
        for (int k = 0; k < INC; ++k) {
            float xv = xr[k];
#pragma unroll
            for (int jj = 0; jj < 8; ++jj)
                acc[jj] = fmaf(xv, Wr[k * OC + j0 + jj], acc[jj]);
        }
#pragma unroll
        for (int jj = 0; jj < 8; ++jj) op[j0 + jj] = acc[jj];
    }
}

// K3b: h[i] = out_pre[i] @ Wg_top + bg + hb
extern "C" __global__ void __launch_bounds__(256)
k_hpre(const float* __restrict__ outp, const float* __restrict__ Wg,
       const float* __restrict__ bg, const float* __restrict__ hb,
       float* __restrict__ h) {
    int i = blockIdx.x * 256 + threadIdx.x;
    if (i >= NN) return;
    float o[OC];
    const float4* op4 = reinterpret_cast<const float4*>(outp + (size_t)i * OC);
#pragma unroll
    for (int k4 = 0; k4 < OC / 4; ++k4) {
        float4 v = op4[k4];
        o[4 * k4 + 0] = v.x; o[4 * k4 + 1] = v.y;
        o[4 * k4 + 2] = v.z; o[4 * k4 + 3] = v.w;
    }
    float* hp = h + (size_t)i * OC;
#pragma unroll 1
    for (int j0 = 0; j0 < OC; j0 += 8) {
        float acc[8];
#pragma unroll
        for (int jj = 0; jj < 8; ++jj) acc[jj] = bg[j0 + jj] + hb[j0 + jj];
#pragma unroll
        for (int k = 0; k < OC; ++k) {
            float ov = o[k];
#pragma unroll
            for (int jj = 0; jj < 8; ++jj)
                acc[jj] = fmaf(ov, Wg[k * OC + j0 + jj], acc[jj]);
        }
#pragma unroll
        for (int jj = 0; jj < 8; ++jj) hp[j0 + jj] = acc[jj];
    }
}

// K4: node-centric gating. One wave per node (grid-strided), lane = channel.
// Weight columns Wf[:,lane], We[:,lane] preloaded into VGPRs once per wave;
// h/out_pre/be loaded once per node. Per edge: 8 wave-uniform float4 loads
// of ein + 64 register FMAs + sigmoid, csum accumulated in-register.
// No LDS, no atomics; one coalesced write per node.
extern "C" __global__ void __launch_bounds__(256)
k_gate(const unsigned long long* __restrict__ ec, const int* __restrict__ cur,
       const float* __restrict__ eattr, const float* __restrict__ We,
       const float* __restrict__ be, const float* __restrict__ Wf,
       const float* __restrict__ h, float* __restrict__ agg) {
    int lane = threadIdx.x & 63;
    int wid = blockIdx.x * 4 + (threadIdx.x >> 6);
    const int NW = 2048 * 4;

    float wf[ED], we_[ED];
#pragma unroll
    for (int k = 0; k < ED; ++k) {
        wf[k]  = Wf[k * OC + lane];
        we_[k] = We[k * OC + lane];
    }
    float bec = be[lane];

    for (int i = wid; i < NN; i += NW) {
        int start = (i == 0) ? 0 : cur[i - 1];
        int end = cur[i];
        float hc = h[(size_t)i * OC + lane];
        float base = agg[(size_t)i * OC + lane];
        float csum = 0.0f;
        int p = start;
#pragma unroll 2
        for (; p + 1 < end; p += 2) {
            int e0 = (int)(ec[p] & 0xffffffffULL);
            int e1 = (int)(ec[p + 1] & 0xffffffffULL);
            const float4* q0 = reinterpret_cast<const float4*>(eattr + (size_t)e0 * ED);
            const float4* q1 = reinterpret_cast<const float4*>(eattr + (size_t)e1 * ED);
            float a0[ED], a1[ED];
#pragma unroll
            for (int q = 0; q < ED / 4; ++q) {
                float4 v0 = q0[q], v1 = q1[q];
                a0[4 * q + 0] = v0.x; a0[4 * q + 1] = v0.y;
                a0[4 * q + 2] = v0.z; a0[4 * q + 3] = v0.w;
                a1[4 * q + 0] = v1.x; a1[4 * q + 1] = v1.y;
                a1[4 * q + 2] = v1.z; a1[4 * q + 3] = v1.w;
            }
            float az0 = hc, ae0 = bec, az1 = hc, ae1 = bec;
#pragma unroll
            for (int k = 0; k < ED; ++k) {
                az0 = fmaf(a0[k], wf[k], az0);
                ae0 = fmaf(a0[k], we_[k], ae0);
                az1 = fmaf(a1[k], wf[k], az1);
                ae1 = fmaf(a1[k], we_[k], ae1);
            }
            csum += sigmoidf_(az0) * ae0;
            csum += sigmoidf_(az1) * ae1;
        }
        if (p < end) {
            int e0 = (int)(ec[p] & 0xffffffffULL);
            const float4* q0 = reinterpret_cast<const float4*>(eattr + (size_t)e0 * ED);
            float a0[ED];
#pragma unroll
            for (int q = 0; q < ED / 4; ++q) {
                float4 v0 = q0[q];
                a0[4 * q + 0] = v0.x; a0[4 * q + 1] = v0.y;
                a0[4 * q + 2] = v0.z; a0[4 * q + 3] = v0.w;
            }
            float az0 = hc, ae0 = bec;
#pragma unroll
            for (int k = 0; k < ED; ++k) {
                az0 = fmaf(a0[k], wf[k], az0);
                ae0 = fmaf(a0[k], we_[k], ae0);
            }
            csum += sigmoidf_(az0) * ae0;
        }
        agg[(size_t)i * OC + lane] = base + csum;
    }
}

// K5: BN batch stats.
extern "C" __global__ void __launch_bounds__(256)
k_stats(const float* __restrict__ a, float* __restrict__ stats) {
    __shared__ float ls[256], lq[256];
    int t = threadIdx.x;
    float s = 0.0f, q = 0.0f;
    for (size_t idx = (size_t)blockIdx.x * 256 + t; idx < (size_t)NN * OC;
         idx += (size_t)gridDim.x * 256) {
        float v = a[idx];
        s += v;
        q = fmaf(v, v, q);
    }
    ls[t] = s; lq[t] = q;
    __syncthreads();
    if (t < OC) {
        s = ls[t] + ls[t + 64] + ls[t + 128] + ls[t + 192];
        q = lq[t] + lq[t + 64] + lq[t + 128] + lq[t + 192];
        atomicAdd(&stats[t], s);
        atomicAdd(&stats[OC + t], q);
    }
}

// K6: BN normalize + residual(2x) + ReLU.
extern "C" __global__ void __launch_bounds__(256)
k_final(const float* __restrict__ a, const float* __restrict__ stats,
        const float* __restrict__ gamma, const float* __restrict__ beta,
        float* __restrict__ out) {
    size_t idx = (size_t)blockIdx.x * 256 + threadIdx.x;
    if (idx >= (size_t)NN * OC) return;
    int c = (int)(idx & 63);
    float mu = stats[c] * (1.0f / NN);
    float var = stats[OC + c] * (1.0f / NN) - mu * mu;
    float v = a[idx];
    float y = fmaf(gamma[c] * (v - mu), rsqrtf(var + 1e-5f), beta[c]);
    out[idx] = fmaxf(2.0f * y, 0.0f);
}

extern "C" void kernel_launch(void* const* d_in, const int* in_sizes, int n_in,
                              void* d_out, int out_size, void* d_ws, size_t ws_size,
                              hipStream_t stream) {
    const float* x     = (const float*)d_in[0];
    const int*   ei    = (const int*)d_in[1];   // (2, NE) int32
    const float* eattr = (const float*)d_in[2];
    const float* Wl    = (const float*)d_in[3];
    const float* bl    = (const float*)d_in[4];
    const float* Wr    = (const float*)d_in[5];
    const float* We    = (const float*)d_in[6];
    const float* be    = (const float*)d_in[7];
    const float* Wg    = (const float*)d_in[8];
    const float* bg    = (const float*)d_in[9];
    const float* gamma = (const float*)d_in[10];
    const float* beta  = (const float*)d_in[11];
    float* out = (float*)d_out;

    // ws (fp32 slots): agg[6.4M] | h/yl[6.4M] | ec[1.6M u64 = 3.2M] |
    //                  cur[100k i32] | bsum[128 i32] | stats[128] |
    //                  Wf[2048] | hb[64]
    float* agg = (float*)d_ws;
    float* yl  = agg + (size_t)NN * OC;      // reused as h after k_agg
    unsigned long long* ec = (unsigned long long*)(yl + (size_t)NN * OC);
    int* cur   = (int*)(ec + (size_t)NE);
    int* bsum  = cur + NN;
    float* stats = (float*)(bsum + 128);
    float* Wf  = stats + 128;
    float* hb  = Wf + ED * OC;
    float* h   = yl;

    const int* rowv = ei;
    const int* colv = ei + NE;

    hipMemsetAsync(cur, 0, NN * sizeof(int), stream);
    hipMemsetAsync(stats, 0, 2 * OC * sizeof(float), stream);

    k_wfuse<<<(ED * OC + OC + 255) / 256, 256, 0, stream>>>(We, be, Wg, Wf, hb);
    k_ylin<<<(NN + 255) / 256, 256, 0, stream>>>(x, Wl, yl);
    // CSR build (hist into cur, scanned in place)
    k_hist<<<(NE + 255) / 256, 256, 0, stream>>>(colv, cur);
    k_scanA<<<98, 1024, 0, stream>>>(cur, cur, bsum);
    k_scanB<<<1, 128, 0, stream>>>(bsum);
    k_scanC<<<98, 1024, 0, stream>>>(cur, bsum);
    k_bucket<<<(NE + 255) / 256, 256, 0, stream>>>(colv, rowv, cur, ec);
    // atomic-free mean-agg numerator
    k_agg<<<(NN + 3) / 4, 256, 0, stream>>>(ec, cur, yl, agg);
    k_outpre<<<(NN + 255) / 256, 256, 0, stream>>>(x, Wr, bl, cur, agg);
    k_hpre<<<(NN + 255) / 256, 256, 0, stream>>>(agg, Wg, bg, hb, h);
    k_gate<<<2048, 256, 0, stream>>>(ec, cur, eattr, We, be, Wf, h, agg);
    k_stats<<<2048, 256, 0, stream>>>(agg, stats);
    k_final<<<((size_t)NN * OC + 255) / 256, 256, 0, stream>>>(agg, stats, gamma, beta, out);
}

// Round 6
// 872.831 us; speedup vs baseline: 1.5657x; 1.5657x over previous
//
#include <hip/hip_runtime.h>
#include <math.h>

#define NN 100000
#define NE 1600000
#define INC 128
#define OC 64
#define ED 32

typedef __attribute__((ext_vector_type(8))) short bf16x8;
typedef __attribute__((ext_vector_type(4))) float f32x4;

__device__ __forceinline__ float sigmoidf_(float z) {
    return 1.0f / (1.0f + __expf(-z));
}

// float -> bf16 bits, round-to-nearest-even
__device__ __forceinline__ unsigned short f2bf(float x) {
    unsigned int u = __float_as_uint(x);
    unsigned int r = u + 0x7FFFu + ((u >> 16) & 1u);
    return (unsigned short)(r >> 16);
}

// K0: fused gate weights, bf16-transposed for MFMA B-operands.
// WfT[ch][k] = bf16( (We @ Wg_bot)[k][ch] ), WeT[ch][k] = bf16( We[k][ch] ),
// hb = be @ Wg_bot.
extern "C" __global__ void __launch_bounds__(256)
k_wfuse(const float* __restrict__ We, const float* __restrict__ be,
        const float* __restrict__ Wg, unsigned short* __restrict__ WfT,
        unsigned short* __restrict__ WeT, float* __restrict__ hb) {
    int idx = blockIdx.x * 256 + threadIdx.x;
    if (idx < ED * OC) {                 // WfT: idx = ch*32 + d
        int ch = idx >> 5, d = idx & 31;
        float acc = 0.0f;
#pragma unroll
        for (int k = 0; k < OC; ++k)
            acc = fmaf(We[d * OC + k], Wg[(OC + k) * OC + ch], acc);
        WfT[idx] = f2bf(acc);
    } else if (idx < 2 * ED * OC) {      // WeT
        int i2 = idx - ED * OC;
        int ch = i2 >> 5, d = i2 & 31;
        WeT[i2] = f2bf(We[d * OC + ch]);
    } else if (idx < 2 * ED * OC + OC) { // hb
        int j = idx - 2 * ED * OC;
        float acc = 0.0f;
#pragma unroll
        for (int k = 0; k < OC; ++k)
            acc = fmaf(be[k], Wg[(OC + k) * OC + j], acc);
        hb[j] = acc;
    }
}

// K1: y_l = x @ W_l
extern "C" __global__ void __launch_bounds__(256)
k_ylin(const float* __restrict__ x, const float* __restrict__ Wl,
       float* __restrict__ yl) {
    int i = blockIdx.x * 256 + threadIdx.x;
    if (i >= NN) return;
    float xr[INC];
    const float4* xp = reinterpret_cast<const float4*>(x + (size_t)i * INC);
#pragma unroll
    for (int k4 = 0; k4 < INC / 4; ++k4) {
        float4 v = xp[k4];
        xr[4 * k4 + 0] = v.x; xr[4 * k4 + 1] = v.y;
        xr[4 * k4 + 2] = v.z; xr[4 * k4 + 3] = v.w;
    }
    float* yp = yl + (size_t)i * OC;
#pragma unroll 1
    for (int j0 = 0; j0 < OC; j0 += 8) {
        float acc[8];
#pragma unroll
        for (int jj = 0; jj < 8; ++jj) acc[jj] = 0.0f;
#pragma unroll
        for (int k = 0; k < INC; ++k) {
            float xv = xr[k];
#pragma unroll
            for (int jj = 0; jj < 8; ++jj)
                acc[jj] = fmaf(xv, Wl[k * OC + j0 + jj], acc[jj]);
        }
#pragma unroll
        for (int jj = 0; jj < 8; ++jj) yp[j0 + jj] = acc[jj];
    }
}

// CSR build step 1: histogram of target nodes.
extern "C" __global__ void __launch_bounds__(256)
k_hist(const int* __restrict__ colv, int* __restrict__ cnti) {
    int e = blockIdx.x * 256 + threadIdx.x;
    if (e >= NE) return;
    int cl = colv[e];
    cl = min(max(cl, 0), NN - 1);
    atomicAdd(&cnti[cl], 1);
}

// CSR build step 2a: per-block exclusive scan (1024 elems/block).
extern "C" __global__ void __launch_bounds__(1024)
k_scanA(const int* __restrict__ cnti, int* __restrict__ cur,
        int* __restrict__ bsum) {
    __shared__ int s[1024];
    int t = threadIdx.x;
    int idx = blockIdx.x * 1024 + t;
    int v = (idx < NN) ? cnti[idx] : 0;
    s[t] = v;
    __syncthreads();
#pragma unroll
    for (int off = 1; off < 1024; off <<= 1) {
        int tmp = (t >= off) ? s[t - off] : 0;
        __syncthreads();
        s[t] += tmp;
        __syncthreads();
    }
    if (idx < NN) cur[idx] = s[t] - v;
    if (t == 1023) bsum[blockIdx.x] = s[1023];
}

// CSR build step 2b: scan the 98 block sums.
extern "C" __global__ void __launch_bounds__(128)
k_scanB(int* __restrict__ bsum) {
    __shared__ int s[128];
    int t = threadIdx.x;
    int v = (t < 98) ? bsum[t] : 0;
    s[t] = v;
    __syncthreads();
#pragma unroll
    for (int off = 1; off < 128; off <<= 1) {
        int tmp = (t >= off) ? s[t - off] : 0;
        __syncthreads();
        s[t] += tmp;
        __syncthreads();
    }
    if (t < 98) bsum[t] = s[t] - v;
}

// CSR build step 2c: add block offsets.
extern "C" __global__ void __launch_bounds__(1024)
k_scanC(int* __restrict__ cur, const int* __restrict__ bsum) {
    int idx = blockIdx.x * 1024 + threadIdx.x;
    if (idx < NN) cur[idx] += bsum[blockIdx.x];
}

// CSR build step 3: bucket edges by target.
// Payload packs row(17b) | col(17b) | e(21b) into u64 (no extra arrays).
extern "C" __global__ void __launch_bounds__(256)
k_bucket(const int* __restrict__ colv, const int* __restrict__ rowv,
         int* __restrict__ cur, unsigned long long* __restrict__ ec) {
    int e = blockIdx.x * 256 + threadIdx.x;
    if (e >= NE) return;
    int cl = colv[e];
    cl = min(max(cl, 0), NN - 1);
    int r = rowv[e];
    r = min(max(r, 0), NN - 1);
    int pos = atomicAdd(&cur[cl], 1);
    ec[pos] = ((unsigned long long)(unsigned)r << 47) |
              ((unsigned long long)(unsigned)cl << 30) | (unsigned)e;
}

// K2': mean-agg numerator, atomic-free. Wave per node, lane = channel.
extern "C" __global__ void __launch_bounds__(256)
k_agg(const unsigned long long* __restrict__ ec, const int* __restrict__ cur,
      const float* __restrict__ yl, float* __restrict__ agg) {
    int i = blockIdx.x * 4 + (threadIdx.x >> 6);
    if (i >= NN) return;
    int c = threadIdx.x & 63;
    int start = (i == 0) ? 0 : cur[i - 1];
    int end = cur[i];
    float acc = 0.0f;
    int p = start;
    for (; p + 1 < end; p += 2) {
        int r0 = (int)(ec[p] >> 47);
        int r1 = (int)(ec[p + 1] >> 47);
        float v0 = yl[(size_t)r0 * OC + c];
        float v1 = yl[(size_t)r1 * OC + c];
        acc += v0;
        acc += v1;
    }
    if (p < end) {
        int r0 = (int)(ec[p] >> 47);
        acc += yl[(size_t)r0 * OC + c];
    }
    agg[(size_t)i * OC + c] = acc;
}

// K3: out_pre = agg/max(deg,1) + b_l + x @ W_r, in-place into agg.
extern "C" __global__ void __launch_bounds__(256)
k_outpre(const float* __restrict__ x, const float* __restrict__ Wr,
         const float* __restrict__ bl, const int* __restrict__ cur,
         float* __restrict__ agg) {
    int i = blockIdx.x * 256 + threadIdx.x;
    if (i >= NN) return;
    float xr[INC];
    const float4* xp = reinterpret_cast<const float4*>(x + (size_t)i * INC);
#pragma unroll
    for (int k4 = 0; k4 < INC / 4; ++k4) {
        float4 v = xp[k4];
        xr[4 * k4 + 0] = v.x; xr[4 * k4 + 1] = v.y;
        xr[4 * k4 + 2] = v.z; xr[4 * k4 + 3] = v.w;
    }
    int deg = cur[i] - ((i == 0) ? 0 : cur[i - 1]);
    float inv = 1.0f / fmaxf((float)deg, 1.0f);
    float* op = agg + (size_t)i * OC;
#pragma unroll 1
    for (int j0 = 0; j0 < OC; j0 += 8) {
        float acc[8];
#pragma unroll
        for (int jj = 0; jj < 8; ++jj)
            acc[jj] = fmaf(op[j0 + jj], inv, bl[j0 + jj]);
#pragma unroll
        for (int k = 0; k < INC; ++k) {
            float xv = xr[k];
#pragma unroll
            for (int jj = 0; jj < 8; ++jj)
                acc[jj] = fmaf(xv, Wr[k * OC + j0 + jj], acc[jj]);
        }
#pragma unroll
        for (int jj = 0; jj < 8; ++jj) op[j0 + jj] = acc[jj];
    }
}

// K3b: h[i] = out_pre[i] @ Wg_top + bg + hb
extern "C" __global__ void __launch_bounds__(256)
k_hpre(const float* __restrict__ outp, const float* __restrict__ Wg,
       const float* __restrict__ bg, const float* __restrict__ hb,
       float* __restrict__ h) {
    int i = blockIdx.x * 256 + threadIdx.x;
    if (i >= NN) return;
    float o[OC];
    const float4* op4 = reinterpret_cast<const float4*>(outp + (size_t)i * OC);
#pragma unroll
    for (int k4 = 0; k4 < OC / 4; ++k4) {
        float4 v = op4[k4];
        o[4 * k4 + 0] = v.x; o[4 * k4 + 1] = v.y;
        o[4 * k4 + 2] = v.z; o[4 * k4 + 3] = v.w;
    }
    float* hp = h + (size_t)i * OC;
#pragma unroll 1
    for (int j0 = 0; j0 < OC; j0 += 8) {
        float acc[8];
#pragma unroll
        for (int jj = 0; jj < 8; ++jj) acc[jj] = bg[j0 + jj] + hb[j0 + jj];
#pragma unroll
        for (int k = 0; k < OC; ++k) {
            float ov = o[k];
#pragma unroll
            for (int jj = 0; jj < 8; ++jj)
                acc[jj] = fmaf(ov, Wg[k * OC + j0 + jj], acc[jj]);
        }
#pragma unroll
        for (int jj = 0; jj < 8; ++jj) hp[j0 + jj] = acc[jj];
    }
}

// K4: MFMA gating. Wave = 64 sorted edges. E-tile (bf16) staged in LDS,
// weights (bf16, transposed) live in VGPRs. Two mfma_f32_16x16x32_bf16
// GEMMs per 16x16 tile: Z = E@Wf (+h[col] via fp32 C-in), EA = E@We (+be).
// contrib = sigmoid(Z)*EA; register-level segmented scatter over the 4
// consecutive sorted edges each lane owns -> coalesced 64B atomics.
extern "C" __global__ void __launch_bounds__(256)
k_gate(const unsigned long long* __restrict__ ec, const float* __restrict__ eattr,
       const unsigned short* __restrict__ WfT, const unsigned short* __restrict__ WeT,
       const float* __restrict__ be, const float* __restrict__ h,
       float* __restrict__ agg) {
    __shared__ unsigned int etile[4][64][20];  // 80B rows: <=2-way banks, 16B aligned
    __shared__ int clsh[4][64];
    int lane = threadIdx.x & 63;
    int w = threadIdx.x >> 6;
    int tb = (blockIdx.x * 4 + w) * 64;  // tile base position (NE % 256 == 0)

    unsigned long long ev = ec[tb + lane];
    int e = (int)(ev & 0x3FFFFFFFULL);
    int cl = (int)((ev >> 30) & 0x1FFFFULL);
    clsh[w][lane] = cl;

    // stage this edge's eattr row as bf16 into LDS
    const float4* ep = reinterpret_cast<const float4*>(eattr + (size_t)e * ED);
#pragma unroll
    for (int q2 = 0; q2 < 4; ++q2) {
        float4 va = ep[2 * q2], vb = ep[2 * q2 + 1];
        uint4 pk;
        pk.x = (unsigned)f2bf(va.x) | ((unsigned)f2bf(va.y) << 16);
        pk.y = (unsigned)f2bf(va.z) | ((unsigned)f2bf(va.w) << 16);
        pk.z = (unsigned)f2bf(vb.x) | ((unsigned)f2bf(vb.y) << 16);
        pk.w = (unsigned)f2bf(vb.z) | ((unsigned)f2bf(vb.w) << 16);
        *reinterpret_cast<uint4*>(&etile[w][lane][4 * q2]) = pk;
    }

    // B-fragments: col = lane&15 within each 16-col tile, k = (lane>>4)*8 + j
    int c = lane & 15, g = lane >> 4;
    bf16x8 bwf[4], bwe[4];
    float bev[4];
#pragma unroll
    for (int nt = 0; nt < 4; ++nt) {
        int ch = nt * 16 + c;
        bwf[nt] = *reinterpret_cast<const bf16x8*>(WfT + ch * ED + g * 8);
        bwe[nt] = *reinterpret_cast<const bf16x8*>(WeT + ch * ED + g * 8);
        bev[nt] = be[ch];
    }

    // wave-local LDS region: same-wave ds_write -> ds_read, no barrier needed
#pragma unroll
    for (int mt = 0; mt < 4; ++mt) {
        int arow = mt * 16 + c;  // A: row = lane&15, k-group = lane>>4
        bf16x8 afrag = *reinterpret_cast<const bf16x8*>(
            reinterpret_cast<const unsigned short*>(&etile[w][arow][0]) + g * 8);
        // the 4 sorted edges this lane's C-rows cover: row = g*4 + r
        int cl0 = clsh[w][mt * 16 + g * 4 + 0];
        int cl1 = clsh[w][mt * 16 + g * 4 + 1];
        int cl2 = clsh[w][mt * 16 + g * 4 + 2];
        int cl3 = clsh[w][mt * 16 + g * 4 + 3];
#pragma unroll
        for (int nt = 0; nt < 4; ++nt) {
            int ch = nt * 16 + c;
            f32x4 cz, ce;
            cz[0] = h[(size_t)cl0 * OC + ch];
            cz[1] = h[(size_t)cl1 * OC + ch];
            cz[2] = h[(size_t)cl2 * OC + ch];
            cz[3] = h[(size_t)cl3 * OC + ch];
            ce[0] = bev[nt]; ce[1] = bev[nt]; ce[2] = bev[nt]; ce[3] = bev[nt];
            f32x4 z  = __builtin_amdgcn_mfma_f32_16x16x32_bf16(afrag, bwf[nt], cz, 0, 0, 0);
            f32x4 ea = __builtin_amdgcn_mfma_f32_16x16x32_bf16(afrag, bwe[nt], ce, 0, 0, 0);
            float c0 = sigmoidf_(z[0]) * ea[0];
            float c1 = sigmoidf_(z[1]) * ea[1];
            float c2 = sigmoidf_(z[2]) * ea[2];
            float c3 = sigmoidf_(z[3]) * ea[3];
            // register segmented scatter over sorted run
            float s = c0;
            int t = cl0;
            if (cl1 != t) { atomicAdd(&agg[(size_t)t * OC + ch], s); s = 0.0f; t = cl1; }
            s += c1;
            if (cl2 != t) { atomicAdd(&agg[(size_t)t * OC + ch], s); s = 0.0f; t = cl2; }
            s += c2;
            if (cl3 != t) { atomicAdd(&agg[(size_t)t * OC + ch], s); s = 0.0f; t = cl3; }
            s += c3;
            atomicAdd(&agg[(size_t)t * OC + ch], s);
        }
    }
}

// K5: BN batch stats.
extern "C" __global__ void __launch_bounds__(256)
k_stats(const float* __restrict__ a, float* __restrict__ stats) {
    __shared__ float ls[256], lq[256];
    int t = threadIdx.x;
    float s = 0.0f, q = 0.0f;
    for (size_t idx = (size_t)blockIdx.x * 256 + t; idx < (size_t)NN * OC;
         idx += (size_t)gridDim.x * 256) {
        float v = a[idx];
        s += v;
        q = fmaf(v, v, q);
    }
    ls[t] = s; lq[t] = q;
    __syncthreads();
    if (t < OC) {
        s = ls[t] + ls[t + 64] + ls[t + 128] + ls[t + 192];
        q = lq[t] + lq[t + 64] + lq[t + 128] + lq[t + 192];
        atomicAdd(&stats[t], s);
        atomicAdd(&stats[OC + t], q);
    }
}

// K6: BN normalize + residual(2x) + ReLU.
extern "C" __global__ void __launch_bounds__(256)
k_final(const float* __restrict__ a, const float* __restrict__ stats,
        const float* __restrict__ gamma, const float* __restrict__ beta,
        float* __restrict__ out) {
    size_t idx = (size_t)blockIdx.x * 256 + threadIdx.x;
    if (idx >= (size_t)NN * OC) return;
    int c = (int)(idx & 63);
    float mu = stats[c] * (1.0f / NN);
    float var = stats[OC + c] * (1.0f / NN) - mu * mu;
    float v = a[idx];
    float y = fmaf(gamma[c] * (v - mu), rsqrtf(var + 1e-5f), beta[c]);
    out[idx] = fmaxf(2.0f * y, 0.0f);
}

extern "C" void kernel_launch(void* const* d_in, const int* in_sizes, int n_in,
                              void* d_out, int out_size, void* d_ws, size_t ws_size,
                              hipStream_t stream) {
    const float* x     = (const float*)d_in[0];
    const int*   ei    = (const int*)d_in[1];   // (2, NE) int32
    const float* eattr = (const float*)d_in[2];
    const float* Wl    = (const float*)d_in[3];
    const float* bl    = (const float*)d_in[4];
    const float* Wr    = (const float*)d_in[5];
    const float* We    = (const float*)d_in[6];
    const float* be    = (const float*)d_in[7];
    const float* Wg    = (const float*)d_in[8];
    const float* bg    = (const float*)d_in[9];
    const float* gamma = (const float*)d_in[10];
    const float* beta  = (const float*)d_in[11];
    float* out = (float*)d_out;

    // ws (fp32 slots): agg[6.4M] | h/yl[6.4M] | ec[1.6M u64 = 3.2M] |
    //                  cur[100k i32] | bsum[128 i32] | stats[128] |
    //                  WfT[2048 u16] + WeT[2048 u16] (=1024 f32) | hb[64]
    float* agg = (float*)d_ws;
    float* yl  = agg + (size_t)NN * OC;      // reused as h after k_agg
    unsigned long long* ec = (unsigned long long*)(yl + (size_t)NN * OC);
    int* cur   = (int*)(ec + (size_t)NE);
    int* bsum  = cur + NN;
    float* stats = (float*)(bsum + 128);
    unsigned short* WfT = (unsigned short*)(stats + 128);
    unsigned short* WeT = WfT + ED * OC;
    float* hb  = (float*)(WeT + ED * OC);
    float* h   = yl;

    const int* rowv = ei;
    const int* colv = ei + NE;

    hipMemsetAsync(cur, 0, NN * sizeof(int), stream);
    hipMemsetAsync(stats, 0, 2 * OC * sizeof(float), stream);

    k_wfuse<<<(2 * ED * OC + OC + 255) / 256, 256, 0, stream>>>(We, be, Wg, WfT, WeT, hb);
    k_ylin<<<(NN + 255) / 256, 256, 0, stream>>>(x, Wl, yl);
    k_hist<<<(NE + 255) / 256, 256, 0, stream>>>(colv, cur);
    k_scanA<<<98, 1024, 0, stream>>>(cur, cur, bsum);
    k_scanB<<<1, 128, 0, stream>>>(bsum);
    k_scanC<<<98, 1024, 0, stream>>>(cur, bsum);
    k_bucket<<<(NE + 255) / 256, 256, 0, stream>>>(colv, rowv, cur, ec);
    k_agg<<<(NN + 3) / 4, 256, 0, stream>>>(ec, cur, yl, agg);
    k_outpre<<<(NN + 255) / 256, 256, 0, stream>>>(x, Wr, bl, cur, agg);
    k_hpre<<<(NN + 255) / 256, 256, 0, stream>>>(agg, Wg, bg, hb, h);
    k_gate<<<NE / 256, 256, 0, stream>>>(ec, eattr, WfT, WeT, be, h, agg);
    k_stats<<<2048, 256, 0, stream>>>(agg, stats);
    k_final<<<((size_t)NN * OC + 255) / 256, 256, 0, stream>>>(agg, stats, gamma, beta, out);
}

// Round 7
// 858.826 us; speedup vs baseline: 1.5913x; 1.0163x over previous
//
#include <hip/hip_runtime.h>
#include <math.h>

#define NN 100000
#define NE 1600000
#define INC 128
#define OC 64
#define ED 32

typedef __attribute__((ext_vector_type(8))) short bf16x8;
typedef __attribute__((ext_vector_type(4))) float f32x4;

__device__ __forceinline__ float sigmoidf_(float z) {
    return 1.0f / (1.0f + __expf(-z));
}

// float -> bf16 bits, round-to-nearest-even
__device__ __forceinline__ unsigned short f2bf(float x) {
    unsigned int u = __float_as_uint(x);
    unsigned int r = u + 0x7FFFu + ((u >> 16) & 1u);
    return (unsigned short)(r >> 16);
}

// K0: fused gate weights, bf16-transposed for MFMA operands.
// WfT[ch][k] = bf16( (We @ Wg_bot)[k][ch] ), WeT[ch][k] = bf16( We[k][ch] ),
// hb = be @ Wg_bot.
extern "C" __global__ void __launch_bounds__(256)
k_wfuse(const float* __restrict__ We, const float* __restrict__ be,
        const float* __restrict__ Wg, unsigned short* __restrict__ WfT,
        unsigned short* __restrict__ WeT, float* __restrict__ hb) {
    int idx = blockIdx.x * 256 + threadIdx.x;
    if (idx < ED * OC) {                 // WfT: idx = ch*32 + d
        int ch = idx >> 5, d = idx & 31;
        float acc = 0.0f;
#pragma unroll
        for (int k = 0; k < OC; ++k)
            acc = fmaf(We[d * OC + k], Wg[(OC + k) * OC + ch], acc);
        WfT[idx] = f2bf(acc);
    } else if (idx < 2 * ED * OC) {      // WeT
        int i2 = idx - ED * OC;
        int ch = i2 >> 5, d = i2 & 31;
        WeT[i2] = f2bf(We[d * OC + ch]);
    } else if (idx < 2 * ED * OC + OC) { // hb
        int j = idx - 2 * ED * OC;
        float acc = 0.0f;
#pragma unroll
        for (int k = 0; k < OC; ++k)
            acc = fmaf(be[k], Wg[(OC + k) * OC + j], acc);
        hb[j] = acc;
    }
}

// K1: y_l = x @ W_l
extern "C" __global__ void __launch_bounds__(256)
k_ylin(const float* __restrict__ x, const float* __restrict__ Wl,
       float* __restrict__ yl) {
    int i = blockIdx.x * 256 + threadIdx.x;
    if (i >= NN) return;
    float xr[INC];
    const float4* xp = reinterpret_cast<const float4*>(x + (size_t)i * INC);
#pragma unroll
    for (int k4 = 0; k4 < INC / 4; ++k4) {
        float4 v = xp[k4];
        xr[4 * k4 + 0] = v.x; xr[4 * k4 + 1] = v.y;
        xr[4 * k4 + 2] = v.z; xr[4 * k4 + 3] = v.w;
    }
    float* yp = yl + (size_t)i * OC;
#pragma unroll 1
    for (int j0 = 0; j0 < OC; j0 += 8) {
        float acc[8];
#pragma unroll
        for (int jj = 0; jj < 8; ++jj) acc[jj] = 0.0f;
#pragma unroll
        for (int k = 0; k < INC; ++k) {
            float xv = xr[k];
#pragma unroll
            for (int jj = 0; jj < 8; ++jj)
                acc[jj] = fmaf(xv, Wl[k * OC + j0 + jj], acc[jj]);
        }
#pragma unroll
        for (int jj = 0; jj < 8; ++jj) yp[j0 + jj] = acc[jj];
    }
}

// CSR build step 1: histogram of target nodes.
extern "C" __global__ void __launch_bounds__(256)
k_hist(const int* __restrict__ colv, int* __restrict__ cnti) {
    int e = blockIdx.x * 256 + threadIdx.x;
    if (e >= NE) return;
    int cl = colv[e];
    cl = min(max(cl, 0), NN - 1);
    atomicAdd(&cnti[cl], 1);
}

// CSR build step 2a: per-block exclusive scan (1024 elems/block).
extern "C" __global__ void __launch_bounds__(1024)
k_scanA(const int* __restrict__ cnti, int* __restrict__ cur,
        int* __restrict__ bsum) {
    __shared__ int s[1024];
    int t = threadIdx.x;
    int idx = blockIdx.x * 1024 + t;
    int v = (idx < NN) ? cnti[idx] : 0;
    s[t] = v;
    __syncthreads();
#pragma unroll
    for (int off = 1; off < 1024; off <<= 1) {
        int tmp = (t >= off) ? s[t - off] : 0;
        __syncthreads();
        s[t] += tmp;
        __syncthreads();
    }
    if (idx < NN) cur[idx] = s[t] - v;
    if (t == 1023) bsum[blockIdx.x] = s[1023];
}

// CSR build step 2b: scan the 98 block sums.
extern "C" __global__ void __launch_bounds__(128)
k_scanB(int* __restrict__ bsum) {
    __shared__ int s[128];
    int t = threadIdx.x;
    int v = (t < 98) ? bsum[t] : 0;
    s[t] = v;
    __syncthreads();
#pragma unroll
    for (int off = 1; off < 128; off <<= 1) {
        int tmp = (t >= off) ? s[t - off] : 0;
        __syncthreads();
        s[t] += tmp;
        __syncthreads();
    }
    if (t < 98) bsum[t] = s[t] - v;
}

// CSR build step 2c: add block offsets.
extern "C" __global__ void __launch_bounds__(1024)
k_scanC(int* __restrict__ cur, const int* __restrict__ bsum) {
    int idx = blockIdx.x * 1024 + threadIdx.x;
    if (idx < NN) cur[idx] += bsum[blockIdx.x];
}

// CSR build step 3: bucket edges by target.
// Payload packs row(17b) | col(17b) | e(21b) into u64.
extern "C" __global__ void __launch_bounds__(256)
k_bucket(const int* __restrict__ colv, const int* __restrict__ rowv,
         int* __restrict__ cur, unsigned long long* __restrict__ ec) {
    int e = blockIdx.x * 256 + threadIdx.x;
    if (e >= NE) return;
    int cl = colv[e];
    cl = min(max(cl, 0), NN - 1);
    int r = rowv[e];
    r = min(max(r, 0), NN - 1);
    int pos = atomicAdd(&cur[cl], 1);
    ec[pos] = ((unsigned long long)(unsigned)r << 47) |
              ((unsigned long long)(unsigned)cl << 30) | (unsigned)e;
}

// K2': mean-agg numerator, atomic-free. Wave per node, lane = channel.
extern "C" __global__ void __launch_bounds__(256)
k_agg(const unsigned long long* __restrict__ ec, const int* __restrict__ cur,
      const float* __restrict__ yl, float* __restrict__ agg) {
    int i = blockIdx.x * 4 + (threadIdx.x >> 6);
    if (i >= NN) return;
    int c = threadIdx.x & 63;
    int start = (i == 0) ? 0 : cur[i - 1];
    int end = cur[i];
    float acc = 0.0f;
    int p = start;
    for (; p + 1 < end; p += 2) {
        int r0 = (int)(ec[p] >> 47);
        int r1 = (int)(ec[p + 1] >> 47);
        float v0 = yl[(size_t)r0 * OC + c];
        float v1 = yl[(size_t)r1 * OC + c];
        acc += v0;
        acc += v1;
    }
    if (p < end) {
        int r0 = (int)(ec[p] >> 47);
        acc += yl[(size_t)r0 * OC + c];
    }
    agg[(size_t)i * OC + c] = acc;
}

// K3: out_pre = agg/max(deg,1) + b_l + x @ W_r, in-place into agg.
extern "C" __global__ void __launch_bounds__(256)
k_outpre(const float* __restrict__ x, const float* __restrict__ Wr,
         const float* __restrict__ bl, const int* __restrict__ cur,
         float* __restrict__ agg) {
    int i = blockIdx.x * 256 + threadIdx.x;
    if (i >= NN) return;
    float xr[INC];
    const float4* xp = reinterpret_cast<const float4*>(x + (size_t)i * INC);
#pragma unroll
    for (int k4 = 0; k4 < INC / 4; ++k4) {
        float4 v = xp[k4];
        xr[4 * k4 + 0] = v.x; xr[4 * k4 + 1] = v.y;
        xr[4 * k4 + 2] = v.z; xr[4 * k4 + 3] = v.w;
    }
    int deg = cur[i] - ((i == 0) ? 0 : cur[i - 1]);
    float inv = 1.0f / fmaxf((float)deg, 1.0f);
    float* op = agg + (size_t)i * OC;
#pragma unroll 1
    for (int j0 = 0; j0 < OC; j0 += 8) {
        float acc[8];
#pragma unroll
        for (int jj = 0; jj < 8; ++jj)
            acc[jj] = fmaf(op[j0 + jj], inv, bl[j0 + jj]);
#pragma unroll
        for (int k = 0; k < INC; ++k) {
            float xv = xr[k];
#pragma unroll
            for (int jj = 0; jj < 8; ++jj)
                acc[jj] = fmaf(xv, Wr[k * OC + j0 + jj], acc[jj]);
        }
#pragma unroll
        for (int jj = 0; jj < 8; ++jj) op[j0 + jj] = acc[jj];
    }
}

// K3b: h[i] = out_pre[i] @ Wg_top + bg + hb
extern "C" __global__ void __launch_bounds__(256)
k_hpre(const float* __restrict__ outp, const float* __restrict__ Wg,
       const float* __restrict__ bg, const float* __restrict__ hb,
       float* __restrict__ h) {
    int i = blockIdx.x * 256 + threadIdx.x;
    if (i >= NN) return;
    float o[OC];
    const float4* op4 = reinterpret_cast<const float4*>(outp + (size_t)i * OC);
#pragma unroll
    for (int k4 = 0; k4 < OC / 4; ++k4) {
        float4 v = op4[k4];
        o[4 * k4 + 0] = v.x; o[4 * k4 + 1] = v.y;
        o[4 * k4 + 2] = v.z; o[4 * k4 + 3] = v.w;
    }
    float* hp = h + (size_t)i * OC;
#pragma unroll 1
    for (int j0 = 0; j0 < OC; j0 += 8) {
        float acc[8];
#pragma unroll
        for (int jj = 0; jj < 8; ++jj) acc[jj] = bg[j0 + jj] + hb[j0 + jj];
#pragma unroll
        for (int k = 0; k < OC; ++k) {
            float ov = o[k];
#pragma unroll
            for (int jj = 0; jj < 8; ++jj)
                acc[jj] = fmaf(ov, Wg[k * OC + j0 + jj], acc[jj]);
        }
#pragma unroll
        for (int jj = 0; jj < 8; ++jj) hp[j0 + jj] = acc[jj];
    }
}

// K4: MFMA gating, zero-LDS. Wave = 64 sorted edges. A-fragments (eattr
// rows, bf16) loaded DIRECTLY from global: edge id for C/A-row via __shfl;
// lanes of a 16-group fetch disjoint 32B segments of the same rows (full
// cache lines). Weights live in VGPRs. launch_bounds(256,4) gives the
// compiler ~128 VGPRs to hoist h-gathers/eattr loads and hide latency.
extern "C" __global__ void __launch_bounds__(256, 4)
k_gate(const unsigned long long* __restrict__ ec, const float* __restrict__ eattr,
       const unsigned short* __restrict__ WfT, const unsigned short* __restrict__ WeT,
       const float* __restrict__ be, const float* __restrict__ h,
       float* __restrict__ agg) {
    int lane = threadIdx.x & 63;
    int w = threadIdx.x >> 6;
    int tb = (blockIdx.x * 4 + w) * 64;  // tile base (NE % 256 == 0)

    unsigned long long ev = ec[tb + lane];
    int e = (int)(ev & 0x3FFFFFFFULL);
    int cl = (int)((ev >> 30) & 0x1FFFFULL);

    int c = lane & 15, g = lane >> 4;

    // weight fragments (B-operand): col = lane&15, k = (lane>>4)*8 + j
    bf16x8 bwf[4], bwe[4];
    float bev[4];
#pragma unroll
    for (int nt = 0; nt < 4; ++nt) {
        int ch = nt * 16 + c;
        bwf[nt] = *reinterpret_cast<const bf16x8*>(WfT + ch * ED + g * 8);
        bwe[nt] = *reinterpret_cast<const bf16x8*>(WeT + ch * ED + g * 8);
        bev[nt] = be[ch];
    }

    // A-fragments: row = lane&15 within each 16-row tile, k-group = lane>>4
    int erow[4];
#pragma unroll
    for (int mt = 0; mt < 4; ++mt) erow[mt] = __shfl(e, mt * 16 + c);

    bf16x8 afr[4];
#pragma unroll
    for (int mt = 0; mt < 4; ++mt) {
        const float4* q = reinterpret_cast<const float4*>(
            eattr + (size_t)erow[mt] * ED + g * 8);
        float4 lo = q[0], hi = q[1];
        union { bf16x8 v; unsigned short u[8]; } pk;
        pk.u[0] = f2bf(lo.x); pk.u[1] = f2bf(lo.y);
        pk.u[2] = f2bf(lo.z); pk.u[3] = f2bf(lo.w);
        pk.u[4] = f2bf(hi.x); pk.u[5] = f2bf(hi.y);
        pk.u[6] = f2bf(hi.z); pk.u[7] = f2bf(hi.w);
        afr[mt] = pk.v;
    }

#pragma unroll
    for (int mt = 0; mt < 4; ++mt) {
        // the 4 sorted edges this lane's C-rows cover: row = g*4 + r
        int r0 = mt * 16 + g * 4;
        int cl0 = __shfl(cl, r0 + 0);
        int cl1 = __shfl(cl, r0 + 1);
        int cl2 = __shfl(cl, r0 + 2);
        int cl3 = __shfl(cl, r0 + 3);
        const float* h0 = h + (size_t)cl0 * OC;
        const float* h1 = h + (size_t)cl1 * OC;
        const float* h2 = h + (size_t)cl2 * OC;
        const float* h3 = h + (size_t)cl3 * OC;
#pragma unroll
        for (int nt = 0; nt < 4; ++nt) {
            int ch = nt * 16 + c;
            f32x4 cz, ce;
            cz[0] = h0[ch]; cz[1] = h1[ch]; cz[2] = h2[ch]; cz[3] = h3[ch];
            ce[0] = bev[nt]; ce[1] = bev[nt]; ce[2] = bev[nt]; ce[3] = bev[nt];
            f32x4 z  = __builtin_amdgcn_mfma_f32_16x16x32_bf16(afr[mt], bwf[nt], cz, 0, 0, 0);
            f32x4 ea = __builtin_amdgcn_mfma_f32_16x16x32_bf16(afr[mt], bwe[nt], ce, 0, 0, 0);
            float c0 = sigmoidf_(z[0]) * ea[0];
            float c1 = sigmoidf_(z[1]) * ea[1];
            float c2 = sigmoidf_(z[2]) * ea[2];
            float c3 = sigmoidf_(z[3]) * ea[3];
            // register segmented scatter over the sorted run
            float s = c0;
            int t = cl0;
            if (cl1 != t) { atomicAdd(&agg[(size_t)t * OC + ch], s); s = 0.0f; t = cl1; }
            s += c1;
            if (cl2 != t) { atomicAdd(&agg[(size_t)t * OC + ch], s); s = 0.0f; t = cl2; }
            s += c2;
            if (cl3 != t) { atomicAdd(&agg[(size_t)t * OC + ch], s); s = 0.0f; t = cl3; }
            s += c3;
            atomicAdd(&agg[(size_t)t * OC + ch], s);
        }
    }
}

// K5: BN batch stats.
extern "C" __global__ void __launch_bounds__(256)
k_stats(const float* __restrict__ a, float* __restrict__ stats) {
    __shared__ float ls[256], lq[256];
    int t = threadIdx.x;
    float s = 0.0f, q = 0.0f;
    for (size_t idx = (size_t)blockIdx.x * 256 + t; idx < (size_t)NN * OC;
         idx += (size_t)gridDim.x * 256) {
        float v = a[idx];
        s += v;
        q = fmaf(v, v, q);
    }
    ls[t] = s; lq[t] = q;
    __syncthreads();
    if (t < OC) {
        s = ls[t] + ls[t + 64] + ls[t + 128] + ls[t + 192];
        q = lq[t] + lq[t + 64] + lq[t + 128] + lq[t + 192];
        atomicAdd(&stats[t], s);
        atomicAdd(&stats[OC + t], q);
    }
}

// K6: BN normalize + residual(2x) + ReLU.
extern "C" __global__ void __launch_bounds__(256)
k_final(const float* __restrict__ a, const float* __restrict__ stats,
        const float* __restrict__ gamma, const float* __restrict__ beta,
        float* __restrict__ out) {
    size_t idx = (size_t)blockIdx.x * 256 + threadIdx.x;
    if (idx >= (size_t)NN * OC) return;
    int c = (int)(idx & 63);
    float mu = stats[c] * (1.0f / NN);
    float var = stats[OC + c] * (1.0f / NN) - mu * mu;
    float v = a[idx];
    float y = fmaf(gamma[c] * (v - mu), rsqrtf(var + 1e-5f), beta[c]);
    out[idx] = fmaxf(2.0f * y, 0.0f);
}

extern "C" void kernel_launch(void* const* d_in, const int* in_sizes, int n_in,
                              void* d_out, int out_size, void* d_ws, size_t ws_size,
                              hipStream_t stream) {
    const float* x     = (const float*)d_in[0];
    const int*   ei    = (const int*)d_in[1];   // (2, NE) int32
    const float* eattr = (const float*)d_in[2];
    const float* Wl    = (const float*)d_in[3];
    const float* bl    = (const float*)d_in[4];
    const float* Wr    = (const float*)d_in[5];
    const float* We    = (const float*)d_in[6];
    const float* be    = (const float*)d_in[7];
    const float* Wg    = (const float*)d_in[8];
    const float* bg    = (const float*)d_in[9];
    const float* gamma = (const float*)d_in[10];
    const float* beta  = (const float*)d_in[11];
    float* out = (float*)d_out;

    // ws (fp32 slots): agg[6.4M] | h/yl[6.4M] | ec[1.6M u64 = 3.2M] |
    //                  cur[100k i32] | bsum[128 i32] | stats[128] |
    //                  WfT[2048 u16] + WeT[2048 u16] | hb[64]
    float* agg = (float*)d_ws;
    float* yl  = agg + (size_t)NN * OC;      // reused as h after k_agg
    unsigned long long* ec = (unsigned long long*)(yl + (size_t)NN * OC);
    int* cur   = (int*)(ec + (size_t)NE);
    int* bsum  = cur + NN;
    float* stats = (float*)(bsum + 128);
    unsigned short* WfT = (unsigned short*)(stats + 128);
    unsigned short* WeT = WfT + ED * OC;
    float* hb  = (float*)(WeT + ED * OC);
    float* h   = yl;

    const int* rowv = ei;
    const int* colv = ei + NE;

    hipMemsetAsync(cur, 0, NN * sizeof(int), stream);
    hipMemsetAsync(stats, 0, 2 * OC * sizeof(float), stream);

    k_wfuse<<<(2 * ED * OC + OC + 255) / 256, 256, 0, stream>>>(We, be, Wg, WfT, WeT, hb);
    k_ylin<<<(NN + 255) / 256, 256, 0, stream>>>(x, Wl, yl);
    k_hist<<<(NE + 255) / 256, 256, 0, stream>>>(colv, cur);
    k_scanA<<<98, 1024, 0, stream>>>(cur, cur, bsum);
    k_scanB<<<1, 128, 0, stream>>>(bsum);
    k_scanC<<<98, 1024, 0, stream>>>(cur, bsum);
    k_bucket<<<(NE + 255) / 256, 256, 0, stream>>>(colv, rowv, cur, ec);
    k_agg<<<(NN + 3) / 4, 256, 0, stream>>>(ec, cur, yl, agg);
    k_outpre<<<(NN + 255) / 256, 256, 0, stream>>>(x, Wr, bl, cur, agg);
    k_hpre<<<(NN + 255) / 256, 256, 0, stream>>>(agg, Wg, bg, hb, h);
    k_gate<<<NE / 256, 256, 0, stream>>>(ec, eattr, WfT, WeT, be, h, agg);
    k_stats<<<2048, 256, 0, stream>>>(agg, stats);
    k_final<<<((size_t)NN * OC + 255) / 256, 256, 0, stream>>>(agg, stats, gamma, beta, out);
}

// Round 8
// 694.741 us; speedup vs baseline: 1.9671x; 1.2362x over previous
//
#include <hip/hip_runtime.h>
#include <math.h>

#define NN 100000
#define NE 1600000
#define INC 128
#define OC 64
#define ED 32

typedef __attribute__((ext_vector_type(8))) short bf16x8;
typedef __attribute__((ext_vector_type(4))) float f32x4;

__device__ __forceinline__ float sigmoidf_(float z) {
    return __builtin_amdgcn_rcpf(1.0f + __expf(-z));
}

// float -> bf16 bits, round-to-nearest-even
__device__ __forceinline__ unsigned short f2bf(float x) {
    unsigned int u = __float_as_uint(x);
    unsigned int r = u + 0x7FFFu + ((u >> 16) & 1u);
    return (unsigned short)(r >> 16);
}
__device__ __forceinline__ float bf2f(unsigned short u) {
    return __uint_as_float((unsigned int)u << 16);
}

// K0: weight prep.
//  WfT[ch][k] = bf16((We@Wg_bot)[k][ch])  (2048)
//  WeT[ch][k] = bf16(We[k][ch])           (2048)
//  hb = be @ Wg_bot                       (64)
//  WlrT[ch][k] = bf16([Wl|Wr][k][ch]), ch in [0,128)  (16384)
extern "C" __global__ void __launch_bounds__(256)
k_wfuse(const float* __restrict__ We, const float* __restrict__ be,
        const float* __restrict__ Wg, const float* __restrict__ Wl,
        const float* __restrict__ Wr, unsigned short* __restrict__ WfT,
        unsigned short* __restrict__ WeT, float* __restrict__ hb,
        unsigned short* __restrict__ WlrT) {
    int idx = blockIdx.x * 256 + threadIdx.x;
    if (idx < ED * OC) {                 // WfT: idx = ch*32 + d
        int ch = idx >> 5, d = idx & 31;
        float acc = 0.0f;
#pragma unroll
        for (int k = 0; k < OC; ++k)
            acc = fmaf(We[d * OC + k], Wg[(OC + k) * OC + ch], acc);
        WfT[idx] = f2bf(acc);
    } else if (idx < 2 * ED * OC) {      // WeT
        int i2 = idx - ED * OC;
        int ch = i2 >> 5, d = i2 & 31;
        WeT[i2] = f2bf(We[d * OC + ch]);
    } else if (idx < 2 * ED * OC + OC) { // hb
        int j = idx - 2 * ED * OC;
        float acc = 0.0f;
#pragma unroll
        for (int k = 0; k < OC; ++k)
            acc = fmaf(be[k], Wg[(OC + k) * OC + j], acc);
        hb[j] = acc;
    } else if (idx < 2 * ED * OC + OC + 2 * INC * OC) {  // WlrT
        int i3 = idx - (2 * ED * OC + OC);
        int ch = i3 >> 7, k = i3 & 127;
        float v = (ch < OC) ? Wl[k * OC + ch] : Wr[k * OC + (ch - OC)];
        WlrT[i3] = f2bf(v);
    }
}

// K1: MFMA GEMM  [yl | xwr](bf16) = x @ [Wl | Wr].
// Block = 64 rows; x tile staged in LDS as bf16; wave w owns 32 output cols.
extern "C" __global__ void __launch_bounds__(256)
k_xw(const float* __restrict__ x, const unsigned short* __restrict__ WlrT,
     unsigned short* __restrict__ ybf, unsigned short* __restrict__ xwrbf) {
    __shared__ unsigned short xs[64][136];  // +8 pad: 2-way banks on b128 reads
    int t = threadIdx.x;
    int base = blockIdx.x * 64;
    {
        int rr = t >> 2, cc = (t & 3) * 32;
        int grow = base + rr;
        if (grow < NN) {
            const float4* xp = reinterpret_cast<const float4*>(
                x + (size_t)grow * INC + cc);
#pragma unroll
            for (int q = 0; q < 8; ++q) {
                float4 v = xp[q];
                uint2 uv;
                uv.x = (unsigned)f2bf(v.x) | ((unsigned)f2bf(v.y) << 16);
                uv.y = (unsigned)f2bf(v.z) | ((unsigned)f2bf(v.w) << 16);
                *reinterpret_cast<uint2*>(&xs[rr][cc + q * 4]) = uv;
            }
        } else {
#pragma unroll
            for (int q = 0; q < 8; ++q) {
                uint2 uv; uv.x = 0u; uv.y = 0u;
                *reinterpret_cast<uint2*>(&xs[rr][cc + q * 4]) = uv;
            }
        }
    }
    __syncthreads();

    int lane = t & 63, w = t >> 6;
    int c = lane & 15, g = lane >> 4;

    // B-frags: wave's 2 col-tiles x 4 k-steps
    bf16x8 bw0[4], bw1[4];
#pragma unroll
    for (int kk = 0; kk < 4; ++kk) {
        bw0[kk] = *reinterpret_cast<const bf16x8*>(
            WlrT + (w * 32 + 0 * 16 + c) * INC + kk * 32 + g * 8);
        bw1[kk] = *reinterpret_cast<const bf16x8*>(
            WlrT + (w * 32 + 1 * 16 + c) * INC + kk * 32 + g * 8);
    }

    f32x4 acc[4][2];
#pragma unroll
    for (int mt = 0; mt < 4; ++mt)
#pragma unroll
        for (int nt = 0; nt < 2; ++nt)
            acc[mt][nt] = (f32x4){0.0f, 0.0f, 0.0f, 0.0f};

#pragma unroll
    for (int kk = 0; kk < 4; ++kk) {
        bf16x8 a0 = *reinterpret_cast<const bf16x8*>(&xs[0 * 16 + c][kk * 32 + g * 8]);
        bf16x8 a1 = *reinterpret_cast<const bf16x8*>(&xs[1 * 16 + c][kk * 32 + g * 8]);
        bf16x8 a2 = *reinterpret_cast<const bf16x8*>(&xs[2 * 16 + c][kk * 32 + g * 8]);
        bf16x8 a3 = *reinterpret_cast<const bf16x8*>(&xs[3 * 16 + c][kk * 32 + g * 8]);
        acc[0][0] = __builtin_amdgcn_mfma_f32_16x16x32_bf16(a0, bw0[kk], acc[0][0], 0, 0, 0);
        acc[0][1] = __builtin_amdgcn_mfma_f32_16x16x32_bf16(a0, bw1[kk], acc[0][1], 0, 0, 0);
        acc[1][0] = __builtin_amdgcn_mfma_f32_16x16x32_bf16(a1, bw0[kk], acc[1][0], 0, 0, 0);
        acc[1][1] = __builtin_amdgcn_mfma_f32_16x16x32_bf16(a1, bw1[kk], acc[1][1], 0, 0, 0);
        acc[2][0] = __builtin_amdgcn_mfma_f32_16x16x32_bf16(a2, bw0[kk], acc[2][0], 0, 0, 0);
        acc[2][1] = __builtin_amdgcn_mfma_f32_16x16x32_bf16(a2, bw1[kk], acc[2][1], 0, 0, 0);
        acc[3][0] = __builtin_amdgcn_mfma_f32_16x16x32_bf16(a3, bw0[kk], acc[3][0], 0, 0, 0);
        acc[3][1] = __builtin_amdgcn_mfma_f32_16x16x32_bf16(a3, bw1[kk], acc[3][1], 0, 0, 0);
    }

#pragma unroll
    for (int mt = 0; mt < 4; ++mt) {
#pragma unroll
        for (int nt = 0; nt < 2; ++nt) {
            int ch = w * 32 + nt * 16 + c;
#pragma unroll
            for (int j = 0; j < 4; ++j) {
                int row = base + mt * 16 + g * 4 + j;
                if (row < NN) {
                    unsigned short vb = f2bf(acc[mt][nt][j]);
                    if (ch < OC) ybf[(size_t)row * OC + ch] = vb;
                    else         xwrbf[(size_t)row * OC + (ch - OC)] = vb;
                }
            }
        }
    }
}

// CSR build step 1: histogram of target nodes.
extern "C" __global__ void __launch_bounds__(256)
k_hist(const int* __restrict__ colv, int* __restrict__ cnti) {
    int e = blockIdx.x * 256 + threadIdx.x;
    if (e >= NE) return;
    int cl = colv[e];
    cl = min(max(cl, 0), NN - 1);
    atomicAdd(&cnti[cl], 1);
}

// CSR build step 2a: per-block exclusive scan (1024 elems/block).
extern "C" __global__ void __launch_bounds__(1024)
k_scanA(const int* __restrict__ cnti, int* __restrict__ cur,
        int* __restrict__ bsum) {
    __shared__ int s[1024];
    int t = threadIdx.x;
    int idx = blockIdx.x * 1024 + t;
    int v = (idx < NN) ? cnti[idx] : 0;
    s[t] = v;
    __syncthreads();
#pragma unroll
    for (int off = 1; off < 1024; off <<= 1) {
        int tmp = (t >= off) ? s[t - off] : 0;
        __syncthreads();
        s[t] += tmp;
        __syncthreads();
    }
    if (idx < NN) cur[idx] = s[t] - v;
    if (t == 1023) bsum[blockIdx.x] = s[1023];
}

// CSR build step 2b: scan the 98 block sums.
extern "C" __global__ void __launch_bounds__(128)
k_scanB(int* __restrict__ bsum) {
    __shared__ int s[128];
    int t = threadIdx.x;
    int v = (t < 98) ? bsum[t] : 0;
    s[t] = v;
    __syncthreads();
#pragma unroll
    for (int off = 1; off < 128; off <<= 1) {
        int tmp = (t >= off) ? s[t - off] : 0;
        __syncthreads();
        s[t] += tmp;
        __syncthreads();
    }
    if (t < 98) bsum[t] = s[t] - v;
}

// CSR build step 2c: add block offsets.
extern "C" __global__ void __launch_bounds__(1024)
k_scanC(int* __restrict__ cur, const int* __restrict__ bsum) {
    int idx = blockIdx.x * 1024 + threadIdx.x;
    if (idx < NN) cur[idx] += bsum[blockIdx.x];
}

// CSR build step 3: bucket edges by target. Payload row(17)|col(17)|e(30-bit field).
extern "C" __global__ void __launch_bounds__(256)
k_bucket(const int* __restrict__ colv, const int* __restrict__ rowv,
         int* __restrict__ cur, unsigned long long* __restrict__ ec) {
    int e = blockIdx.x * 256 + threadIdx.x;
    if (e >= NE) return;
    int cl = colv[e];
    cl = min(max(cl, 0), NN - 1);
    int r = rowv[e];
    r = min(max(r, 0), NN - 1);
    int pos = atomicAdd(&cur[cl], 1);
    ec[pos] = ((unsigned long long)(unsigned)r << 47) |
              ((unsigned long long)(unsigned)cl << 30) | (unsigned)e;
}

// K2: mean-agg numerator, atomic-free. Wave per node, lane = channel; bf16 yl.
extern "C" __global__ void __launch_bounds__(256)
k_agg(const unsigned long long* __restrict__ ec, const int* __restrict__ cur,
      const unsigned short* __restrict__ ybf, float* __restrict__ agg) {
    int i = blockIdx.x * 4 + (threadIdx.x >> 6);
    if (i >= NN) return;
    int c = threadIdx.x & 63;
    int start = (i == 0) ? 0 : cur[i - 1];
    int end = cur[i];
    float acc = 0.0f;
    int p = start;
    for (; p + 1 < end; p += 2) {
        int r0 = (int)(ec[p] >> 47);
        int r1 = (int)(ec[p + 1] >> 47);
        float v0 = bf2f(ybf[(size_t)r0 * OC + c]);
        float v1 = bf2f(ybf[(size_t)r1 * OC + c]);
        acc += v0;
        acc += v1;
    }
    if (p < end) {
        int r0 = (int)(ec[p] >> 47);
        acc += bf2f(ybf[(size_t)r0 * OC + c]);
    }
    agg[(size_t)i * OC + c] = acc;
}

// K3: fused out_pre finalize + h projection.
// o = agg/max(deg,1) + bl + xwr ; agg <- o ; h(bf16) = o@Wg_top + bg + hb.
extern "C" __global__ void __launch_bounds__(256)
k_oh(const unsigned short* __restrict__ xwrbf, const float* __restrict__ bl,
     const int* __restrict__ cur, const float* __restrict__ Wg,
     const float* __restrict__ bg, const float* __restrict__ hb,
     float* __restrict__ agg, unsigned short* __restrict__ hbf) {
    int i = blockIdx.x * 256 + threadIdx.x;
    if (i >= NN) return;
    int deg = cur[i] - ((i == 0) ? 0 : cur[i - 1]);
    float inv = 1.0f / fmaxf((float)deg, 1.0f);
    float o[OC];
    float* ap = agg + (size_t)i * OC;
    const uint2* xq = reinterpret_cast<const uint2*>(xwrbf + (size_t)i * OC);
#pragma unroll
    for (int q = 0; q < 16; ++q) {
        float4 av = *reinterpret_cast<const float4*>(ap + 4 * q);
        uint2 xv = xq[q];
        o[4 * q + 0] = fmaf(av.x, inv, bl[4 * q + 0] + bf2f((unsigned short)(xv.x & 0xffffu)));
        o[4 * q + 1] = fmaf(av.y, inv, bl[4 * q + 1] + bf2f((unsigned short)(xv.x >> 16)));
        o[4 * q + 2] = fmaf(av.z, inv, bl[4 * q + 2] + bf2f((unsigned short)(xv.y & 0xffffu)));
        o[4 * q + 3] = fmaf(av.w, inv, bl[4 * q + 3] + bf2f((unsigned short)(xv.y >> 16)));
    }
#pragma unroll
    for (int q = 0; q < 16; ++q) {
        float4 sv;
        sv.x = o[4 * q + 0]; sv.y = o[4 * q + 1];
        sv.z = o[4 * q + 2]; sv.w = o[4 * q + 3];
        *reinterpret_cast<float4*>(ap + 4 * q) = sv;
    }
#pragma unroll 1
    for (int j0 = 0; j0 < OC; j0 += 8) {
        float a8[8];
#pragma unroll
        for (int jj = 0; jj < 8; ++jj) a8[jj] = bg[j0 + jj] + hb[j0 + jj];
#pragma unroll
        for (int k = 0; k < OC; ++k) {
            float ov = o[k];
#pragma unroll
            for (int jj = 0; jj < 8; ++jj)
                a8[jj] = fmaf(ov, Wg[k * OC + j0 + jj], a8[jj]);
        }
        uint4 pk;
        pk.x = (unsigned)f2bf(a8[0]) | ((unsigned)f2bf(a8[1]) << 16);
        pk.y = (unsigned)f2bf(a8[2]) | ((unsigned)f2bf(a8[3]) << 16);
        pk.z = (unsigned)f2bf(a8[4]) | ((unsigned)f2bf(a8[5]) << 16);
        pk.w = (unsigned)f2bf(a8[6]) | ((unsigned)f2bf(a8[7]) << 16);
        *reinterpret_cast<uint4*>(hbf + (size_t)i * OC + j0) = pk;
    }
}

// K4: MFMA gating, zero-LDS, latency-hoisted. Wave = 64 sorted edges.
// All shuffles + A-frags upfront; per-mt the 16 h-gathers (bf16) are issued
// as a batch before the 8 MFMAs. launch_bounds(256,3) -> ~160 VGPR budget.
extern "C" __global__ void __launch_bounds__(256, 3)
k_gate(const unsigned long long* __restrict__ ec, const float* __restrict__ eattr,
       const unsigned short* __restrict__ WfT, const unsigned short* __restrict__ WeT,
       const float* __restrict__ be, const unsigned short* __restrict__ hbf,
       float* __restrict__ agg) {
    int lane = threadIdx.x & 63;
    int w = threadIdx.x >> 6;
    int tb = (blockIdx.x * 4 + w) * 64;  // NE % 256 == 0

    unsigned long long ev = ec[tb + lane];
    int e = (int)(ev & 0x3FFFFFFFULL);
    int cl = (int)((ev >> 30) & 0x1FFFFULL);
    int c = lane & 15, g = lane >> 4;

    // all cross-lane traffic upfront
    int erow0 = __shfl(e, 0 * 16 + c);
    int erow1 = __shfl(e, 1 * 16 + c);
    int erow2 = __shfl(e, 2 * 16 + c);
    int erow3 = __shfl(e, 3 * 16 + c);
    int clx[16];
#pragma unroll
    for (int mt = 0; mt < 4; ++mt)
#pragma unroll
        for (int r = 0; r < 4; ++r)
            clx[mt * 4 + r] = __shfl(cl, mt * 16 + g * 4 + r);

    // weight fragments + be
    bf16x8 bwf[4], bwe[4];
    float bev[4];
#pragma unroll
    for (int nt = 0; nt < 4; ++nt) {
        int ch = nt * 16 + c;
        bwf[nt] = *reinterpret_cast<const bf16x8*>(WfT + ch * ED + g * 8);
        bwe[nt] = *reinterpret_cast<const bf16x8*>(WeT + ch * ED + g * 8);
        bev[nt] = be[ch];
    }

    // A-fragments direct from global
    bf16x8 afr[4];
#pragma unroll
    for (int mt = 0; mt < 4; ++mt) {
        int er = (mt == 0) ? erow0 : (mt == 1) ? erow1 : (mt == 2) ? erow2 : erow3;
        const float4* q = reinterpret_cast<const float4*>(
            eattr + (size_t)er * ED + g * 8);
        float4 lo = q[0], hi = q[1];
        union { bf16x8 v; unsigned short u[8]; } pk;
        pk.u[0] = f2bf(lo.x); pk.u[1] = f2bf(lo.y);
        pk.u[2] = f2bf(lo.z); pk.u[3] = f2bf(lo.w);
        pk.u[4] = f2bf(hi.x); pk.u[5] = f2bf(hi.y);
        pk.u[6] = f2bf(hi.z); pk.u[7] = f2bf(hi.w);
        afr[mt] = pk.v;
    }

#pragma unroll
    for (int mt = 0; mt < 4; ++mt) {
        int cl0 = clx[mt * 4 + 0];
        int cl1 = clx[mt * 4 + 1];
        int cl2 = clx[mt * 4 + 2];
        int cl3 = clx[mt * 4 + 3];
        // batch the 16 h-gathers (bf16) for all nt before any MFMA
        float hz[16];
#pragma unroll
        for (int nt = 0; nt < 4; ++nt) {
            int ch = nt * 16 + c;
            hz[nt * 4 + 0] = bf2f(hbf[(size_t)cl0 * OC + ch]);
            hz[nt * 4 + 1] = bf2f(hbf[(size_t)cl1 * OC + ch]);
            hz[nt * 4 + 2] = bf2f(hbf[(size_t)cl2 * OC + ch]);
            hz[nt * 4 + 3] = bf2f(hbf[(size_t)cl3 * OC + ch]);
        }
#pragma unroll
        for (int nt = 0; nt < 4; ++nt) {
            int ch = nt * 16 + c;
            f32x4 cz, ce;
            cz[0] = hz[nt * 4 + 0]; cz[1] = hz[nt * 4 + 1];
            cz[2] = hz[nt * 4 + 2]; cz[3] = hz[nt * 4 + 3];
            ce[0] = bev[nt]; ce[1] = bev[nt]; ce[2] = bev[nt]; ce[3] = bev[nt];
            f32x4 z  = __builtin_amdgcn_mfma_f32_16x16x32_bf16(afr[mt], bwf[nt], cz, 0, 0, 0);
            f32x4 ea = __builtin_amdgcn_mfma_f32_16x16x32_bf16(afr[mt], bwe[nt], ce, 0, 0, 0);
            float c0 = sigmoidf_(z[0]) * ea[0];
            float c1 = sigmoidf_(z[1]) * ea[1];
            float c2 = sigmoidf_(z[2]) * ea[2];
            float c3 = sigmoidf_(z[3]) * ea[3];
            // register segmented scatter over the sorted run
            float s = c0;
            int t = cl0;
            if (cl1 != t) { atomicAdd(&agg[(size_t)t * OC + ch], s); s = 0.0f; t = cl1; }
            s += c1;
            if (cl2 != t) { atomicAdd(&agg[(size_t)t * OC + ch], s); s = 0.0f; t = cl2; }
            s += c2;
            if (cl3 != t) { atomicAdd(&agg[(size_t)t * OC + ch], s); s = 0.0f; t = cl3; }
            s += c3;
            atomicAdd(&agg[(size_t)t * OC + ch], s);
        }
    }
}

// K5: BN batch stats.
extern "C" __global__ void __launch_bounds__(256)
k_stats(const float* __restrict__ a, float* __restrict__ stats) {
    __shared__ float ls[256], lq[256];
    int t = threadIdx.x;
    float s = 0.0f, q = 0.0f;
    for (size_t idx = (size_t)blockIdx.x * 256 + t; idx < (size_t)NN * OC;
         idx += (size_t)gridDim.x * 256) {
        float v = a[idx];
        s += v;
        q = fmaf(v, v, q);
    }
    ls[t] = s; lq[t] = q;
    __syncthreads();
    if (t < OC) {
        s = ls[t] + ls[t + 64] + ls[t + 128] + ls[t + 192];
        q = lq[t] + lq[t + 64] + lq[t + 128] + lq[t + 192];
        atomicAdd(&stats[t], s);
        atomicAdd(&stats[OC + t], q);
    }
}

// K6: BN normalize + residual(2x) + ReLU.
extern "C" __global__ void __launch_bounds__(256)
k_final(const float* __restrict__ a, const float* __restrict__ stats,
        const float* __restrict__ gamma, const float* __restrict__ beta,
        float* __restrict__ out) {
    size_t idx = (size_t)blockIdx.x * 256 + threadIdx.x;
    if (idx >= (size_t)NN * OC) return;
    int c = (int)(idx & 63);
    float mu = stats[c] * (1.0f / NN);
    float var = stats[OC + c] * (1.0f / NN) - mu * mu;
    float v = a[idx];
    float y = fmaf(gamma[c] * (v - mu), rsqrtf(var + 1e-5f), beta[c]);
    out[idx] = fmaxf(2.0f * y, 0.0f);
}

extern "C" void kernel_launch(void* const* d_in, const int* in_sizes, int n_in,
                              void* d_out, int out_size, void* d_ws, size_t ws_size,
                              hipStream_t stream) {
    const float* x     = (const float*)d_in[0];
    const int*   ei    = (const int*)d_in[1];   // (2, NE) int32
    const float* eattr = (const float*)d_in[2];
    const float* Wl    = (const float*)d_in[3];
    const float* bl    = (const float*)d_in[4];
    const float* Wr    = (const float*)d_in[5];
    const float* We    = (const float*)d_in[6];
    const float* be    = (const float*)d_in[7];
    const float* Wg    = (const float*)d_in[8];
    const float* bg    = (const float*)d_in[9];
    const float* gamma = (const float*)d_in[10];
    const float* beta  = (const float*)d_in[11];
    float* out = (float*)d_out;

    // ws: agg f32[6.4M] | ybf/hbf u16[6.4M] | xwrbf u16[6.4M] | ec u64[1.6M] |
    //     cur i32[100k] | bsum i32[128] | stats f32[128] |
    //     WfT u16[2048] | WeT u16[2048] | WlrT u16[16384] | hb f32[64]   (~64.4MB)
    float* agg = (float*)d_ws;
    unsigned short* ybf   = (unsigned short*)(agg + (size_t)NN * OC);
    unsigned short* xwrbf = ybf + (size_t)NN * OC;
    unsigned long long* ec = (unsigned long long*)(xwrbf + (size_t)NN * OC);
    int* cur   = (int*)(ec + (size_t)NE);
    int* bsum  = cur + NN;
    float* stats = (float*)(bsum + 128);
    unsigned short* WfT  = (unsigned short*)(stats + 128);
    unsigned short* WeT  = WfT + ED * OC;
    unsigned short* WlrT = WeT + ED * OC;
    float* hb = (float*)(WlrT + 2 * INC * OC);
    unsigned short* hbf = ybf;  // yl slot is dead after k_agg

    const int* rowv = ei;
    const int* colv = ei + NE;

    hipMemsetAsync(cur, 0, NN * sizeof(int), stream);
    hipMemsetAsync(stats, 0, 2 * OC * sizeof(float), stream);

    k_wfuse<<<(2 * ED * OC + OC + 2 * INC * OC + 255) / 256, 256, 0, stream>>>(
        We, be, Wg, Wl, Wr, WfT, WeT, hb, WlrT);
    k_xw<<<(NN + 63) / 64, 256, 0, stream>>>(x, WlrT, ybf, xwrbf);
    k_hist<<<(NE + 255) / 256, 256, 0, stream>>>(colv, cur);
    k_scanA<<<98, 1024, 0, stream>>>(cur, cur, bsum);
    k_scanB<<<1, 128, 0, stream>>>(bsum);
    k_scanC<<<98, 1024, 0, stream>>>(cur, bsum);
    k_bucket<<<(NE + 255) / 256, 256, 0, stream>>>(colv, rowv, cur, ec);
    k_agg<<<(NN + 3) / 4, 256, 0, stream>>>(ec, cur, ybf, agg);
    k_oh<<<(NN + 255) / 256, 256, 0, stream>>>(xwrbf, bl, cur, Wg, bg, hb, agg, hbf);
    k_gate<<<NE / 256, 256, 0, stream>>>(ec, eattr, WfT, WeT, be, hbf, agg);
    k_stats<<<2048, 256, 0, stream>>>(agg, stats);
    k_final<<<((size_t)NN * OC + 255) / 256, 256, 0, stream>>>(agg, stats, gamma, beta, out);
}

// Round 9
// 693.853 us; speedup vs baseline: 1.9696x; 1.0013x over previous
//
#include <hip/hip_runtime.h>
#include <math.h>

#define NN 100000
#define NE 1600000
#define INC 128
#define OC 64
#define ED 32

typedef __attribute__((ext_vector_type(8))) short bf16x8;
typedef __attribute__((ext_vector_type(4))) float f32x4;

__device__ __forceinline__ float sigmoidf_(float z) {
    return __builtin_amdgcn_rcpf(1.0f + __expf(-z));
}

// float -> bf16 bits, round-to-nearest-even
__device__ __forceinline__ unsigned short f2bf(float x) {
    unsigned int u = __float_as_uint(x);
    unsigned int r = u + 0x7FFFu + ((u >> 16) & 1u);
    return (unsigned short)(r >> 16);
}
__device__ __forceinline__ float bf2f(unsigned short u) {
    return __uint_as_float((unsigned int)u << 16);
}

// K0: weight prep.
//  WfT[ch][k] = bf16((We@Wg_bot)[k][ch])  (2048)
//  WeT[ch][k] = bf16(We[k][ch])           (2048)
//  hb = be @ Wg_bot                       (64)
//  WlrT[ch][k] = bf16([Wl|Wr][k][ch]), ch in [0,128)  (16384)
extern "C" __global__ void __launch_bounds__(256)
k_wfuse(const float* __restrict__ We, const float* __restrict__ be,
        const float* __restrict__ Wg, const float* __restrict__ Wl,
        const float* __restrict__ Wr, unsigned short* __restrict__ WfT,
        unsigned short* __restrict__ WeT, float* __restrict__ hb,
        unsigned short* __restrict__ WlrT) {
    int idx = blockIdx.x * 256 + threadIdx.x;
    if (idx < ED * OC) {                 // WfT: idx = ch*32 + d
        int ch = idx >> 5, d = idx & 31;
        float acc = 0.0f;
#pragma unroll
        for (int k = 0; k < OC; ++k)
            acc = fmaf(We[d * OC + k], Wg[(OC + k) * OC + ch], acc);
        WfT[idx] = f2bf(acc);
    } else if (idx < 2 * ED * OC) {      // WeT
        int i2 = idx - ED * OC;
        int ch = i2 >> 5, d = i2 & 31;
        WeT[i2] = f2bf(We[d * OC + ch]);
    } else if (idx < 2 * ED * OC + OC) { // hb
        int j = idx - 2 * ED * OC;
        float acc = 0.0f;
#pragma unroll
        for (int k = 0; k < OC; ++k)
            acc = fmaf(be[k], Wg[(OC + k) * OC + j], acc);
        hb[j] = acc;
    } else if (idx < 2 * ED * OC + OC + 2 * INC * OC) {  // WlrT
        int i3 = idx - (2 * ED * OC + OC);
        int ch = i3 >> 7, k = i3 & 127;
        float v = (ch < OC) ? Wl[k * OC + ch] : Wr[k * OC + (ch - OC)];
        WlrT[i3] = f2bf(v);
    }
}

// K1: MFMA GEMM  [yl | xwr](bf16) = x @ [Wl | Wr].
extern "C" __global__ void __launch_bounds__(256)
k_xw(const float* __restrict__ x, const unsigned short* __restrict__ WlrT,
     unsigned short* __restrict__ ybf, unsigned short* __restrict__ xwrbf) {
    __shared__ unsigned short xs[64][136];
    int t = threadIdx.x;
    int base = blockIdx.x * 64;
    {
        int rr = t >> 2, cc = (t & 3) * 32;
        int grow = base + rr;
        if (grow < NN) {
            const float4* xp = reinterpret_cast<const float4*>(
                x + (size_t)grow * INC + cc);
#pragma unroll
            for (int q = 0; q < 8; ++q) {
                float4 v = xp[q];
                uint2 uv;
                uv.x = (unsigned)f2bf(v.x) | ((unsigned)f2bf(v.y) << 16);
                uv.y = (unsigned)f2bf(v.z) | ((unsigned)f2bf(v.w) << 16);
                *reinterpret_cast<uint2*>(&xs[rr][cc + q * 4]) = uv;
            }
        } else {
#pragma unroll
            for (int q = 0; q < 8; ++q) {
                uint2 uv; uv.x = 0u; uv.y = 0u;
                *reinterpret_cast<uint2*>(&xs[rr][cc + q * 4]) = uv;
            }
        }
    }
    __syncthreads();

    int lane = t & 63, w = t >> 6;
    int c = lane & 15, g = lane >> 4;

    bf16x8 bw0[4], bw1[4];
#pragma unroll
    for (int kk = 0; kk < 4; ++kk) {
        bw0[kk] = *reinterpret_cast<const bf16x8*>(
            WlrT + (w * 32 + 0 * 16 + c) * INC + kk * 32 + g * 8);
        bw1[kk] = *reinterpret_cast<const bf16x8*>(
            WlrT + (w * 32 + 1 * 16 + c) * INC + kk * 32 + g * 8);
    }

    f32x4 acc[4][2];
#pragma unroll
    for (int mt = 0; mt < 4; ++mt)
#pragma unroll
        for (int nt = 0; nt < 2; ++nt)
            acc[mt][nt] = (f32x4){0.0f, 0.0f, 0.0f, 0.0f};

#pragma unroll
    for (int kk = 0; kk < 4; ++kk) {
        bf16x8 a0 = *reinterpret_cast<const bf16x8*>(&xs[0 * 16 + c][kk * 32 + g * 8]);
        bf16x8 a1 = *reinterpret_cast<const bf16x8*>(&xs[1 * 16 + c][kk * 32 + g * 8]);
        bf16x8 a2 = *reinterpret_cast<const bf16x8*>(&xs[2 * 16 + c][kk * 32 + g * 8]);
        bf16x8 a3 = *reinterpret_cast<const bf16x8*>(&xs[3 * 16 + c][kk * 32 + g * 8]);
        acc[0][0] = __builtin_amdgcn_mfma_f32_16x16x32_bf16(a0, bw0[kk], acc[0][0], 0, 0, 0);
        acc[0][1] = __builtin_amdgcn_mfma_f32_16x16x32_bf16(a0, bw1[kk], acc[0][1], 0, 0, 0);
        acc[1][0] = __builtin_amdgcn_mfma_f32_16x16x32_bf16(a1, bw0[kk], acc[1][0], 0, 0, 0);
        acc[1][1] = __builtin_amdgcn_mfma_f32_16x16x32_bf16(a1, bw1[kk], acc[1][1], 0, 0, 0);
        acc[2][0] = __builtin_amdgcn_mfma_f32_16x16x32_bf16(a2, bw0[kk], acc[2][0], 0, 0, 0);
        acc[2][1] = __builtin_amdgcn_mfma_f32_16x16x32_bf16(a2, bw1[kk], acc[2][1], 0, 0, 0);
        acc[3][0] = __builtin_amdgcn_mfma_f32_16x16x32_bf16(a3, bw0[kk], acc[3][0], 0, 0, 0);
        acc[3][1] = __builtin_amdgcn_mfma_f32_16x16x32_bf16(a3, bw1[kk], acc[3][1], 0, 0, 0);
    }

#pragma unroll
    for (int mt = 0; mt < 4; ++mt) {
#pragma unroll
        for (int nt = 0; nt < 2; ++nt) {
            int ch = w * 32 + nt * 16 + c;
#pragma unroll
            for (int j = 0; j < 4; ++j) {
                int row = base + mt * 16 + g * 4 + j;
                if (row < NN) {
                    unsigned short vb = f2bf(acc[mt][nt][j]);
                    if (ch < OC) ybf[(size_t)row * OC + ch] = vb;
                    else         xwrbf[(size_t)row * OC + (ch - OC)] = vb;
                }
            }
        }
    }
}

// CSR build step 1: histogram of target nodes.
extern "C" __global__ void __launch_bounds__(256)
k_hist(const int* __restrict__ colv, int* __restrict__ cnti) {
    int e = blockIdx.x * 256 + threadIdx.x;
    if (e >= NE) return;
    int cl = colv[e];
    cl = min(max(cl, 0), NN - 1);
    atomicAdd(&cnti[cl], 1);
}

// CSR build step 2a: per-block exclusive scan.
extern "C" __global__ void __launch_bounds__(1024)
k_scanA(const int* __restrict__ cnti, int* __restrict__ cur,
        int* __restrict__ bsum) {
    __shared__ int s[1024];
    int t = threadIdx.x;
    int idx = blockIdx.x * 1024 + t;
    int v = (idx < NN) ? cnti[idx] : 0;
    s[t] = v;
    __syncthreads();
#pragma unroll
    for (int off = 1; off < 1024; off <<= 1) {
        int tmp = (t >= off) ? s[t - off] : 0;
        __syncthreads();
        s[t] += tmp;
        __syncthreads();
    }
    if (idx < NN) cur[idx] = s[t] - v;
    if (t == 1023) bsum[blockIdx.x] = s[1023];
}

// CSR build step 2b.
extern "C" __global__ void __launch_bounds__(128)
k_scanB(int* __restrict__ bsum) {
    __shared__ int s[128];
    int t = threadIdx.x;
    int v = (t < 98) ? bsum[t] : 0;
    s[t] = v;
    __syncthreads();
#pragma unroll
    for (int off = 1; off < 128; off <<= 1) {
        int tmp = (t >= off) ? s[t - off] : 0;
        __syncthreads();
        s[t] += tmp;
        __syncthreads();
    }
    if (t < 98) bsum[t] = s[t] - v;
}

// CSR build step 2c.
extern "C" __global__ void __launch_bounds__(1024)
k_scanC(int* __restrict__ cur, const int* __restrict__ bsum) {
    int idx = blockIdx.x * 1024 + threadIdx.x;
    if (idx < NN) cur[idx] += bsum[blockIdx.x];
}

// CSR build step 3: bucket edges by target. Payload row(17)|col(17)|e(30-bit).
extern "C" __global__ void __launch_bounds__(256)
k_bucket(const int* __restrict__ colv, const int* __restrict__ rowv,
         int* __restrict__ cur, unsigned long long* __restrict__ ec) {
    int e = blockIdx.x * 256 + threadIdx.x;
    if (e >= NE) return;
    int cl = colv[e];
    cl = min(max(cl, 0), NN - 1);
    int r = rowv[e];
    r = min(max(r, 0), NN - 1);
    int pos = atomicAdd(&cur[cl], 1);
    ec[pos] = ((unsigned long long)(unsigned)r << 47) |
              ((unsigned long long)(unsigned)cl << 30) | (unsigned)e;
}

// K2: mean-agg numerator, atomic-free, batch-4 MLP: all 4 gathers issued
// before the adds (addresses from scalar ec loads).
extern "C" __global__ void __launch_bounds__(256)
k_agg(const unsigned long long* __restrict__ ec, const int* __restrict__ cur,
      const unsigned short* __restrict__ ybf, float* __restrict__ agg) {
    int i = blockIdx.x * 4 + (threadIdx.x >> 6);
    if (i >= NN) return;
    int c = threadIdx.x & 63;
    int start = (i == 0) ? 0 : cur[i - 1];
    int end = cur[i];
    float acc = 0.0f;
    int p = start;
    for (; p + 3 < end; p += 4) {
        int r0 = (int)(ec[p] >> 47);
        int r1 = (int)(ec[p + 1] >> 47);
        int r2 = (int)(ec[p + 2] >> 47);
        int r3 = (int)(ec[p + 3] >> 47);
        unsigned short u0 = ybf[(size_t)r0 * OC + c];
        unsigned short u1 = ybf[(size_t)r1 * OC + c];
        unsigned short u2 = ybf[(size_t)r2 * OC + c];
        unsigned short u3 = ybf[(size_t)r3 * OC + c];
        acc += bf2f(u0);
        acc += bf2f(u1);
        acc += bf2f(u2);
        acc += bf2f(u3);
    }
    for (; p < end; ++p) {
        int r0 = (int)(ec[p] >> 47);
        acc += bf2f(ybf[(size_t)r0 * OC + c]);
    }
    agg[(size_t)i * OC + c] = acc;
}

// K3: fused out_pre finalize + h projection. h output is bf16 in SWIZZLED
// layout: hswz[i*64 + c*4 + nt] = h[i][nt*16+c]  (one uint2 gather in k_gate
// fetches all 4 nt-channels of a (node, c) pair).
extern "C" __global__ void __launch_bounds__(256)
k_oh(const unsigned short* __restrict__ xwrbf, const float* __restrict__ bl,
     const int* __restrict__ cur, const float* __restrict__ Wg,
     const float* __restrict__ bg, const float* __restrict__ hb,
     float* __restrict__ agg, unsigned short* __restrict__ hswz) {
    int i = blockIdx.x * 256 + threadIdx.x;
    if (i >= NN) return;
    int deg = cur[i] - ((i == 0) ? 0 : cur[i - 1]);
    float inv = 1.0f / fmaxf((float)deg, 1.0f);
    float o[OC];
    float* ap = agg + (size_t)i * OC;
    const uint2* xq = reinterpret_cast<const uint2*>(xwrbf + (size_t)i * OC);
#pragma unroll
    for (int q = 0; q < 16; ++q) {
        float4 av = *reinterpret_cast<const float4*>(ap + 4 * q);
        uint2 xv = xq[q];
        o[4 * q + 0] = fmaf(av.x, inv, bl[4 * q + 0] + bf2f((unsigned short)(xv.x & 0xffffu)));
        o[4 * q + 1] = fmaf(av.y, inv, bl[4 * q + 1] + bf2f((unsigned short)(xv.x >> 16)));
        o[4 * q + 2] = fmaf(av.z, inv, bl[4 * q + 2] + bf2f((unsigned short)(xv.y & 0xffffu)));
        o[4 * q + 3] = fmaf(av.w, inv, bl[4 * q + 3] + bf2f((unsigned short)(xv.y >> 16)));
    }
#pragma unroll
    for (int q = 0; q < 16; ++q) {
        float4 sv;
        sv.x = o[4 * q + 0]; sv.y = o[4 * q + 1];
        sv.z = o[4 * q + 2]; sv.w = o[4 * q + 3];
        *reinterpret_cast<float4*>(ap + 4 * q) = sv;
    }
    float h64[OC];
#pragma unroll 1
    for (int j0 = 0; j0 < OC; j0 += 8) {
        float a8[8];
#pragma unroll
        for (int jj = 0; jj < 8; ++jj) a8[jj] = bg[j0 + jj] + hb[j0 + jj];
#pragma unroll
        for (int k = 0; k < OC; ++k) {
            float ov = o[k];
#pragma unroll
            for (int jj = 0; jj < 8; ++jj)
                a8[jj] = fmaf(ov, Wg[k * OC + j0 + jj], a8[jj]);
        }
#pragma unroll
        for (int jj = 0; jj < 8; ++jj) h64[j0 + jj] = a8[jj];
    }
    // swizzled store: position c*4+nt holds channel nt*16+c
    unsigned short* hp = hswz + (size_t)i * OC;
#pragma unroll
    for (int c = 0; c < 16; ++c) {
        uint2 pk;
        pk.x = (unsigned)f2bf(h64[c]) | ((unsigned)f2bf(h64[16 + c]) << 16);
        pk.y = (unsigned)f2bf(h64[32 + c]) | ((unsigned)f2bf(h64[48 + c]) << 16);
        *reinterpret_cast<uint2*>(hp + c * 4) = pk;
    }
}

// K4: MFMA gating, zero-LDS, FULL memory-level parallelism. Wave = 64 sorted
// edges. ALL memory issued upfront in source order (1 ec + 16 h-uint2 +
// 16 weight frags + 8 A float4s, distinct static registers) -> one latency
// exposure per wave, then pure-register compute (32 MFMA + sigmoid +
// run-merged atomics). h gathers use the swizzled layout: uint2 at
// hswz[cl*64 + c*4] = channels {c, 16+c, 32+c, 48+c}.
extern "C" __global__ void __launch_bounds__(256, 3)
k_gate(const unsigned long long* __restrict__ ec, const float* __restrict__ eattr,
       const unsigned short* __restrict__ WfT, const unsigned short* __restrict__ WeT,
       const float* __restrict__ be, const unsigned short* __restrict__ hswz,
       float* __restrict__ agg) {
    int lane = threadIdx.x & 63;
    int w = threadIdx.x >> 6;
    int tb = (blockIdx.x * 4 + w) * 64;  // NE % 256 == 0

    unsigned long long ev = ec[tb + lane];
    int e = (int)(ev & 0x3FFFFFFFULL);
    int cl = (int)((ev >> 30) & 0x1FFFFULL);
    int c = lane & 15, g = lane >> 4;

    // cross-lane traffic
    int erow0 = __shfl(e, 0 * 16 + c);
    int erow1 = __shfl(e, 1 * 16 + c);
    int erow2 = __shfl(e, 2 * 16 + c);
    int erow3 = __shfl(e, 3 * 16 + c);
    int clx[16];
#pragma unroll
    for (int mt = 0; mt < 4; ++mt)
#pragma unroll
        for (int r = 0; r < 4; ++r)
            clx[mt * 4 + r] = __shfl(cl, mt * 16 + g * 4 + r);

    // ---- issue ALL loads upfront ----
    uint2 hg[16];
#pragma unroll
    for (int q = 0; q < 16; ++q)
        hg[q] = *reinterpret_cast<const uint2*>(hswz + (size_t)clx[q] * OC + c * 4);

    bf16x8 bwf[4], bwe[4];
    float bev[4];
#pragma unroll
    for (int nt = 0; nt < 4; ++nt) {
        int ch = nt * 16 + c;
        bwf[nt] = *reinterpret_cast<const bf16x8*>(WfT + ch * ED + g * 8);
        bwe[nt] = *reinterpret_cast<const bf16x8*>(WeT + ch * ED + g * 8);
        bev[nt] = be[ch];
    }

    float4 alo0 = reinterpret_cast<const float4*>(eattr + (size_t)erow0 * ED + g * 8)[0];
    float4 ahi0 = reinterpret_cast<const float4*>(eattr + (size_t)erow0 * ED + g * 8)[1];
    float4 alo1 = reinterpret_cast<const float4*>(eattr + (size_t)erow1 * ED + g * 8)[0];
    float4 ahi1 = reinterpret_cast<const float4*>(eattr + (size_t)erow1 * ED + g * 8)[1];
    float4 alo2 = reinterpret_cast<const float4*>(eattr + (size_t)erow2 * ED + g * 8)[0];
    float4 ahi2 = reinterpret_cast<const float4*>(eattr + (size_t)erow2 * ED + g * 8)[1];
    float4 alo3 = reinterpret_cast<const float4*>(eattr + (size_t)erow3 * ED + g * 8)[0];
    float4 ahi3 = reinterpret_cast<const float4*>(eattr + (size_t)erow3 * ED + g * 8)[1];

    // ---- convert A (single wait point drains everything: vmcnt is in-order) ----
    bf16x8 afr[4];
    {
        union { bf16x8 v; unsigned short u[8]; } pk;
#define PACKA(idx, lo, hi)                                    \
        pk.u[0] = f2bf(lo.x); pk.u[1] = f2bf(lo.y);           \
        pk.u[2] = f2bf(lo.z); pk.u[3] = f2bf(lo.w);           \
        pk.u[4] = f2bf(hi.x); pk.u[5] = f2bf(hi.y);           \
        pk.u[6] = f2bf(hi.z); pk.u[7] = f2bf(hi.w);           \
        afr[idx] = pk.v;
        PACKA(0, alo0, ahi0)
        PACKA(1, alo1, ahi1)
        PACKA(2, alo2, ahi2)
        PACKA(3, alo3, ahi3)
#undef PACKA
    }

    // ---- pure-register compute ----
#pragma unroll
    for (int mt = 0; mt < 4; ++mt) {
        int cl0 = clx[mt * 4 + 0];
        int cl1 = clx[mt * 4 + 1];
        int cl2 = clx[mt * 4 + 2];
        int cl3 = clx[mt * 4 + 3];
        uint2 h0 = hg[mt * 4 + 0];
        uint2 h1 = hg[mt * 4 + 1];
        uint2 h2 = hg[mt * 4 + 2];
        uint2 h3 = hg[mt * 4 + 3];
#pragma unroll
        for (int nt = 0; nt < 4; ++nt) {
            int ch = nt * 16 + c;
            f32x4 cz, ce;
            // extract channel nt from the packed uint2 (word nt>>1, half nt&1)
            unsigned w0 = (nt < 2) ? h0.x : h0.y;
            unsigned w1 = (nt < 2) ? h1.x : h1.y;
            unsigned w2 = (nt < 2) ? h2.x : h2.y;
            unsigned w3 = (nt < 2) ? h3.x : h3.y;
            cz[0] = bf2f((unsigned short)((nt & 1) ? (w0 >> 16) : (w0 & 0xffffu)));
            cz[1] = bf2f((unsigned short)((nt & 1) ? (w1 >> 16) : (w1 & 0xffffu)));
            cz[2] = bf2f((unsigned short)((nt & 1) ? (w2 >> 16) : (w2 & 0xffffu)));
            cz[3] = bf2f((unsigned short)((nt & 1) ? (w3 >> 16) : (w3 & 0xffffu)));
            ce[0] = bev[nt]; ce[1] = bev[nt]; ce[2] = bev[nt]; ce[3] = bev[nt];
            f32x4 z  = __builtin_amdgcn_mfma_f32_16x16x32_bf16(afr[mt], bwf[nt], cz, 0, 0, 0);
            f32x4 ea = __builtin_amdgcn_mfma_f32_16x16x32_bf16(afr[mt], bwe[nt], ce, 0, 0, 0);
            float c0 = sigmoidf_(z[0]) * ea[0];
            float c1 = sigmoidf_(z[1]) * ea[1];
            float c2 = sigmoidf_(z[2]) * ea[2];
            float c3 = sigmoidf_(z[3]) * ea[3];
            // register segmented scatter over the sorted run
            float s = c0;
            int t = cl0;
            if (cl1 != t) { atomicAdd(&agg[(size_t)t * OC + ch], s); s = 0.0f; t = cl1; }
            s += c1;
            if (cl2 != t) { atomicAdd(&agg[(size_t)t * OC + ch], s); s = 0.0f; t = cl2; }
            s += c2;
            if (cl3 != t) { atomicAdd(&agg[(size_t)t * OC + ch], s); s = 0.0f; t = cl3; }
            s += c3;
            atomicAdd(&agg[(size_t)t * OC + ch], s);
        }
    }
}

// K5: BN batch stats.
extern "C" __global__ void __launch_bounds__(256)
k_stats(const float* __restrict__ a, float* __restrict__ stats) {
    __shared__ float ls[256], lq[256];
    int t = threadIdx.x;
    float s = 0.0f, q = 0.0f;
    for (size_t idx = (size_t)blockIdx.x * 256 + t; idx < (size_t)NN * OC;
         idx += (size_t)gridDim.x * 256) {
        float v = a[idx];
        s += v;
        q = fmaf(v, v, q);
    }
    ls[t] = s; lq[t] = q;
    __syncthreads();
    if (t < OC) {
        s = ls[t] + ls[t + 64] + ls[t + 128] + ls[t + 192];
        q = lq[t] + lq[t + 64] + lq[t + 128] + lq[t + 192];
        atomicAdd(&stats[t], s);
        atomicAdd(&stats[OC + t], q);
    }
}

// K6: BN normalize + residual(2x) + ReLU.
extern "C" __global__ void __launch_bounds__(256)
k_final(const float* __restrict__ a, const float* __restrict__ stats,
        const float* __restrict__ gamma, const float* __restrict__ beta,
        float* __restrict__ out) {
    size_t idx = (size_t)blockIdx.x * 256 + threadIdx.x;
    if (idx >= (size_t)NN * OC) return;
    int c = (int)(idx & 63);
    float mu = stats[c] * (1.0f / NN);
    float var = stats[OC + c] * (1.0f / NN) - mu * mu;
    float v = a[idx];
    float y = fmaf(gamma[c] * (v - mu), rsqrtf(var + 1e-5f), beta[c]);
    out[idx] = fmaxf(2.0f * y, 0.0f);
}

extern "C" void kernel_launch(void* const* d_in, const int* in_sizes, int n_in,
                              void* d_out, int out_size, void* d_ws, size_t ws_size,
                              hipStream_t stream) {
    const float* x     = (const float*)d_in[0];
    const int*   ei    = (const int*)d_in[1];   // (2, NE) int32
    const float* eattr = (const float*)d_in[2];
    const float* Wl    = (const float*)d_in[3];
    const float* bl    = (const float*)d_in[4];
    const float* Wr    = (const float*)d_in[5];
    const float* We    = (const float*)d_in[6];
    const float* be    = (const float*)d_in[7];
    const float* Wg    = (const float*)d_in[8];
    const float* bg    = (const float*)d_in[9];
    const float* gamma = (const float*)d_in[10];
    const float* beta  = (const float*)d_in[11];
    float* out = (float*)d_out;

    float* agg = (float*)d_ws;
    unsigned short* ybf   = (unsigned short*)(agg + (size_t)NN * OC);
    unsigned short* xwrbf = ybf + (size_t)NN * OC;
    unsigned long long* ec = (unsigned long long*)(xwrbf + (size_t)NN * OC);
    int* cur   = (int*)(ec + (size_t)NE);
    int* bsum  = cur + NN;
    float* stats = (float*)(bsum + 128);
    unsigned short* WfT  = (unsigned short*)(stats + 128);
    unsigned short* WeT  = WfT + ED * OC;
    unsigned short* WlrT = WeT + ED * OC;
    float* hb = (float*)(WlrT + 2 * INC * OC);
    unsigned short* hswz = ybf;  // yl slot dead after k_agg

    const int* rowv = ei;
    const int* colv = ei + NE;

    hipMemsetAsync(cur, 0, NN * sizeof(int), stream);
    hipMemsetAsync(stats, 0, 2 * OC * sizeof(float), stream);

    k_wfuse<<<(2 * ED * OC + OC + 2 * INC * OC + 255) / 256, 256, 0, stream>>>(
        We, be, Wg, Wl, Wr, WfT, WeT, hb, WlrT);
    k_xw<<<(NN + 63) / 64, 256, 0, stream>>>(x, WlrT, ybf, xwrbf);
    k_hist<<<(NE + 255) / 256, 256, 0, stream>>>(colv, cur);
    k_scanA<<<98, 1024, 0, stream>>>(cur, cur, bsum);
    k_scanB<<<1, 128, 0, stream>>>(bsum);
    k_scanC<<<98, 1024, 0, stream>>>(cur, bsum);
    k_bucket<<<(NE + 255) / 256, 256, 0, stream>>>(colv, rowv, cur, ec);
    k_agg<<<(NN + 3) / 4, 256, 0, stream>>>(ec, cur, ybf, agg);
    k_oh<<<(NN + 255) / 256, 256, 0, stream>>>(xwrbf, bl, cur, Wg, bg, hb, agg, hswz);
    k_gate<<<NE / 256, 256, 0, stream>>>(ec, eattr, WfT, WeT, be, hswz, agg);
    k_stats<<<2048, 256, 0, stream>>>(agg, stats);
    k_final<<<((size_t)NN * OC + 255) / 256, 256, 0, stream>>>(agg, stats, gamma, beta, out);
}

// Round 11
// 557.253 us; speedup vs baseline: 2.4524x; 1.2451x over previous
//
#include <hip/hip_runtime.h>
#include <math.h>

#define NN 100000
#define NE 1600000
#define INC 128
#define OC 64
#define ED 32

typedef __attribute__((ext_vector_type(8))) short bf16x8;
typedef __attribute__((ext_vector_type(4))) float f32x4;

__device__ __forceinline__ float sigmoidf_(float z) {
    return __builtin_amdgcn_rcpf(1.0f + __expf(-z));
}

// float -> bf16 bits, round-to-nearest-even (scalar)
__device__ __forceinline__ unsigned short f2bf(float x) {
    unsigned int u = __float_as_uint(x);
    unsigned int r = u + 0x7FFFu + ((u >> 16) & 1u);
    return (unsigned short)(r >> 16);
}
__device__ __forceinline__ float bf2f(unsigned short u) {
    return __uint_as_float((unsigned int)u << 16);
}
// packed 2xf32 -> 2xbf16 in one VALU op
__device__ __forceinline__ unsigned cvtpk(float lo, float hi) {
    unsigned r;
    asm("v_cvt_pk_bf16_f32 %0, %1, %2" : "=v"(r) : "v"(lo), "v"(hi));
    return r;
}

// K0: weight prep.
extern "C" __global__ void __launch_bounds__(256)
k_wfuse(const float* __restrict__ We, const float* __restrict__ be,
        const float* __restrict__ Wg, const float* __restrict__ Wl,
        const float* __restrict__ Wr, unsigned short* __restrict__ WfT,
        unsigned short* __restrict__ WeT, float* __restrict__ hb,
        unsigned short* __restrict__ WlrT) {
    int idx = blockIdx.x * 256 + threadIdx.x;
    if (idx < ED * OC) {
        int ch = idx >> 5, d = idx & 31;
        float acc = 0.0f;
#pragma unroll
        for (int k = 0; k < OC; ++k)
            acc = fmaf(We[d * OC + k], Wg[(OC + k) * OC + ch], acc);
        WfT[idx] = f2bf(acc);
    } else if (idx < 2 * ED * OC) {
        int i2 = idx - ED * OC;
        int ch = i2 >> 5, d = i2 & 31;
        WeT[i2] = f2bf(We[d * OC + ch]);
    } else if (idx < 2 * ED * OC + OC) {
        int j = idx - 2 * ED * OC;
        float acc = 0.0f;
#pragma unroll
        for (int k = 0; k < OC; ++k)
            acc = fmaf(be[k], Wg[(OC + k) * OC + j], acc);
        hb[j] = acc;
    } else if (idx < 2 * ED * OC + OC + 2 * INC * OC) {
        int i3 = idx - (2 * ED * OC + OC);
        int ch = i3 >> 7, k = i3 & 127;
        float v = (ch < OC) ? Wl[k * OC + ch] : Wr[k * OC + (ch - OC)];
        WlrT[i3] = f2bf(v);
    }
}

// K1: MFMA GEMM  [yl | xwr](bf16) = x @ [Wl | Wr].
extern "C" __global__ void __launch_bounds__(256)
k_xw(const float* __restrict__ x, const unsigned short* __restrict__ WlrT,
     unsigned short* __restrict__ ybf, unsigned short* __restrict__ xwrbf) {
    __shared__ unsigned short xs[64][136];
    int t = threadIdx.x;
    int base = blockIdx.x * 64;
    {
        int rr = t >> 2, cc = (t & 3) * 32;
        int grow = base + rr;
        if (grow < NN) {
            const float4* xp = reinterpret_cast<const float4*>(
                x + (size_t)grow * INC + cc);
#pragma unroll
            for (int q = 0; q < 8; ++q) {
                float4 v = xp[q];
                uint2 uv;
                uv.x = cvtpk(v.x, v.y);
                uv.y = cvtpk(v.z, v.w);
                *reinterpret_cast<uint2*>(&xs[rr][cc + q * 4]) = uv;
            }
        } else {
#pragma unroll
            for (int q = 0; q < 8; ++q) {
                uint2 uv; uv.x = 0u; uv.y = 0u;
                *reinterpret_cast<uint2*>(&xs[rr][cc + q * 4]) = uv;
            }
        }
    }
    __syncthreads();

    int lane = t & 63, w = t >> 6;
    int c = lane & 15, g = lane >> 4;

    bf16x8 bw0[4], bw1[4];
#pragma unroll
    for (int kk = 0; kk < 4; ++kk) {
        bw0[kk] = *reinterpret_cast<const bf16x8*>(
            WlrT + (w * 32 + 0 * 16 + c) * INC + kk * 32 + g * 8);
        bw1[kk] = *reinterpret_cast<const bf16x8*>(
            WlrT + (w * 32 + 1 * 16 + c) * INC + kk * 32 + g * 8);
    }

    f32x4 acc[4][2];
#pragma unroll
    for (int mt = 0; mt < 4; ++mt)
#pragma unroll
        for (int nt = 0; nt < 2; ++nt)
            acc[mt][nt] = (f32x4){0.0f, 0.0f, 0.0f, 0.0f};

#pragma unroll
    for (int kk = 0; kk < 4; ++kk) {
        bf16x8 a0 = *reinterpret_cast<const bf16x8*>(&xs[0 * 16 + c][kk * 32 + g * 8]);
        bf16x8 a1 = *reinterpret_cast<const bf16x8*>(&xs[1 * 16 + c][kk * 32 + g * 8]);
        bf16x8 a2 = *reinterpret_cast<const bf16x8*>(&xs[2 * 16 + c][kk * 32 + g * 8]);
        bf16x8 a3 = *reinterpret_cast<const bf16x8*>(&xs[3 * 16 + c][kk * 32 + g * 8]);
        acc[0][0] = __builtin_amdgcn_mfma_f32_16x16x32_bf16(a0, bw0[kk], acc[0][0], 0, 0, 0);
        acc[0][1] = __builtin_amdgcn_mfma_f32_16x16x32_bf16(a0, bw1[kk], acc[0][1], 0, 0, 0);
        acc[1][0] = __builtin_amdgcn_mfma_f32_16x16x32_bf16(a1, bw0[kk], acc[1][0], 0, 0, 0);
        acc[1][1] = __builtin_amdgcn_mfma_f32_16x16x32_bf16(a1, bw1[kk], acc[1][1], 0, 0, 0);
        acc[2][0] = __builtin_amdgcn_mfma_f32_16x16x32_bf16(a2, bw0[kk], acc[2][0], 0, 0, 0);
        acc[2][1] = __builtin_amdgcn_mfma_f32_16x16x32_bf16(a2, bw1[kk], acc[2][1], 0, 0, 0);
        acc[3][0] = __builtin_amdgcn_mfma_f32_16x16x32_bf16(a3, bw0[kk], acc[3][0], 0, 0, 0);
        acc[3][1] = __builtin_amdgcn_mfma_f32_16x16x32_bf16(a3, bw1[kk], acc[3][1], 0, 0, 0);
    }

#pragma unroll
    for (int mt = 0; mt < 4; ++mt) {
#pragma unroll
        for (int nt = 0; nt < 2; ++nt) {
            int ch = w * 32 + nt * 16 + c;
#pragma unroll
            for (int j = 0; j < 4; ++j) {
                int row = base + mt * 16 + g * 4 + j;
                if (row < NN) {
                    unsigned short vb = f2bf(acc[mt][nt][j]);
                    if (ch < OC) ybf[(size_t)row * OC + ch] = vb;
                    else         xwrbf[(size_t)row * OC + (ch - OC)] = vb;
                }
            }
        }
    }
}

// CSR build.
extern "C" __global__ void __launch_bounds__(256)
k_hist(const int* __restrict__ colv, int* __restrict__ cnti) {
    int e = blockIdx.x * 256 + threadIdx.x;
    if (e >= NE) return;
    int cl = colv[e];
    cl = min(max(cl, 0), NN - 1);
    atomicAdd(&cnti[cl], 1);
}

extern "C" __global__ void __launch_bounds__(1024)
k_scanA(const int* __restrict__ cnti, int* __restrict__ cur,
        int* __restrict__ bsum) {
    __shared__ int s[1024];
    int t = threadIdx.x;
    int idx = blockIdx.x * 1024 + t;
    int v = (idx < NN) ? cnti[idx] : 0;
    s[t] = v;
    __syncthreads();
#pragma unroll
    for (int off = 1; off < 1024; off <<= 1) {
        int tmp = (t >= off) ? s[t - off] : 0;
        __syncthreads();
        s[t] += tmp;
        __syncthreads();
    }
    if (idx < NN) cur[idx] = s[t] - v;
    if (t == 1023) bsum[blockIdx.x] = s[1023];
}

extern "C" __global__ void __launch_bounds__(128)
k_scanB(int* __restrict__ bsum) {
    __shared__ int s[128];
    int t = threadIdx.x;
    int v = (t < 98) ? bsum[t] : 0;
    s[t] = v;
    __syncthreads();
#pragma unroll
    for (int off = 1; off < 128; off <<= 1) {
        int tmp = (t >= off) ? s[t - off] : 0;
        __syncthreads();
        s[t] += tmp;
        __syncthreads();
    }
    if (t < 98) bsum[t] = s[t] - v;
}

extern "C" __global__ void __launch_bounds__(1024)
k_scanC(int* __restrict__ cur, const int* __restrict__ bsum) {
    int idx = blockIdx.x * 1024 + threadIdx.x;
    if (idx < NN) cur[idx] += bsum[blockIdx.x];
}

extern "C" __global__ void __launch_bounds__(256)
k_bucket(const int* __restrict__ colv, const int* __restrict__ rowv,
         int* __restrict__ cur, unsigned long long* __restrict__ ec) {
    int e = blockIdx.x * 256 + threadIdx.x;
    if (e >= NE) return;
    int cl = colv[e];
    cl = min(max(cl, 0), NN - 1);
    int r = rowv[e];
    r = min(max(r, 0), NN - 1);
    int pos = atomicAdd(&cur[cl], 1);
    ec[pos] = ((unsigned long long)(unsigned)r << 47) |
              ((unsigned long long)(unsigned)cl << 30) | (unsigned)e;
}

// K2: FUSED agg + out_pre + h projection. Wave per node, lane = channel.
// h (bf16, swizzled) is written IN PLACE into the xwr buffer: xwr row i is
// read only by node i's own wave, and the read precedes the write in
// program order -> race-free (unlike aliasing ybf, which other waves read).
// xwr_h is intentionally NOT __restrict__ (read+write same buffer).
extern "C" __global__ void __launch_bounds__(256)
k_aggoh(const unsigned long long* __restrict__ ec, const int* __restrict__ cur,
        const unsigned short* __restrict__ ybf, unsigned short* xwr_h,
        const float* __restrict__ bl, const float* __restrict__ Wg,
        const float* __restrict__ bg, const float* __restrict__ hb,
        float* __restrict__ agg) {
    __shared__ float ol[4][64];
    int w = threadIdx.x >> 6, c = threadIdx.x & 63;
    int i = blockIdx.x * 4 + w;
    if (i >= NN) return;
    int start = (i == 0) ? 0 : cur[i - 1];
    int end = cur[i];
    // read xwr BEFORE any store to the buffer
    float xwr = bf2f(xwr_h[(size_t)i * OC + c]);
    float acc = 0.0f;
    int p = start;
    for (; p + 3 < end; p += 4) {
        int r0 = (int)(ec[p + 0] >> 47);
        int r1 = (int)(ec[p + 1] >> 47);
        int r2 = (int)(ec[p + 2] >> 47);
        int r3 = (int)(ec[p + 3] >> 47);
        unsigned short u0 = ybf[(size_t)r0 * OC + c];
        unsigned short u1 = ybf[(size_t)r1 * OC + c];
        unsigned short u2 = ybf[(size_t)r2 * OC + c];
        unsigned short u3 = ybf[(size_t)r3 * OC + c];
        acc += bf2f(u0);
        acc += bf2f(u1);
        acc += bf2f(u2);
        acc += bf2f(u3);
    }
    for (; p < end; ++p) {
        int r0 = (int)(ec[p] >> 47);
        acc += bf2f(ybf[(size_t)r0 * OC + c]);
    }
    float inv = 1.0f / fmaxf((float)(end - start), 1.0f);
    float o = fmaf(acc, inv, bl[c] + xwr);
    agg[(size_t)i * OC + c] = o;
    ol[w][c] = o;
    __builtin_amdgcn_wave_barrier();  // LDS write visible to wave before reads
    // h_c = bg + hb + sum_k o[k] * Wg[k][c]
    float h0 = bg[c] + hb[c];
    float h1 = 0.0f, h2 = 0.0f, h3 = 0.0f;
#pragma unroll
    for (int k = 0; k < OC; k += 4) {
        float o0 = ol[w][k + 0], o1 = ol[w][k + 1];
        float o2 = ol[w][k + 2], o3 = ol[w][k + 3];
        h0 = fmaf(o0, Wg[(k + 0) * OC + c], h0);
        h1 = fmaf(o1, Wg[(k + 1) * OC + c], h1);
        h2 = fmaf(o2, Wg[(k + 2) * OC + c], h2);
        h3 = fmaf(o3, Wg[(k + 3) * OC + c], h3);
    }
    float h = (h0 + h1) + (h2 + h3);
    // swizzled store into the same buffer (slot (ch&15)*4 + (ch>>4))
    xwr_h[(size_t)i * OC + (c & 15) * 4 + (c >> 4)] = f2bf(h);
}

// K4-NS: MFMA gating, NO atomics: bf16 contrib per edge (nt-swizzled),
// reduced by k_csum over contiguous CSR segments.
extern "C" __global__ void __launch_bounds__(256, 3)
k_gate_ns(const unsigned long long* __restrict__ ec, const float* __restrict__ eattr,
          const unsigned short* __restrict__ WfT, const unsigned short* __restrict__ WeT,
          const float* __restrict__ be, const unsigned short* __restrict__ hswz,
          unsigned short* __restrict__ contrib) {
    int lane = threadIdx.x & 63;
    int w = threadIdx.x >> 6;
    int tb = (blockIdx.x * 4 + w) * 64;

    unsigned long long ev = ec[tb + lane];
    int e = (int)(ev & 0x3FFFFFFFULL);
    int cl = (int)((ev >> 30) & 0x1FFFFULL);
    int c = lane & 15, g = lane >> 4;

    int erow0 = __shfl(e, 0 * 16 + c);
    int erow1 = __shfl(e, 1 * 16 + c);
    int erow2 = __shfl(e, 2 * 16 + c);
    int erow3 = __shfl(e, 3 * 16 + c);
    int clx[16];
#pragma unroll
    for (int mt = 0; mt < 4; ++mt)
#pragma unroll
        for (int r = 0; r < 4; ++r)
            clx[mt * 4 + r] = __shfl(cl, mt * 16 + g * 4 + r);

    uint2 hg[16];
#pragma unroll
    for (int q = 0; q < 16; ++q)
        hg[q] = *reinterpret_cast<const uint2*>(hswz + (size_t)clx[q] * OC + c * 4);

    bf16x8 bwf[4], bwe[4];
    float bev[4];
#pragma unroll
    for (int nt = 0; nt < 4; ++nt) {
        int ch = nt * 16 + c;
        bwf[nt] = *reinterpret_cast<const bf16x8*>(WfT + ch * ED + g * 8);
        bwe[nt] = *reinterpret_cast<const bf16x8*>(WeT + ch * ED + g * 8);
        bev[nt] = be[ch];
    }

    float4 alo0 = reinterpret_cast<const float4*>(eattr + (size_t)erow0 * ED + g * 8)[0];
    float4 ahi0 = reinterpret_cast<const float4*>(eattr + (size_t)erow0 * ED + g * 8)[1];
    float4 alo1 = reinterpret_cast<const float4*>(eattr + (size_t)erow1 * ED + g * 8)[0];
    float4 ahi1 = reinterpret_cast<const float4*>(eattr + (size_t)erow1 * ED + g * 8)[1];
    float4 alo2 = reinterpret_cast<const float4*>(eattr + (size_t)erow2 * ED + g * 8)[0];
    float4 ahi2 = reinterpret_cast<const float4*>(eattr + (size_t)erow2 * ED + g * 8)[1];
    float4 alo3 = reinterpret_cast<const float4*>(eattr + (size_t)erow3 * ED + g * 8)[0];
    float4 ahi3 = reinterpret_cast<const float4*>(eattr + (size_t)erow3 * ED + g * 8)[1];

    bf16x8 afr[4];
    {
        union { bf16x8 v; unsigned d[4]; } pk;
#define PACKA(idx, lo, hi)                         \
        pk.d[0] = cvtpk(lo.x, lo.y);               \
        pk.d[1] = cvtpk(lo.z, lo.w);               \
        pk.d[2] = cvtpk(hi.x, hi.y);               \
        pk.d[3] = cvtpk(hi.z, hi.w);               \
        afr[idx] = pk.v;
        PACKA(0, alo0, ahi0)
        PACKA(1, alo1, ahi1)
        PACKA(2, alo2, ahi2)
        PACKA(3, alo3, ahi3)
#undef PACKA
    }

#pragma unroll
    for (int mt = 0; mt < 4; ++mt) {
        uint2 h0 = hg[mt * 4 + 0];
        uint2 h1 = hg[mt * 4 + 1];
        uint2 h2 = hg[mt * 4 + 2];
        uint2 h3 = hg[mt * 4 + 3];
        float sv[4][4];
#pragma unroll
        for (int nt = 0; nt < 4; ++nt) {
            f32x4 cz, ce;
            unsigned w0 = (nt < 2) ? h0.x : h0.y;
            unsigned w1 = (nt < 2) ? h1.x : h1.y;
            unsigned w2 = (nt < 2) ? h2.x : h2.y;
            unsigned w3 = (nt < 2) ? h3.x : h3.y;
            cz[0] = bf2f((unsigned short)((nt & 1) ? (w0 >> 16) : (w0 & 0xffffu)));
            cz[1] = bf2f((unsigned short)((nt & 1) ? (w1 >> 16) : (w1 & 0xffffu)));
            cz[2] = bf2f((unsigned short)((nt & 1) ? (w2 >> 16) : (w2 & 0xffffu)));
            cz[3] = bf2f((unsigned short)((nt & 1) ? (w3 >> 16) : (w3 & 0xffffu)));
            ce[0] = bev[nt]; ce[1] = bev[nt]; ce[2] = bev[nt]; ce[3] = bev[nt];
            f32x4 z  = __builtin_amdgcn_mfma_f32_16x16x32_bf16(afr[mt], bwf[nt], cz, 0, 0, 0);
            f32x4 ea = __builtin_amdgcn_mfma_f32_16x16x32_bf16(afr[mt], bwe[nt], ce, 0, 0, 0);
            sv[nt][0] = sigmoidf_(z[0]) * ea[0];
            sv[nt][1] = sigmoidf_(z[1]) * ea[1];
            sv[nt][2] = sigmoidf_(z[2]) * ea[2];
            sv[nt][3] = sigmoidf_(z[3]) * ea[3];
        }
#pragma unroll
        for (int r = 0; r < 4; ++r) {
            int row = tb + mt * 16 + g * 4 + r;
            uint2 pk;
            pk.x = cvtpk(sv[0][r], sv[1][r]);
            pk.y = cvtpk(sv[2][r], sv[3][r]);
            *reinterpret_cast<uint2*>(contrib + (size_t)row * OC + c * 4) = pk;
        }
    }
}

// K4-AT: atomic fallback (R9's proven k_gate).
extern "C" __global__ void __launch_bounds__(256, 3)
k_gate_at(const unsigned long long* __restrict__ ec, const float* __restrict__ eattr,
          const unsigned short* __restrict__ WfT, const unsigned short* __restrict__ WeT,
          const float* __restrict__ be, const unsigned short* __restrict__ hswz,
          float* __restrict__ agg) {
    int lane = threadIdx.x & 63;
    int w = threadIdx.x >> 6;
    int tb = (blockIdx.x * 4 + w) * 64;

    unsigned long long ev = ec[tb + lane];
    int e = (int)(ev & 0x3FFFFFFFULL);
    int cl = (int)((ev >> 30) & 0x1FFFFULL);
    int c = lane & 15, g = lane >> 4;

    int erow0 = __shfl(e, 0 * 16 + c);
    int erow1 = __shfl(e, 1 * 16 + c);
    int erow2 = __shfl(e, 2 * 16 + c);
    int erow3 = __shfl(e, 3 * 16 + c);
    int clx[16];
#pragma unroll
    for (int mt = 0; mt < 4; ++mt)
#pragma unroll
        for (int r = 0; r < 4; ++r)
            clx[mt * 4 + r] = __shfl(cl, mt * 16 + g * 4 + r);

    uint2 hg[16];
#pragma unroll
    for (int q = 0; q < 16; ++q)
        hg[q] = *reinterpret_cast<const uint2*>(hswz + (size_t)clx[q] * OC + c * 4);

    bf16x8 bwf[4], bwe[4];
    float bev[4];
#pragma unroll
    for (int nt = 0; nt < 4; ++nt) {
        int ch = nt * 16 + c;
        bwf[nt] = *reinterpret_cast<const bf16x8*>(WfT + ch * ED + g * 8);
        bwe[nt] = *reinterpret_cast<const bf16x8*>(WeT + ch * ED + g * 8);
        bev[nt] = be[ch];
    }

    float4 alo0 = reinterpret_cast<const float4*>(eattr + (size_t)erow0 * ED + g * 8)[0];
    float4 ahi0 = reinterpret_cast<const float4*>(eattr + (size_t)erow0 * ED + g * 8)[1];
    float4 alo1 = reinterpret_cast<const float4*>(eattr + (size_t)erow1 * ED + g * 8)[0];
    float4 ahi1 = reinterpret_cast<const float4*>(eattr + (size_t)erow1 * ED + g * 8)[1];
    float4 alo2 = reinterpret_cast<const float4*>(eattr + (size_t)erow2 * ED + g * 8)[0];
    float4 ahi2 = reinterpret_cast<const float4*>(eattr + (size_t)erow2 * ED + g * 8)[1];
    float4 alo3 = reinterpret_cast<const float4*>(eattr + (size_t)erow3 * ED + g * 8)[0];
    float4 ahi3 = reinterpret_cast<const float4*>(eattr + (size_t)erow3 * ED + g * 8)[1];

    bf16x8 afr[4];
    {
        union { bf16x8 v; unsigned d[4]; } pk;
#define PACKA(idx, lo, hi)                         \
        pk.d[0] = cvtpk(lo.x, lo.y);               \
        pk.d[1] = cvtpk(lo.z, lo.w);               \
        pk.d[2] = cvtpk(hi.x, hi.y);               \
        pk.d[3] = cvtpk(hi.z, hi.w);               \
        afr[idx] = pk.v;
        PACKA(0, alo0, ahi0)
        PACKA(1, alo1, ahi1)
        PACKA(2, alo2, ahi2)
        PACKA(3, alo3, ahi3)
#undef PACKA
    }

#pragma unroll
    for (int mt = 0; mt < 4; ++mt) {
        int cl0 = clx[mt * 4 + 0];
        int cl1 = clx[mt * 4 + 1];
        int cl2 = clx[mt * 4 + 2];
        int cl3 = clx[mt * 4 + 3];
        uint2 h0 = hg[mt * 4 + 0];
        uint2 h1 = hg[mt * 4 + 1];
        uint2 h2 = hg[mt * 4 + 2];
        uint2 h3 = hg[mt * 4 + 3];
#pragma unroll
        for (int nt = 0; nt < 4; ++nt) {
            int ch = nt * 16 + c;
            f32x4 cz, ce;
            unsigned w0 = (nt < 2) ? h0.x : h0.y;
            unsigned w1 = (nt < 2) ? h1.x : h1.y;
            unsigned w2 = (nt < 2) ? h2.x : h2.y;
            unsigned w3 = (nt < 2) ? h3.x : h3.y;
            cz[0] = bf2f((unsigned short)((nt & 1) ? (w0 >> 16) : (w0 & 0xffffu)));
            cz[1] = bf2f((unsigned short)((nt & 1) ? (w1 >> 16) : (w1 & 0xffffu)));
            cz[2] = bf2f((unsigned short)((nt & 1) ? (w2 >> 16) : (w2 & 0xffffu)));
            cz[3] = bf2f((unsigned short)((nt & 1) ? (w3 >> 16) : (w3 & 0xffffu)));
            ce[0] = bev[nt]; ce[1] = bev[nt]; ce[2] = bev[nt]; ce[3] = bev[nt];
            f32x4 z  = __builtin_amdgcn_mfma_f32_16x16x32_bf16(afr[mt], bwf[nt], cz, 0, 0, 0);
            f32x4 ea = __builtin_amdgcn_mfma_f32_16x16x32_bf16(afr[mt], bwe[nt], ce, 0, 0, 0);
            float c0 = sigmoidf_(z[0]) * ea[0];
            float c1 = sigmoidf_(z[1]) * ea[1];
            float c2 = sigmoidf_(z[2]) * ea[2];
            float c3 = sigmoidf_(z[3]) * ea[3];
            float s = c0;
            int t = cl0;
            if (cl1 != t) { atomicAdd(&agg[(size_t)t * OC + ch], s); s = 0.0f; t = cl1; }
            s += c1;
            if (cl2 != t) { atomicAdd(&agg[(size_t)t * OC + ch], s); s = 0.0f; t = cl2; }
            s += c2;
            if (cl3 != t) { atomicAdd(&agg[(size_t)t * OC + ch], s); s = 0.0f; t = cl3; }
            s += c3;
            atomicAdd(&agg[(size_t)t * OC + ch], s);
        }
    }
}

// K4b (NS only): contiguous segmented sum of contrib per node, non-atomic.
extern "C" __global__ void __launch_bounds__(256)
k_csum(const unsigned short* __restrict__ contrib, const int* __restrict__ cur,
       float* __restrict__ agg) {
    int w = threadIdx.x >> 6, c = threadIdx.x & 63;
    int i = blockIdx.x * 4 + w;
    if (i >= NN) return;
    int start = (i == 0) ? 0 : cur[i - 1];
    int end = cur[i];
    float s = 0.0f;
    int p = start;
    for (; p + 3 < end; p += 4) {
        unsigned short u0 = contrib[(size_t)(p + 0) * OC + c];
        unsigned short u1 = contrib[(size_t)(p + 1) * OC + c];
        unsigned short u2 = contrib[(size_t)(p + 2) * OC + c];
        unsigned short u3 = contrib[(size_t)(p + 3) * OC + c];
        s += bf2f(u0);
        s += bf2f(u1);
        s += bf2f(u2);
        s += bf2f(u3);
    }
    for (; p < end; ++p) s += bf2f(contrib[(size_t)p * OC + c]);
    int ch = (c >> 2) + 16 * (c & 3);
    agg[(size_t)i * OC + ch] += s;
}

// K5: BN batch stats.
extern "C" __global__ void __launch_bounds__(256)
k_stats(const float* __restrict__ a, float* __restrict__ stats) {
    __shared__ float ls[256], lq[256];
    int t = threadIdx.x;
    float s = 0.0f, q = 0.0f;
    for (size_t idx = (size_t)blockIdx.x * 256 + t; idx < (size_t)NN * OC;
         idx += (size_t)gridDim.x * 256) {
        float v = a[idx];
        s += v;
        q = fmaf(v, v, q);
    }
    ls[t] = s; lq[t] = q;
    __syncthreads();
    if (t < OC) {
        s = ls[t] + ls[t + 64] + ls[t + 128] + ls[t + 192];
        q = lq[t] + lq[t + 64] + lq[t + 128] + lq[t + 192];
        atomicAdd(&stats[t], s);
        atomicAdd(&stats[OC + t], q);
    }
}

// K6: BN normalize + residual(2x) + ReLU.
extern "C" __global__ void __launch_bounds__(256)
k_final(const float* __restrict__ a, const float* __restrict__ stats,
        const float* __restrict__ gamma, const float* __restrict__ beta,
        float* __restrict__ out) {
    size_t idx = (size_t)blockIdx.x * 256 + threadIdx.x;
    if (idx >= (size_t)NN * OC) return;
    int c = (int)(idx & 63);
    float mu = stats[c] * (1.0f / NN);
    float var = stats[OC + c] * (1.0f / NN) - mu * mu;
    float v = a[idx];
    float y = fmaf(gamma[c] * (v - mu), rsqrtf(var + 1e-5f), beta[c]);
    out[idx] = fmaxf(2.0f * y, 0.0f);
}

extern "C" void kernel_launch(void* const* d_in, const int* in_sizes, int n_in,
                              void* d_out, int out_size, void* d_ws, size_t ws_size,
                              hipStream_t stream) {
    const float* x     = (const float*)d_in[0];
    const int*   ei    = (const int*)d_in[1];   // (2, NE) int32
    const float* eattr = (const float*)d_in[2];
    const float* Wl    = (const float*)d_in[3];
    const float* bl    = (const float*)d_in[4];
    const float* Wr    = (const float*)d_in[5];
    const float* We    = (const float*)d_in[6];
    const float* be    = (const float*)d_in[7];
    const float* Wg    = (const float*)d_in[8];
    const float* bg    = (const float*)d_in[9];
    const float* gamma = (const float*)d_in[10];
    const float* beta  = (const float*)d_in[11];
    float* out = (float*)d_out;

    float* agg = (float*)d_ws;
    unsigned short* ybf   = (unsigned short*)(agg + (size_t)NN * OC);
    unsigned short* xwrbf = ybf + (size_t)NN * OC;   // becomes hswz after k_aggoh
    unsigned long long* ec = (unsigned long long*)(xwrbf + (size_t)NN * OC);
    int* cur   = (int*)(ec + (size_t)NE);
    int* bsum  = cur + NN;
    float* stats = (float*)(bsum + 128);
    unsigned short* WfT  = (unsigned short*)(stats + 128);
    unsigned short* WeT  = WfT + ED * OC;
    unsigned short* WlrT = WeT + ED * OC;
    float* hb = (float*)(WlrT + 2 * INC * OC);
    unsigned short* contrib = (unsigned short*)(hb + OC);
    unsigned short* hswz = xwrbf;  // h written in place over xwr (safe: see k_aggoh)

    size_t base_bytes = (size_t)((char*)(hb + OC) - (char*)d_ws);
    bool ns = ws_size >= base_bytes + (size_t)NE * OC * sizeof(unsigned short);

    const int* rowv = ei;
    const int* colv = ei + NE;

    hipMemsetAsync(cur, 0, NN * sizeof(int), stream);
    hipMemsetAsync(stats, 0, 2 * OC * sizeof(float), stream);

    k_wfuse<<<(2 * ED * OC + OC + 2 * INC * OC + 255) / 256, 256, 0, stream>>>(
        We, be, Wg, Wl, Wr, WfT, WeT, hb, WlrT);
    k_xw<<<(NN + 63) / 64, 256, 0, stream>>>(x, WlrT, ybf, xwrbf);
    k_hist<<<(NE + 255) / 256, 256, 0, stream>>>(colv, cur);
    k_scanA<<<98, 1024, 0, stream>>>(cur, cur, bsum);
    k_scanB<<<1, 128, 0, stream>>>(bsum);
    k_scanC<<<98, 1024, 0, stream>>>(cur, bsum);
    k_bucket<<<(NE + 255) / 256, 256, 0, stream>>>(colv, rowv, cur, ec);
    k_aggoh<<<(NN + 3) / 4, 256, 0, stream>>>(ec, cur, ybf, xwrbf, bl, Wg, bg, hb, agg);
    if (ns) {
        k_gate_ns<<<NE / 256, 256, 0, stream>>>(ec, eattr, WfT, WeT, be, hswz, contrib);
        k_csum<<<(NN + 3) / 4, 256, 0, stream>>>(contrib, cur, agg);
    } else {
        k_gate_at<<<NE / 256, 256, 0, stream>>>(ec, eattr, WfT, WeT, be, hswz, agg);
    }
    k_stats<<<2048, 256, 0, stream>>>(agg, stats);
    k_final<<<((size_t)NN * OC + 255) / 256, 256, 0, stream>>>(agg, stats, gamma, beta, out);
}

// Round 12
// 548.608 us; speedup vs baseline: 2.4911x; 1.0158x over previous
//
#include <hip/hip_runtime.h>
#include <math.h>

#define NN 100000
#define NE 1600000
#define INC 128
#define OC 64
#define ED 32

typedef __attribute__((ext_vector_type(8))) short bf16x8;
typedef __attribute__((ext_vector_type(4))) float f32x4;

__device__ __forceinline__ float sigmoidf_(float z) {
    return __builtin_amdgcn_rcpf(1.0f + __expf(-z));
}

__device__ __forceinline__ unsigned short f2bf(float x) {
    unsigned int u = __float_as_uint(x);
    unsigned int r = u + 0x7FFFu + ((u >> 16) & 1u);
    return (unsigned short)(r >> 16);
}
__device__ __forceinline__ float bf2f(unsigned short u) {
    return __uint_as_float((unsigned int)u << 16);
}
__device__ __forceinline__ unsigned cvtpk(float lo, float hi) {
    unsigned r;
    asm("v_cvt_pk_bf16_f32 %0, %1, %2" : "=v"(r) : "v"(lo), "v"(hi));
    return r;
}

// K0: weight prep.
extern "C" __global__ void __launch_bounds__(256)
k_wfuse(const float* __restrict__ We, const float* __restrict__ be,
        const float* __restrict__ Wg, const float* __restrict__ Wl,
        const float* __restrict__ Wr, unsigned short* __restrict__ WfT,
        unsigned short* __restrict__ WeT, float* __restrict__ hb,
        unsigned short* __restrict__ WlrT) {
    int idx = blockIdx.x * 256 + threadIdx.x;
    if (idx < ED * OC) {
        int ch = idx >> 5, d = idx & 31;
        float acc = 0.0f;
#pragma unroll
        for (int k = 0; k < OC; ++k)
            acc = fmaf(We[d * OC + k], Wg[(OC + k) * OC + ch], acc);
        WfT[idx] = f2bf(acc);
    } else if (idx < 2 * ED * OC) {
        int i2 = idx - ED * OC;
        int ch = i2 >> 5, d = i2 & 31;
        WeT[i2] = f2bf(We[d * OC + ch]);
    } else if (idx < 2 * ED * OC + OC) {
        int j = idx - 2 * ED * OC;
        float acc = 0.0f;
#pragma unroll
        for (int k = 0; k < OC; ++k)
            acc = fmaf(be[k], Wg[(OC + k) * OC + j], acc);
        hb[j] = acc;
    } else if (idx < 2 * ED * OC + OC + 2 * INC * OC) {
        int i3 = idx - (2 * ED * OC + OC);
        int ch = i3 >> 7, k = i3 & 127;
        float v = (ch < OC) ? Wl[k * OC + ch] : Wr[k * OC + (ch - OC)];
        WlrT[i3] = f2bf(v);
    }
}

// K1: MFMA GEMM [yl | xwr](bf16) = x @ [Wl | Wr], with the target-node
// HISTOGRAM fused in: each thread fires 4 edge atomicAdds at kernel start
// (fire-and-forget, no result wait) which complete under the GEMM.
// Thread coverage: 1563 blocks * 256 * 4 = 1,600,512 >= NE.
extern "C" __global__ void __launch_bounds__(256)
k_xw(const float* __restrict__ x, const unsigned short* __restrict__ WlrT,
     unsigned short* __restrict__ ybf, unsigned short* __restrict__ xwrbf,
     const int* __restrict__ colv, int* __restrict__ cnti) {
    int t = threadIdx.x;
    {
        int eb = (blockIdx.x * 256 + t) * 4;
        if (eb + 3 < NE) {
            int4 cv = *reinterpret_cast<const int4*>(colv + eb);
            int c0 = min(max(cv.x, 0), NN - 1);
            int c1 = min(max(cv.y, 0), NN - 1);
            int c2 = min(max(cv.z, 0), NN - 1);
            int c3 = min(max(cv.w, 0), NN - 1);
            atomicAdd(&cnti[c0], 1);
            atomicAdd(&cnti[c1], 1);
            atomicAdd(&cnti[c2], 1);
            atomicAdd(&cnti[c3], 1);
        }
    }

    __shared__ unsigned short xs[64][136];
    int base = blockIdx.x * 64;
    {
        int rr = t >> 2, cc = (t & 3) * 32;
        int grow = base + rr;
        if (grow < NN) {
            const float4* xp = reinterpret_cast<const float4*>(
                x + (size_t)grow * INC + cc);
#pragma unroll
            for (int q = 0; q < 8; ++q) {
                float4 v = xp[q];
                uint2 uv;
                uv.x = cvtpk(v.x, v.y);
                uv.y = cvtpk(v.z, v.w);
                *reinterpret_cast<uint2*>(&xs[rr][cc + q * 4]) = uv;
            }
        } else {
#pragma unroll
            for (int q = 0; q < 8; ++q) {
                uint2 uv; uv.x = 0u; uv.y = 0u;
                *reinterpret_cast<uint2*>(&xs[rr][cc + q * 4]) = uv;
            }
        }
    }
    __syncthreads();

    int lane = t & 63, w = t >> 6;
    int c = lane & 15, g = lane >> 4;

    bf16x8 bw0[4], bw1[4];
#pragma unroll
    for (int kk = 0; kk < 4; ++kk) {
        bw0[kk] = *reinterpret_cast<const bf16x8*>(
            WlrT + (w * 32 + 0 * 16 + c) * INC + kk * 32 + g * 8);
        bw1[kk] = *reinterpret_cast<const bf16x8*>(
            WlrT + (w * 32 + 1 * 16 + c) * INC + kk * 32 + g * 8);
    }

    f32x4 acc[4][2];
#pragma unroll
    for (int mt = 0; mt < 4; ++mt)
#pragma unroll
        for (int nt = 0; nt < 2; ++nt)
            acc[mt][nt] = (f32x4){0.0f, 0.0f, 0.0f, 0.0f};

#pragma unroll
    for (int kk = 0; kk < 4; ++kk) {
        bf16x8 a0 = *reinterpret_cast<const bf16x8*>(&xs[0 * 16 + c][kk * 32 + g * 8]);
        bf16x8 a1 = *reinterpret_cast<const bf16x8*>(&xs[1 * 16 + c][kk * 32 + g * 8]);
        bf16x8 a2 = *reinterpret_cast<const bf16x8*>(&xs[2 * 16 + c][kk * 32 + g * 8]);
        bf16x8 a3 = *reinterpret_cast<const bf16x8*>(&xs[3 * 16 + c][kk * 32 + g * 8]);
        acc[0][0] = __builtin_amdgcn_mfma_f32_16x16x32_bf16(a0, bw0[kk], acc[0][0], 0, 0, 0);
        acc[0][1] = __builtin_amdgcn_mfma_f32_16x16x32_bf16(a0, bw1[kk], acc[0][1], 0, 0, 0);
        acc[1][0] = __builtin_amdgcn_mfma_f32_16x16x32_bf16(a1, bw0[kk], acc[1][0], 0, 0, 0);
        acc[1][1] = __builtin_amdgcn_mfma_f32_16x16x32_bf16(a1, bw1[kk], acc[1][1], 0, 0, 0);
        acc[2][0] = __builtin_amdgcn_mfma_f32_16x16x32_bf16(a2, bw0[kk], acc[2][0], 0, 0, 0);
        acc[2][1] = __builtin_amdgcn_mfma_f32_16x16x32_bf16(a2, bw1[kk], acc[2][1], 0, 0, 0);
        acc[3][0] = __builtin_amdgcn_mfma_f32_16x16x32_bf16(a3, bw0[kk], acc[3][0], 0, 0, 0);
        acc[3][1] = __builtin_amdgcn_mfma_f32_16x16x32_bf16(a3, bw1[kk], acc[3][1], 0, 0, 0);
    }

#pragma unroll
    for (int mt = 0; mt < 4; ++mt) {
#pragma unroll
        for (int nt = 0; nt < 2; ++nt) {
            int ch = w * 32 + nt * 16 + c;
#pragma unroll
            for (int j = 0; j < 4; ++j) {
                int row = base + mt * 16 + g * 4 + j;
                if (row < NN) {
                    unsigned short vb = f2bf(acc[mt][nt][j]);
                    if (ch < OC) ybf[(size_t)row * OC + ch] = vb;
                    else         xwrbf[(size_t)row * OC + (ch - OC)] = vb;
                }
            }
        }
    }
}

extern "C" __global__ void __launch_bounds__(1024)
k_scanA(const int* __restrict__ cnti, int* __restrict__ cur,
        int* __restrict__ bsum) {
    __shared__ int s[1024];
    int t = threadIdx.x;
    int idx = blockIdx.x * 1024 + t;
    int v = (idx < NN) ? cnti[idx] : 0;
    s[t] = v;
    __syncthreads();
#pragma unroll
    for (int off = 1; off < 1024; off <<= 1) {
        int tmp = (t >= off) ? s[t - off] : 0;
        __syncthreads();
        s[t] += tmp;
        __syncthreads();
    }
    if (idx < NN) cur[idx] = s[t] - v;
    if (t == 1023) bsum[blockIdx.x] = s[1023];
}

extern "C" __global__ void __launch_bounds__(128)
k_scanB(int* __restrict__ bsum) {
    __shared__ int s[128];
    int t = threadIdx.x;
    int v = (t < 98) ? bsum[t] : 0;
    s[t] = v;
    __syncthreads();
#pragma unroll
    for (int off = 1; off < 128; off <<= 1) {
        int tmp = (t >= off) ? s[t - off] : 0;
        __syncthreads();
        s[t] += tmp;
        __syncthreads();
    }
    if (t < 98) bsum[t] = s[t] - v;
}

extern "C" __global__ void __launch_bounds__(1024)
k_scanC(int* __restrict__ cur, const int* __restrict__ bsum) {
    int idx = blockIdx.x * 1024 + threadIdx.x;
    if (idx < NN) cur[idx] += bsum[blockIdx.x];
}

// CSR bucket, 4 edges/thread: coalesced int4 col/row loads, 4 independent
// atomicAdd->store chains in flight per lane (R11 had MLP=1, VALUBusy 0.5%).
extern "C" __global__ void __launch_bounds__(256)
k_bucket(const int* __restrict__ colv, const int* __restrict__ rowv,
         int* __restrict__ cur, unsigned long long* __restrict__ ec) {
    int eb = (blockIdx.x * 256 + threadIdx.x) * 4;
    if (eb >= NE) return;  // NE % 4 == 0: full int4 groups only
    int4 cv = *reinterpret_cast<const int4*>(colv + eb);
    int4 rv = *reinterpret_cast<const int4*>(rowv + eb);
    int c0 = min(max(cv.x, 0), NN - 1), r0 = min(max(rv.x, 0), NN - 1);
    int c1 = min(max(cv.y, 0), NN - 1), r1 = min(max(rv.y, 0), NN - 1);
    int c2 = min(max(cv.z, 0), NN - 1), r2 = min(max(rv.z, 0), NN - 1);
    int c3 = min(max(cv.w, 0), NN - 1), r3 = min(max(rv.w, 0), NN - 1);
    int p0 = atomicAdd(&cur[c0], 1);
    int p1 = atomicAdd(&cur[c1], 1);
    int p2 = atomicAdd(&cur[c2], 1);
    int p3 = atomicAdd(&cur[c3], 1);
    ec[p0] = ((unsigned long long)(unsigned)r0 << 47) |
             ((unsigned long long)(unsigned)c0 << 30) | (unsigned)(eb + 0);
    ec[p1] = ((unsigned long long)(unsigned)r1 << 47) |
             ((unsigned long long)(unsigned)c1 << 30) | (unsigned)(eb + 1);
    ec[p2] = ((unsigned long long)(unsigned)r2 << 47) |
             ((unsigned long long)(unsigned)c2 << 30) | (unsigned)(eb + 2);
    ec[p3] = ((unsigned long long)(unsigned)r3 << 47) |
             ((unsigned long long)(unsigned)c3 << 30) | (unsigned)(eb + 3);
}

// K2: FUSED agg + out_pre + h projection (unroll 8 gathers).
extern "C" __global__ void __launch_bounds__(256)
k_aggoh(const unsigned long long* __restrict__ ec, const int* __restrict__ cur,
        const unsigned short* __restrict__ ybf, unsigned short* xwr_h,
        const float* __restrict__ bl, const float* __restrict__ Wg,
        const float* __restrict__ bg, const float* __restrict__ hb,
        float* __restrict__ agg) {
    __shared__ float ol[4][64];
    int w = threadIdx.x >> 6, c = threadIdx.x & 63;
    int i = blockIdx.x * 4 + w;
    if (i >= NN) return;
    int start = (i == 0) ? 0 : cur[i - 1];
    int end = cur[i];
    float xwr = bf2f(xwr_h[(size_t)i * OC + c]);  // read before any write
    float acc = 0.0f;
    int p = start;
    for (; p + 7 < end; p += 8) {
        int r0 = (int)(ec[p + 0] >> 47);
        int r1 = (int)(ec[p + 1] >> 47);
        int r2 = (int)(ec[p + 2] >> 47);
        int r3 = (int)(ec[p + 3] >> 47);
        int r4 = (int)(ec[p + 4] >> 47);
        int r5 = (int)(ec[p + 5] >> 47);
        int r6 = (int)(ec[p + 6] >> 47);
        int r7 = (int)(ec[p + 7] >> 47);
        unsigned short u0 = ybf[(size_t)r0 * OC + c];
        unsigned short u1 = ybf[(size_t)r1 * OC + c];
        unsigned short u2 = ybf[(size_t)r2 * OC + c];
        unsigned short u3 = ybf[(size_t)r3 * OC + c];
        unsigned short u4 = ybf[(size_t)r4 * OC + c];
        unsigned short u5 = ybf[(size_t)r5 * OC + c];
        unsigned short u6 = ybf[(size_t)r6 * OC + c];
        unsigned short u7 = ybf[(size_t)r7 * OC + c];
        acc += bf2f(u0); acc += bf2f(u1); acc += bf2f(u2); acc += bf2f(u3);
        acc += bf2f(u4); acc += bf2f(u5); acc += bf2f(u6); acc += bf2f(u7);
    }
    for (; p < end; ++p) {
        int r0 = (int)(ec[p] >> 47);
        acc += bf2f(ybf[(size_t)r0 * OC + c]);
    }
    float inv = 1.0f / fmaxf((float)(end - start), 1.0f);
    float o = fmaf(acc, inv, bl[c] + xwr);
    agg[(size_t)i * OC + c] = o;
    ol[w][c] = o;
    __builtin_amdgcn_wave_barrier();
    float h0 = bg[c] + hb[c];
    float h1 = 0.0f, h2 = 0.0f, h3 = 0.0f;
#pragma unroll
    for (int k = 0; k < OC; k += 4) {
        float o0 = ol[w][k + 0], o1 = ol[w][k + 1];
        float o2 = ol[w][k + 2], o3 = ol[w][k + 3];
        h0 = fmaf(o0, Wg[(k + 0) * OC + c], h0);
        h1 = fmaf(o1, Wg[(k + 1) * OC + c], h1);
        h2 = fmaf(o2, Wg[(k + 2) * OC + c], h2);
        h3 = fmaf(o3, Wg[(k + 3) * OC + c], h3);
    }
    float h = (h0 + h1) + (h2 + h3);
    xwr_h[(size_t)i * OC + (c & 15) * 4 + (c >> 4)] = f2bf(h);
}

// K4-NS: MFMA gating, NO atomics (as R11).
extern "C" __global__ void __launch_bounds__(256, 3)
k_gate_ns(const unsigned long long* __restrict__ ec, const float* __restrict__ eattr,
          const unsigned short* __restrict__ WfT, const unsigned short* __restrict__ WeT,
          const float* __restrict__ be, const unsigned short* __restrict__ hswz,
          unsigned short* __restrict__ contrib) {
    int lane = threadIdx.x & 63;
    int w = threadIdx.x >> 6;
    int tb = (blockIdx.x * 4 + w) * 64;

    unsigned long long ev = ec[tb + lane];
    int e = (int)(ev & 0x3FFFFFFFULL);
    int cl = (int)((ev >> 30) & 0x1FFFFULL);
    int c = lane & 15, g = lane >> 4;

    int erow0 = __shfl(e, 0 * 16 + c);
    int erow1 = __shfl(e, 1 * 16 + c);
    int erow2 = __shfl(e, 2 * 16 + c);
    int erow3 = __shfl(e, 3 * 16 + c);
    int clx[16];
#pragma unroll
    for (int mt = 0; mt < 4; ++mt)
#pragma unroll
        for (int r = 0; r < 4; ++r)
            clx[mt * 4 + r] = __shfl(cl, mt * 16 + g * 4 + r);

    uint2 hg[16];
#pragma unroll
    for (int q = 0; q < 16; ++q)
        hg[q] = *reinterpret_cast<const uint2*>(hswz + (size_t)clx[q] * OC + c * 4);

    bf16x8 bwf[4], bwe[4];
    float bev[4];
#pragma unroll
    for (int nt = 0; nt < 4; ++nt) {
        int ch = nt * 16 + c;
        bwf[nt] = *reinterpret_cast<const bf16x8*>(WfT + ch * ED + g * 8);
        bwe[nt] = *reinterpret_cast<const bf16x8*>(WeT + ch * ED + g * 8);
        bev[nt] = be[ch];
    }

    float4 alo0 = reinterpret_cast<const float4*>(eattr + (size_t)erow0 * ED + g * 8)[0];
    float4 ahi0 = reinterpret_cast<const float4*>(eattr + (size_t)erow0 * ED + g * 8)[1];
    float4 alo1 = reinterpret_cast<const float4*>(eattr + (size_t)erow1 * ED + g * 8)[0];
    float4 ahi1 = reinterpret_cast<const float4*>(eattr + (size_t)erow1 * ED + g * 8)[1];
    float4 alo2 = reinterpret_cast<const float4*>(eattr + (size_t)erow2 * ED + g * 8)[0];
    float4 ahi2 = reinterpret_cast<const float4*>(eattr + (size_t)erow2 * ED + g * 8)[1];
    float4 alo3 = reinterpret_cast<const float4*>(eattr + (size_t)erow3 * ED + g * 8)[0];
    float4 ahi3 = reinterpret_cast<const float4*>(eattr + (size_t)erow3 * ED + g * 8)[1];

    bf16x8 afr[4];
    {
        union { bf16x8 v; unsigned d[4]; } pk;
#define PACKA(idx, lo, hi)                         \
        pk.d[0] = cvtpk(lo.x, lo.y);               \
        pk.d[1] = cvtpk(lo.z, lo.w);               \
        pk.d[2] = cvtpk(hi.x, hi.y);               \
        pk.d[3] = cvtpk(hi.z, hi.w);               \
        afr[idx] = pk.v;
        PACKA(0, alo0, ahi0)
        PACKA(1, alo1, ahi1)
        PACKA(2, alo2, ahi2)
        PACKA(3, alo3, ahi3)
#undef PACKA
    }

#pragma unroll
    for (int mt = 0; mt < 4; ++mt) {
        uint2 h0 = hg[mt * 4 + 0];
        uint2 h1 = hg[mt * 4 + 1];
        uint2 h2 = hg[mt * 4 + 2];
        uint2 h3 = hg[mt * 4 + 3];
        float sv[4][4];
#pragma unroll
        for (int nt = 0; nt < 4; ++nt) {
            f32x4 cz, ce;
            unsigned w0 = (nt < 2) ? h0.x : h0.y;
            unsigned w1 = (nt < 2) ? h1.x : h1.y;
            unsigned w2 = (nt < 2) ? h2.x : h2.y;
            unsigned w3 = (nt < 2) ? h3.x : h3.y;
            cz[0] = bf2f((unsigned short)((nt & 1) ? (w0 >> 16) : (w0 & 0xffffu)));
            cz[1] = bf2f((unsigned short)((nt & 1) ? (w1 >> 16) : (w1 & 0xffffu)));
            cz[2] = bf2f((unsigned short)((nt & 1) ? (w2 >> 16) : (w2 & 0xffffu)));
            cz[3] = bf2f((unsigned short)((nt & 1) ? (w3 >> 16) : (w3 & 0xffffu)));
            ce[0] = bev[nt]; ce[1] = bev[nt]; ce[2] = bev[nt]; ce[3] = bev[nt];
            f32x4 z  = __builtin_amdgcn_mfma_f32_16x16x32_bf16(afr[mt], bwf[nt], cz, 0, 0, 0);
            f32x4 ea = __builtin_amdgcn_mfma_f32_16x16x32_bf16(afr[mt], bwe[nt], ce, 0, 0, 0);
            sv[nt][0] = sigmoidf_(z[0]) * ea[0];
            sv[nt][1] = sigmoidf_(z[1]) * ea[1];
            sv[nt][2] = sigmoidf_(z[2]) * ea[2];
            sv[nt][3] = sigmoidf_(z[3]) * ea[3];
        }
#pragma unroll
        for (int r = 0; r < 4; ++r) {
            int row = tb + mt * 16 + g * 4 + r;
            uint2 pk;
            pk.x = cvtpk(sv[0][r], sv[1][r]);
            pk.y = cvtpk(sv[2][r], sv[3][r]);
            *reinterpret_cast<uint2*>(contrib + (size_t)row * OC + c * 4) = pk;
        }
    }
}

// K4-AT: atomic fallback (R9's proven k_gate).
extern "C" __global__ void __launch_bounds__(256, 3)
k_gate_at(const unsigned long long* __restrict__ ec, const float* __restrict__ eattr,
          const unsigned short* __restrict__ WfT, const unsigned short* __restrict__ WeT,
          const float* __restrict__ be, const unsigned short* __restrict__ hswz,
          float* __restrict__ agg) {
    int lane = threadIdx.x & 63;
    int w = threadIdx.x >> 6;
    int tb = (blockIdx.x * 4 + w) * 64;

    unsigned long long ev = ec[tb + lane];
    int e = (int)(ev & 0x3FFFFFFFULL);
    int cl = (int)((ev >> 30) & 0x1FFFFULL);
    int c = lane & 15, g = lane >> 4;

    int erow0 = __shfl(e, 0 * 16 + c);
    int erow1 = __shfl(e, 1 * 16 + c);
    int erow2 = __shfl(e, 2 * 16 + c);
    int erow3 = __shfl(e, 3 * 16 + c);
    int clx[16];
#pragma unroll
    for (int mt = 0; mt < 4; ++mt)
#pragma unroll
        for (int r = 0; r < 4; ++r)
            clx[mt * 4 + r] = __shfl(cl, mt * 16 + g * 4 + r);

    uint2 hg[16];
#pragma unroll
    for (int q = 0; q < 16; ++q)
        hg[q] = *reinterpret_cast<const uint2*>(hswz + (size_t)clx[q] * OC + c * 4);

    bf16x8 bwf[4], bwe[4];
    float bev[4];
#pragma unroll
    for (int nt = 0; nt < 4; ++nt) {
        int ch = nt * 16 + c;
        bwf[nt] = *reinterpret_cast<const bf16x8*>(WfT + ch * ED + g * 8);
        bwe[nt] = *reinterpret_cast<const bf16x8*>(WeT + ch * ED + g * 8);
        bev[nt] = be[ch];
    }

    float4 alo0 = reinterpret_cast<const float4*>(eattr + (size_t)erow0 * ED + g * 8)[0];
    float4 ahi0 = reinterpret_cast<const float4*>(eattr + (size_t)erow0 * ED + g * 8)[1];
    float4 alo1 = reinterpret_cast<const float4*>(eattr + (size_t)erow1 * ED + g * 8)[0];
    float4 ahi1 = reinterpret_cast<const float4*>(eattr + (size_t)erow1 * ED + g * 8)[1];
    float4 alo2 = reinterpret_cast<const float4*>(eattr + (size_t)erow2 * ED + g * 8)[0];
    float4 ahi2 = reinterpret_cast<const float4*>(eattr + (size_t)erow2 * ED + g * 8)[1];
    float4 alo3 = reinterpret_cast<const float4*>(eattr + (size_t)erow3 * ED + g * 8)[0];
    float4 ahi3 = reinterpret_cast<const float4*>(eattr + (size_t)erow3 * ED + g * 8)[1];

    bf16x8 afr[4];
    {
        union { bf16x8 v; unsigned d[4]; } pk;
#define PACKA(idx, lo, hi)                         \
        pk.d[0] = cvtpk(lo.x, lo.y);               \
        pk.d[1] = cvtpk(lo.z, lo.w);               \
        pk.d[2] = cvtpk(hi.x, hi.y);               \
        pk.d[3] = cvtpk(hi.z, hi.w);               \
        afr[idx] = pk.v;
        PACKA(0, alo0, ahi0)
        PACKA(1, alo1, ahi1)
        PACKA(2, alo2, ahi2)
        PACKA(3, alo3, ahi3)
#undef PACKA
    }

#pragma unroll
    for (int mt = 0; mt < 4; ++mt) {
        int cl0 = clx[mt * 4 + 0];
        int cl1 = clx[mt * 4 + 1];
        int cl2 = clx[mt * 4 + 2];
        int cl3 = clx[mt * 4 + 3];
        uint2 h0 = hg[mt * 4 + 0];
        uint2 h1 = hg[mt * 4 + 1];
        uint2 h2 = hg[mt * 4 + 2];
        uint2 h3 = hg[mt * 4 + 3];
#pragma unroll
        for (int nt = 0; nt < 4; ++nt) {
            int ch = nt * 16 + c;
            f32x4 cz, ce;
            unsigned w0 = (nt < 2) ? h0.x : h0.y;
            unsigned w1 = (nt < 2) ? h1.x : h1.y;
            unsigned w2 = (nt < 2) ? h2.x : h2.y;
            unsigned w3 = (nt < 2) ? h3.x : h3.y;
            cz[0] = bf2f((unsigned short)((nt & 1) ? (w0 >> 16) : (w0 & 0xffffu)));
            cz[1] = bf2f((unsigned short)((nt & 1) ? (w1 >> 16) : (w1 & 0xffffu)));
            cz[2] = bf2f((unsigned short)((nt & 1) ? (w2 >> 16) : (w2 & 0xffffu)));
            cz[3] = bf2f((unsigned short)((nt & 1) ? (w3 >> 16) : (w3 & 0xffffu)));
            ce[0] = bev[nt]; ce[1] = bev[nt]; ce[2] = bev[nt]; ce[3] = bev[nt];
            f32x4 z  = __builtin_amdgcn_mfma_f32_16x16x32_bf16(afr[mt], bwf[nt], cz, 0, 0, 0);
            f32x4 ea = __builtin_amdgcn_mfma_f32_16x16x32_bf16(afr[mt], bwe[nt], ce, 0, 0, 0);
            float c0 = sigmoidf_(z[0]) * ea[0];
            float c1 = sigmoidf_(z[1]) * ea[1];
            float c2 = sigmoidf_(z[2]) * ea[2];
            float c3 = sigmoidf_(z[3]) * ea[3];
            float s = c0;
            int t = cl0;
            if (cl1 != t) { atomicAdd(&agg[(size_t)t * OC + ch], s); s = 0.0f; t = cl1; }
            s += c1;
            if (cl2 != t) { atomicAdd(&agg[(size_t)t * OC + ch], s); s = 0.0f; t = cl2; }
            s += c2;
            if (cl3 != t) { atomicAdd(&agg[(size_t)t * OC + ch], s); s = 0.0f; t = cl3; }
            s += c3;
            atomicAdd(&agg[(size_t)t * OC + ch], s);
        }
    }
}

// K4b (NS): segmented sum of contrib + FUSED BN stats. Grid-stride 2048
// blocks (keeps the per-address stats atomic count at k_stats levels);
// per-thread v/v^2 accumulated across nodes, one block reduce at end.
extern "C" __global__ void __launch_bounds__(256)
k_csumst(const unsigned short* __restrict__ contrib, const int* __restrict__ cur,
         float* __restrict__ agg, float* __restrict__ stats) {
    __shared__ float ls[256], lq[256];
    int w = threadIdx.x >> 6, c = threadIdx.x & 63;
    int ch = (c >> 2) + 16 * (c & 3);
    float sv = 0.0f, sq = 0.0f;
    for (int i = blockIdx.x * 4 + w; i < NN; i += 2048 * 4) {
        int start = (i == 0) ? 0 : cur[i - 1];
        int end = cur[i];
        float s = 0.0f;
        int p = start;
        for (; p + 7 < end; p += 8) {
            unsigned short u0 = contrib[(size_t)(p + 0) * OC + c];
            unsigned short u1 = contrib[(size_t)(p + 1) * OC + c];
            unsigned short u2 = contrib[(size_t)(p + 2) * OC + c];
            unsigned short u3 = contrib[(size_t)(p + 3) * OC + c];
            unsigned short u4 = contrib[(size_t)(p + 4) * OC + c];
            unsigned short u5 = contrib[(size_t)(p + 5) * OC + c];
            unsigned short u6 = contrib[(size_t)(p + 6) * OC + c];
            unsigned short u7 = contrib[(size_t)(p + 7) * OC + c];
            s += bf2f(u0); s += bf2f(u1); s += bf2f(u2); s += bf2f(u3);
            s += bf2f(u4); s += bf2f(u5); s += bf2f(u6); s += bf2f(u7);
        }
        for (; p < end; ++p) s += bf2f(contrib[(size_t)p * OC + c]);
        float v = agg[(size_t)i * OC + ch] + s;
        agg[(size_t)i * OC + ch] = v;
        sv += v;
        sq = fmaf(v, v, sq);
    }
    ls[threadIdx.x] = sv;
    lq[threadIdx.x] = sq;
    __syncthreads();
    if (threadIdx.x < 64) {
        float a = ls[c] + ls[c + 64] + ls[c + 128] + ls[c + 192];
        float b = lq[c] + lq[c + 64] + lq[c + 128] + lq[c + 192];
        atomicAdd(&stats[ch], a);
        atomicAdd(&stats[OC + ch], b);
    }
}

// K5: BN batch stats (AT path only).
extern "C" __global__ void __launch_bounds__(256)
k_stats(const float* __restrict__ a, float* __restrict__ stats) {
    __shared__ float ls[256], lq[256];
    int t = threadIdx.x;
    float s = 0.0f, q = 0.0f;
    for (size_t idx = (size_t)blockIdx.x * 256 + t; idx < (size_t)NN * OC;
         idx += (size_t)gridDim.x * 256) {
        float v = a[idx];
        s += v;
        q = fmaf(v, v, q);
    }
    ls[t] = s; lq[t] = q;
    __syncthreads();
    if (t < OC) {
        s = ls[t] + ls[t + 64] + ls[t + 128] + ls[t + 192];
        q = lq[t] + lq[t + 64] + lq[t + 128] + lq[t + 192];
        atomicAdd(&stats[t], s);
        atomicAdd(&stats[OC + t], q);
    }
}

// K6: BN normalize + residual(2x) + ReLU.
extern "C" __global__ void __launch_bounds__(256)
k_final(const float* __restrict__ a, const float* __restrict__ stats,
        const float* __restrict__ gamma, const float* __restrict__ beta,
        float* __restrict__ out) {
    size_t idx = (size_t)blockIdx.x * 256 + threadIdx.x;
    if (idx >= (size_t)NN * OC) return;
    int c = (int)(idx & 63);
    float mu = stats[c] * (1.0f / NN);
    float var = stats[OC + c] * (1.0f / NN) - mu * mu;
    float v = a[idx];
    float y = fmaf(gamma[c] * (v - mu), rsqrtf(var + 1e-5f), beta[c]);
    out[idx] = fmaxf(2.0f * y, 0.0f);
}

extern "C" void kernel_launch(void* const* d_in, const int* in_sizes, int n_in,
                              void* d_out, int out_size, void* d_ws, size_t ws_size,
                              hipStream_t stream) {
    const float* x     = (const float*)d_in[0];
    const int*   ei    = (const int*)d_in[1];   // (2, NE) int32
    const float* eattr = (const float*)d_in[2];
    const float* Wl    = (const float*)d_in[3];
    const float* bl    = (const float*)d_in[4];
    const float* Wr    = (const float*)d_in[5];
    const float* We    = (const float*)d_in[6];
    const float* be    = (const float*)d_in[7];
    const float* Wg    = (const float*)d_in[8];
    const float* bg    = (const float*)d_in[9];
    const float* gamma = (const float*)d_in[10];
    const float* beta  = (const float*)d_in[11];
    float* out = (float*)d_out;

    float* agg = (float*)d_ws;
    unsigned short* ybf   = (unsigned short*)(agg + (size_t)NN * OC);
    unsigned short* xwrbf = ybf + (size_t)NN * OC;   // becomes hswz after k_aggoh
    unsigned long long* ec = (unsigned long long*)(xwrbf + (size_t)NN * OC);
    int* cur   = (int*)(ec + (size_t)NE);
    int* bsum  = cur + NN;
    float* stats = (float*)(bsum + 128);
    unsigned short* WfT  = (unsigned short*)(stats + 128);
    unsigned short* WeT  = WfT + ED * OC;
    unsigned short* WlrT = WeT + ED * OC;
    float* hb = (float*)(WlrT + 2 * INC * OC);
    unsigned short* contrib = (unsigned short*)(hb + OC);
    unsigned short* hswz = xwrbf;

    size_t base_bytes = (size_t)((char*)(hb + OC) - (char*)d_ws);
    bool ns = ws_size >= base_bytes + (size_t)NE * OC * sizeof(unsigned short);

    const int* rowv = ei;
    const int* colv = ei + NE;

    hipMemsetAsync(cur, 0, NN * sizeof(int), stream);
    hipMemsetAsync(stats, 0, 2 * OC * sizeof(float), stream);

    k_wfuse<<<(2 * ED * OC + OC + 2 * INC * OC + 255) / 256, 256, 0, stream>>>(
        We, be, Wg, Wl, Wr, WfT, WeT, hb, WlrT);
    k_xw<<<(NN + 63) / 64, 256, 0, stream>>>(x, WlrT, ybf, xwrbf, colv, cur);
    k_scanA<<<98, 1024, 0, stream>>>(cur, cur, bsum);
    k_scanB<<<1, 128, 0, stream>>>(bsum);
    k_scanC<<<98, 1024, 0, stream>>>(cur, bsum);
    k_bucket<<<(NE / 4 + 255) / 256, 256, 0, stream>>>(colv, rowv, cur, ec);
    k_aggoh<<<(NN + 3) / 4, 256, 0, stream>>>(ec, cur, ybf, xwrbf, bl, Wg, bg, hb, agg);
    if (ns) {
        k_gate_ns<<<NE / 256, 256, 0, stream>>>(ec, eattr, WfT, WeT, be, hswz, contrib);
        k_csumst<<<2048, 256, 0, stream>>>(contrib, cur, agg, stats);
    } else {
        k_gate_at<<<NE / 256, 256, 0, stream>>>(ec, eattr, WfT, WeT, be, hswz, agg);
        k_stats<<<2048, 256, 0, stream>>>(agg, stats);
    }
    k_final<<<((size_t)NN * OC + 255) / 256, 256, 0, stream>>>(agg, stats, gamma, beta, out);
}

// Round 14
// 471.633 us; speedup vs baseline: 2.8977x; 1.1632x over previous
//
#include <hip/hip_runtime.h>
#include <math.h>

#define NN 100000
#define NE 1600000
#define INC 128
#define OC 64
#define ED 32

typedef __attribute__((ext_vector_type(8))) short bf16x8;
typedef __attribute__((ext_vector_type(4))) float f32x4;

__device__ __forceinline__ float sigmoidf_(float z) {
    return __builtin_amdgcn_rcpf(1.0f + __expf(-z));
}

__device__ __forceinline__ unsigned short f2bf(float x) {
    unsigned int u = __float_as_uint(x);
    unsigned int r = u + 0x7FFFu + ((u >> 16) & 1u);
    return (unsigned short)(r >> 16);
}
__device__ __forceinline__ float bf2f(unsigned short u) {
    return __uint_as_float((unsigned int)u << 16);
}
__device__ __forceinline__ unsigned cvtpk(float lo, float hi) {
    unsigned r;
    asm("v_cvt_pk_bf16_f32 %0, %1, %2" : "=v"(r) : "v"(lo), "v"(hi));
    return r;
}

__device__ __forceinline__ unsigned long long pack_ec(int r, int cl, int e) {
    return ((unsigned long long)(unsigned)r << 47) |
           ((unsigned long long)(unsigned)cl << 30) | (unsigned)e;
}

// K0: weight prep.
extern "C" __global__ void __launch_bounds__(256)
k_wfuse(const float* __restrict__ We, const float* __restrict__ be,
        const float* __restrict__ Wg, const float* __restrict__ Wl,
        const float* __restrict__ Wr, unsigned short* __restrict__ WfT,
        unsigned short* __restrict__ WeT, float* __restrict__ hb,
        unsigned short* __restrict__ WlrT) {
    int idx = blockIdx.x * 256 + threadIdx.x;
    if (idx < ED * OC) {
        int ch = idx >> 5, d = idx & 31;
        float acc = 0.0f;
#pragma unroll
        for (int k = 0; k < OC; ++k)
            acc = fmaf(We[d * OC + k], Wg[(OC + k) * OC + ch], acc);
        WfT[idx] = f2bf(acc);
    } else if (idx < 2 * ED * OC) {
        int i2 = idx - ED * OC;
        int ch = i2 >> 5, d = i2 & 31;
        WeT[i2] = f2bf(We[d * OC + ch]);
    } else if (idx < 2 * ED * OC + OC) {
        int j = idx - 2 * ED * OC;
        float acc = 0.0f;
#pragma unroll
        for (int k = 0; k < OC; ++k)
            acc = fmaf(be[k], Wg[(OC + k) * OC + j], acc);
        hb[j] = acc;
    } else if (idx < 2 * ED * OC + OC + 2 * INC * OC) {
        int i3 = idx - (2 * ED * OC + OC);
        int ch = i3 >> 7, k = i3 & 127;
        float v = (ch < OC) ? Wl[k * OC + ch] : Wr[k * OC + (ch - OC)];
        WlrT[i3] = f2bf(v);
    }
}

// K1: MFMA GEMM [yl | xwr](bf16) = x @ [Wl | Wr], hist fused (fire-and-forget).
extern "C" __global__ void __launch_bounds__(256)
k_xw(const float* __restrict__ x, const unsigned short* __restrict__ WlrT,
     unsigned short* __restrict__ ybf, unsigned short* __restrict__ xwrbf,
     const int* __restrict__ colv, int* __restrict__ cnti) {
    int t = threadIdx.x;
    {
        int eb = (blockIdx.x * 256 + t) * 4;
        if (eb + 3 < NE) {
            int4 cv = *reinterpret_cast<const int4*>(colv + eb);
            int c0 = min(max(cv.x, 0), NN - 1);
            int c1 = min(max(cv.y, 0), NN - 1);
            int c2 = min(max(cv.z, 0), NN - 1);
            int c3 = min(max(cv.w, 0), NN - 1);
            atomicAdd(&cnti[c0], 1);
            atomicAdd(&cnti[c1], 1);
            atomicAdd(&cnti[c2], 1);
            atomicAdd(&cnti[c3], 1);
        }
    }

    __shared__ unsigned short xs[64][136];
    int base = blockIdx.x * 64;
    {
        int rr = t >> 2, cc = (t & 3) * 32;
        int grow = base + rr;
        if (grow < NN) {
            const float4* xp = reinterpret_cast<const float4*>(
                x + (size_t)grow * INC + cc);
#pragma unroll
            for (int q = 0; q < 8; ++q) {
                float4 v = xp[q];
                uint2 uv;
                uv.x = cvtpk(v.x, v.y);
                uv.y = cvtpk(v.z, v.w);
                *reinterpret_cast<uint2*>(&xs[rr][cc + q * 4]) = uv;
            }
        } else {
#pragma unroll
            for (int q = 0; q < 8; ++q) {
                uint2 uv; uv.x = 0u; uv.y = 0u;
                *reinterpret_cast<uint2*>(&xs[rr][cc + q * 4]) = uv;
            }
        }
    }
    __syncthreads();

    int lane = t & 63, w = t >> 6;
    int c = lane & 15, g = lane >> 4;

    bf16x8 bw0[4], bw1[4];
#pragma unroll
    for (int kk = 0; kk < 4; ++kk) {
        bw0[kk] = *reinterpret_cast<const bf16x8*>(
            WlrT + (w * 32 + 0 * 16 + c) * INC + kk * 32 + g * 8);
        bw1[kk] = *reinterpret_cast<const bf16x8*>(
            WlrT + (w * 32 + 1 * 16 + c) * INC + kk * 32 + g * 8);
    }

    f32x4 acc[4][2];
#pragma unroll
    for (int mt = 0; mt < 4; ++mt)
#pragma unroll
        for (int nt = 0; nt < 2; ++nt)
            acc[mt][nt] = (f32x4){0.0f, 0.0f, 0.0f, 0.0f};

#pragma unroll
    for (int kk = 0; kk < 4; ++kk) {
        bf16x8 a0 = *reinterpret_cast<const bf16x8*>(&xs[0 * 16 + c][kk * 32 + g * 8]);
        bf16x8 a1 = *reinterpret_cast<const bf16x8*>(&xs[1 * 16 + c][kk * 32 + g * 8]);
        bf16x8 a2 = *reinterpret_cast<const bf16x8*>(&xs[2 * 16 + c][kk * 32 + g * 8]);
        bf16x8 a3 = *reinterpret_cast<const bf16x8*>(&xs[3 * 16 + c][kk * 32 + g * 8]);
        acc[0][0] = __builtin_amdgcn_mfma_f32_16x16x32_bf16(a0, bw0[kk], acc[0][0], 0, 0, 0);
        acc[0][1] = __builtin_amdgcn_mfma_f32_16x16x32_bf16(a0, bw1[kk], acc[0][1], 0, 0, 0);
        acc[1][0] = __builtin_amdgcn_mfma_f32_16x16x32_bf16(a1, bw0[kk], acc[1][0], 0, 0, 0);
        acc[1][1] = __builtin_amdgcn_mfma_f32_16x16x32_bf16(a1, bw1[kk], acc[1][1], 0, 0, 0);
        acc[2][0] = __builtin_amdgcn_mfma_f32_16x16x32_bf16(a2, bw0[kk], acc[2][0], 0, 0, 0);
        acc[2][1] = __builtin_amdgcn_mfma_f32_16x16x32_bf16(a2, bw1[kk], acc[2][1], 0, 0, 0);
        acc[3][0] = __builtin_amdgcn_mfma_f32_16x16x32_bf16(a3, bw0[kk], acc[3][0], 0, 0, 0);
        acc[3][1] = __builtin_amdgcn_mfma_f32_16x16x32_bf16(a3, bw1[kk], acc[3][1], 0, 0, 0);
    }

#pragma unroll
    for (int mt = 0; mt < 4; ++mt) {
#pragma unroll
        for (int nt = 0; nt < 2; ++nt) {
            int ch = w * 32 + nt * 16 + c;
#pragma unroll
            for (int j = 0; j < 4; ++j) {
                int row = base + mt * 16 + g * 4 + j;
                if (row < NN) {
                    unsigned short vb = f2bf(acc[mt][nt][j]);
                    if (ch < OC) ybf[(size_t)row * OC + ch] = vb;
                    else         xwrbf[(size_t)row * OC + (ch - OC)] = vb;
                }
            }
        }
    }
}

extern "C" __global__ void __launch_bounds__(1024)
k_scanA(const int* __restrict__ cnti, int* __restrict__ cur,
        int* __restrict__ bsum) {
    __shared__ int s[1024];
    int t = threadIdx.x;
    int idx = blockIdx.x * 1024 + t;
    int v = (idx < NN) ? cnti[idx] : 0;
    s[t] = v;
    __syncthreads();
#pragma unroll
    for (int off = 1; off < 1024; off <<= 1) {
        int tmp = (t >= off) ? s[t - off] : 0;
        __syncthreads();
        s[t] += tmp;
        __syncthreads();
    }
    if (idx < NN) cur[idx] = s[t] - v;
    if (t == 1023) bsum[blockIdx.x] = s[1023];
}

extern "C" __global__ void __launch_bounds__(128)
k_scanB(int* __restrict__ bsum) {
    __shared__ int s[128];
    int t = threadIdx.x;
    int v = (t < 98) ? bsum[t] : 0;
    s[t] = v;
    __syncthreads();
#pragma unroll
    for (int off = 1; off < 128; off <<= 1) {
        int tmp = (t >= off) ? s[t - off] : 0;
        __syncthreads();
        s[t] += tmp;
        __syncthreads();
    }
    if (t < 98) bsum[t] = s[t] - v;
}

extern "C" __global__ void __launch_bounds__(1024)
k_scanC(int* __restrict__ cur, const int* __restrict__ bsum) {
    int idx = blockIdx.x * 1024 + threadIdx.x;
    if (idx < NN) cur[idx] += bsum[blockIdx.x];
}

// coarse-bucket cursors: gcur256[t] = START of coarse bucket t (nodes
// [t*512, (t+1)*512)). cur[i] is the exclusive prefix (= start of node i)
// at this point, so the bucket start is cur[t*512]  (R13 bug: used
// cur[t*512-1], overlapping regions -> garbage ecp -> OOB crash).
extern "C" __global__ void __launch_bounds__(256)
k_init256(const int* __restrict__ cur, int* __restrict__ gcur256) {
    int t = threadIdx.x;
    int nb = t * 512;
    gcur256[t] = (nb < NN) ? cur[nb] : NE;
}

// Bucket pass A: bin 2048 edges/block by coarse digit cl>>9 via LDS ranks;
// per-digit global reservation -> contiguous 8B entries per digit per block.
extern "C" __global__ void __launch_bounds__(256)
k_coarse(const int* __restrict__ colv, const int* __restrict__ rowv,
         int* __restrict__ gcur256, unsigned long long* __restrict__ ecp) {
    __shared__ int lh[256];
    __shared__ int sbase[256];
    int t = threadIdx.x;
    lh[t] = 0;
    __syncthreads();
    int e0 = blockIdx.x * 2048 + t * 8;
    int cls[8], rws[8];
    if (e0 + 7 < NE) {
        int4 a = *reinterpret_cast<const int4*>(colv + e0);
        int4 b = *reinterpret_cast<const int4*>(colv + e0 + 4);
        int4 ra = *reinterpret_cast<const int4*>(rowv + e0);
        int4 rb = *reinterpret_cast<const int4*>(rowv + e0 + 4);
        cls[0] = a.x; cls[1] = a.y; cls[2] = a.z; cls[3] = a.w;
        cls[4] = b.x; cls[5] = b.y; cls[6] = b.z; cls[7] = b.w;
        rws[0] = ra.x; rws[1] = ra.y; rws[2] = ra.z; rws[3] = ra.w;
        rws[4] = rb.x; rws[5] = rb.y; rws[6] = rb.z; rws[7] = rb.w;
    } else {
#pragma unroll
        for (int j = 0; j < 8; ++j) {
            cls[j] = (e0 + j < NE) ? colv[e0 + j] : 0;
            rws[j] = (e0 + j < NE) ? rowv[e0 + j] : 0;
        }
    }
    int d[8];
#pragma unroll
    for (int j = 0; j < 8; ++j) {
        if (e0 + j < NE) {
            cls[j] = min(max(cls[j], 0), NN - 1);
            rws[j] = min(max(rws[j], 0), NN - 1);
            d[j] = cls[j] >> 9;
            atomicAdd(&lh[d[j]], 1);
        } else {
            d[j] = -1;
        }
    }
    __syncthreads();
    int cnt = lh[t];
    if (cnt) sbase[t] = atomicAdd(&gcur256[t], cnt);
    __syncthreads();
    lh[t] = 0;
    __syncthreads();
#pragma unroll
    for (int j = 0; j < 8; ++j) {
        if (d[j] >= 0) {
            int r = atomicAdd(&lh[d[j]], 1);
            ecp[sbase[d[j]] + r] = pack_ec(rws[j], cls[j], e0 + j);
        }
    }
}

// Bucket pass B: fine placement within L2-resident coarse regions.
extern "C" __global__ void __launch_bounds__(256)
k_fine(const unsigned long long* __restrict__ ecp, int* __restrict__ cur,
       unsigned long long* __restrict__ ec) {
    int p = blockIdx.x * 256 + threadIdx.x;
    if (p >= NE) return;
    unsigned long long v = ecp[p];
    int cl = (int)((v >> 30) & 0x1FFFFULL);
    cl = min(cl, NN - 1);  // defensive
    int pos = atomicAdd(&cur[cl], 1);
    ec[pos] = v;
}

// Single-pass bucket (fallback when ws too small for ecp/contrib).
extern "C" __global__ void __launch_bounds__(256)
k_bucket(const int* __restrict__ colv, const int* __restrict__ rowv,
         int* __restrict__ cur, unsigned long long* __restrict__ ec) {
    int e = blockIdx.x * 256 + threadIdx.x;
    if (e >= NE) return;
    int cl = colv[e];
    cl = min(max(cl, 0), NN - 1);
    int r = rowv[e];
    r = min(max(r, 0), NN - 1);
    int pos = atomicAdd(&cur[cl], 1);
    ec[pos] = pack_ec(r, cl, e);
}

// K2: FUSED agg + out_pre + h projection.
extern "C" __global__ void __launch_bounds__(256)
k_aggoh(const unsigned long long* __restrict__ ec, const int* __restrict__ cur,
        const unsigned short* __restrict__ ybf, unsigned short* xwr_h,
        const float* __restrict__ bl, const float* __restrict__ Wg,
        const float* __restrict__ bg, const float* __restrict__ hb,
        float* __restrict__ agg) {
    __shared__ float ol[4][64];
    int w = threadIdx.x >> 6, c = threadIdx.x & 63;
    int i = blockIdx.x * 4 + w;
    if (i >= NN) return;
    int start = (i == 0) ? 0 : cur[i - 1];
    int end = cur[i];
    float xwr = bf2f(xwr_h[(size_t)i * OC + c]);  // read before any write
    float acc = 0.0f;
    int p = start;
    for (; p + 7 < end; p += 8) {
        int r0 = (int)(ec[p + 0] >> 47);
        int r1 = (int)(ec[p + 1] >> 47);
        int r2 = (int)(ec[p + 2] >> 47);
        int r3 = (int)(ec[p + 3] >> 47);
        int r4 = (int)(ec[p + 4] >> 47);
        int r5 = (int)(ec[p + 5] >> 47);
        int r6 = (int)(ec[p + 6] >> 47);
        int r7 = (int)(ec[p + 7] >> 47);
        unsigned short u0 = ybf[(size_t)r0 * OC + c];
        unsigned short u1 = ybf[(size_t)r1 * OC + c];
        unsigned short u2 = ybf[(size_t)r2 * OC + c];
        unsigned short u3 = ybf[(size_t)r3 * OC + c];
        unsigned short u4 = ybf[(size_t)r4 * OC + c];
        unsigned short u5 = ybf[(size_t)r5 * OC + c];
        unsigned short u6 = ybf[(size_t)r6 * OC + c];
        unsigned short u7 = ybf[(size_t)r7 * OC + c];
        acc += bf2f(u0); acc += bf2f(u1); acc += bf2f(u2); acc += bf2f(u3);
        acc += bf2f(u4); acc += bf2f(u5); acc += bf2f(u6); acc += bf2f(u7);
    }
    for (; p < end; ++p) {
        int r0 = (int)(ec[p] >> 47);
        acc += bf2f(ybf[(size_t)r0 * OC + c]);
    }
    float inv = 1.0f / fmaxf((float)(end - start), 1.0f);
    float o = fmaf(acc, inv, bl[c] + xwr);
    agg[(size_t)i * OC + c] = o;
    ol[w][c] = o;
    __builtin_amdgcn_wave_barrier();
    float h0 = bg[c] + hb[c];
    float h1 = 0.0f, h2 = 0.0f, h3 = 0.0f;
#pragma unroll
    for (int k = 0; k < OC; k += 4) {
        float o0 = ol[w][k + 0], o1 = ol[w][k + 1];
        float o2 = ol[w][k + 2], o3 = ol[w][k + 3];
        h0 = fmaf(o0, Wg[(k + 0) * OC + c], h0);
        h1 = fmaf(o1, Wg[(k + 1) * OC + c], h1);
        h2 = fmaf(o2, Wg[(k + 2) * OC + c], h2);
        h3 = fmaf(o3, Wg[(k + 3) * OC + c], h3);
    }
    float h = (h0 + h1) + (h2 + h3);
    xwr_h[(size_t)i * OC + (c & 15) * 4 + (c >> 4)] = f2bf(h);
}

// K4-NS: MFMA gating, NO atomics.
extern "C" __global__ void __launch_bounds__(256, 3)
k_gate_ns(const unsigned long long* __restrict__ ec, const float* __restrict__ eattr,
          const unsigned short* __restrict__ WfT, const unsigned short* __restrict__ WeT,
          const float* __restrict__ be, const unsigned short* __restrict__ hswz,
          unsigned short* __restrict__ contrib) {
    int lane = threadIdx.x & 63;
    int w = threadIdx.x >> 6;
    int tb = (blockIdx.x * 4 + w) * 64;

    unsigned long long ev = ec[tb + lane];
    int e = (int)(ev & 0x3FFFFFFFULL);
    int cl = (int)((ev >> 30) & 0x1FFFFULL);
    int c = lane & 15, g = lane >> 4;

    int erow0 = __shfl(e, 0 * 16 + c);
    int erow1 = __shfl(e, 1 * 16 + c);
    int erow2 = __shfl(e, 2 * 16 + c);
    int erow3 = __shfl(e, 3 * 16 + c);
    int clx[16];
#pragma unroll
    for (int mt = 0; mt < 4; ++mt)
#pragma unroll
        for (int r = 0; r < 4; ++r)
            clx[mt * 4 + r] = __shfl(cl, mt * 16 + g * 4 + r);

    uint2 hg[16];
#pragma unroll
    for (int q = 0; q < 16; ++q)
        hg[q] = *reinterpret_cast<const uint2*>(hswz + (size_t)clx[q] * OC + c * 4);

    bf16x8 bwf[4], bwe[4];
    float bev[4];
#pragma unroll
    for (int nt = 0; nt < 4; ++nt) {
        int ch = nt * 16 + c;
        bwf[nt] = *reinterpret_cast<const bf16x8*>(WfT + ch * ED + g * 8);
        bwe[nt] = *reinterpret_cast<const bf16x8*>(WeT + ch * ED + g * 8);
        bev[nt] = be[ch];
    }

    float4 alo0 = reinterpret_cast<const float4*>(eattr + (size_t)erow0 * ED + g * 8)[0];
    float4 ahi0 = reinterpret_cast<const float4*>(eattr + (size_t)erow0 * ED + g * 8)[1];
    float4 alo1 = reinterpret_cast<const float4*>(eattr + (size_t)erow1 * ED + g * 8)[0];
    float4 ahi1 = reinterpret_cast<const float4*>(eattr + (size_t)erow1 * ED + g * 8)[1];
    float4 alo2 = reinterpret_cast<const float4*>(eattr + (size_t)erow2 * ED + g * 8)[0];
    float4 ahi2 = reinterpret_cast<const float4*>(eattr + (size_t)erow2 * ED + g * 8)[1];
    float4 alo3 = reinterpret_cast<const float4*>(eattr + (size_t)erow3 * ED + g * 8)[0];
    float4 ahi3 = reinterpret_cast<const float4*>(eattr + (size_t)erow3 * ED + g * 8)[1];

    bf16x8 afr[4];
    {
        union { bf16x8 v; unsigned d[4]; } pk;
#define PACKA(idx, lo, hi)                         \
        pk.d[0] = cvtpk(lo.x, lo.y);               \
        pk.d[1] = cvtpk(lo.z, lo.w);               \
        pk.d[2] = cvtpk(hi.x, hi.y);               \
        pk.d[3] = cvtpk(hi.z, hi.w);               \
        afr[idx] = pk.v;
        PACKA(0, alo0, ahi0)
        PACKA(1, alo1, ahi1)
        PACKA(2, alo2, ahi2)
        PACKA(3, alo3, ahi3)
#undef PACKA
    }

#pragma unroll
    for (int mt = 0; mt < 4; ++mt) {
        uint2 h0 = hg[mt * 4 + 0];
        uint2 h1 = hg[mt * 4 + 1];
        uint2 h2 = hg[mt * 4 + 2];
        uint2 h3 = hg[mt * 4 + 3];
        float sv[4][4];
#pragma unroll
        for (int nt = 0; nt < 4; ++nt) {
            f32x4 cz, ce;
            unsigned w0 = (nt < 2) ? h0.x : h0.y;
            unsigned w1 = (nt < 2) ? h1.x : h1.y;
            unsigned w2 = (nt < 2) ? h2.x : h2.y;
            unsigned w3 = (nt < 2) ? h3.x : h3.y;
            cz[0] = bf2f((unsigned short)((nt & 1) ? (w0 >> 16) : (w0 & 0xffffu)));
            cz[1] = bf2f((unsigned short)((nt & 1) ? (w1 >> 16) : (w1 & 0xffffu)));
            cz[2] = bf2f((unsigned short)((nt & 1) ? (w2 >> 16) : (w2 & 0xffffu)));
            cz[3] = bf2f((unsigned short)((nt & 1) ? (w3 >> 16) : (w3 & 0xffffu)));
            ce[0] = bev[nt]; ce[1] = bev[nt]; ce[2] = bev[nt]; ce[3] = bev[nt];
            f32x4 z  = __builtin_amdgcn_mfma_f32_16x16x32_bf16(afr[mt], bwf[nt], cz, 0, 0, 0);
            f32x4 ea = __builtin_amdgcn_mfma_f32_16x16x32_bf16(afr[mt], bwe[nt], ce, 0, 0, 0);
            sv[nt][0] = sigmoidf_(z[0]) * ea[0];
            sv[nt][1] = sigmoidf_(z[1]) * ea[1];
            sv[nt][2] = sigmoidf_(z[2]) * ea[2];
            sv[nt][3] = sigmoidf_(z[3]) * ea[3];
        }
#pragma unroll
        for (int r = 0; r < 4; ++r) {
            int row = tb + mt * 16 + g * 4 + r;
            uint2 pk;
            pk.x = cvtpk(sv[0][r], sv[1][r]);
            pk.y = cvtpk(sv[2][r], sv[3][r]);
            *reinterpret_cast<uint2*>(contrib + (size_t)row * OC + c * 4) = pk;
        }
    }
}

// K4-AT: atomic fallback.
extern "C" __global__ void __launch_bounds__(256, 3)
k_gate_at(const unsigned long long* __restrict__ ec, const float* __restrict__ eattr,
          const unsigned short* __restrict__ WfT, const unsigned short* __restrict__ WeT,
          const float* __restrict__ be, const unsigned short* __restrict__ hswz,
          float* __restrict__ agg) {
    int lane = threadIdx.x & 63;
    int w = threadIdx.x >> 6;
    int tb = (blockIdx.x * 4 + w) * 64;

    unsigned long long ev = ec[tb + lane];
    int e = (int)(ev & 0x3FFFFFFFULL);
    int cl = (int)((ev >> 30) & 0x1FFFFULL);
    int c = lane & 15, g = lane >> 4;

    int erow0 = __shfl(e, 0 * 16 + c);
    int erow1 = __shfl(e, 1 * 16 + c);
    int erow2 = __shfl(e, 2 * 16 + c);
    int erow3 = __shfl(e, 3 * 16 + c);
    int clx[16];
#pragma unroll
    for (int mt = 0; mt < 4; ++mt)
#pragma unroll
        for (int r = 0; r < 4; ++r)
            clx[mt * 4 + r] = __shfl(cl, mt * 16 + g * 4 + r);

    uint2 hg[16];
#pragma unroll
    for (int q = 0; q < 16; ++q)
        hg[q] = *reinterpret_cast<const uint2*>(hswz + (size_t)clx[q] * OC + c * 4);

    bf16x8 bwf[4], bwe[4];
    float bev[4];
#pragma unroll
    for (int nt = 0; nt < 4; ++nt) {
        int ch = nt * 16 + c;
        bwf[nt] = *reinterpret_cast<const bf16x8*>(WfT + ch * ED + g * 8);
        bwe[nt] = *reinterpret_cast<const bf16x8*>(WeT + ch * ED + g * 8);
        bev[nt] = be[ch];
    }

    float4 alo0 = reinterpret_cast<const float4*>(eattr + (size_t)erow0 * ED + g * 8)[0];
    float4 ahi0 = reinterpret_cast<const float4*>(eattr + (size_t)erow0 * ED + g * 8)[1];
    float4 alo1 = reinterpret_cast<const float4*>(eattr + (size_t)erow1 * ED + g * 8)[0];
    float4 ahi1 = reinterpret_cast<const float4*>(eattr + (size_t)erow1 * ED + g * 8)[1];
    float4 alo2 = reinterpret_cast<const float4*>(eattr + (size_t)erow2 * ED + g * 8)[0];
    float4 ahi2 = reinterpret_cast<const float4*>(eattr + (size_t)erow2 * ED + g * 8)[1];
    float4 alo3 = reinterpret_cast<const float4*>(eattr + (size_t)erow3 * ED + g * 8)[0];
    float4 ahi3 = reinterpret_cast<const float4*>(eattr + (size_t)erow3 * ED + g * 8)[1];

    bf16x8 afr[4];
    {
        union { bf16x8 v; unsigned d[4]; } pk;
#define PACKA(idx, lo, hi)                         \
        pk.d[0] = cvtpk(lo.x, lo.y);               \
        pk.d[1] = cvtpk(lo.z, lo.w);               \
        pk.d[2] = cvtpk(hi.x, hi.y);               \
        pk.d[3] = cvtpk(hi.z, hi.w);               \
        afr[idx] = pk.v;
        PACKA(0, alo0, ahi0)
        PACKA(1, alo1, ahi1)
        PACKA(2, alo2, ahi2)
        PACKA(3, alo3, ahi3)
#undef PACKA
    }

#pragma unroll
    for (int mt = 0; mt < 4; ++mt) {
        int cl0 = clx[mt * 4 + 0];
        int cl1 = clx[mt * 4 + 1];
        int cl2 = clx[mt * 4 + 2];
        int cl3 = clx[mt * 4 + 3];
        uint2 h0 = hg[mt * 4 + 0];
        uint2 h1 = hg[mt * 4 + 1];
        uint2 h2 = hg[mt * 4 + 2];
        uint2 h3 = hg[mt * 4 + 3];
#pragma unroll
        for (int nt = 0; nt < 4; ++nt) {
            int ch = nt * 16 + c;
            f32x4 cz, ce;
            unsigned w0 = (nt < 2) ? h0.x : h0.y;
            unsigned w1 = (nt < 2) ? h1.x : h1.y;
            unsigned w2 = (nt < 2) ? h2.x : h2.y;
            unsigned w3 = (nt < 2) ? h3.x : h3.y;
            cz[0] = bf2f((unsigned short)((nt & 1) ? (w0 >> 16) : (w0 & 0xffffu)));
            cz[1] = bf2f((unsigned short)((nt & 1) ? (w1 >> 16) : (w1 & 0xffffu)));
            cz[2] = bf2f((unsigned short)((nt & 1) ? (w2 >> 16) : (w2 & 0xffffu)));
            cz[3] = bf2f((unsigned short)((nt & 1) ? (w3 >> 16) : (w3 & 0xffffu)));
            ce[0] = bev[nt]; ce[1] = bev[nt]; ce[2] = bev[nt]; ce[3] = bev[nt];
            f32x4 z  = __builtin_amdgcn_mfma_f32_16x16x32_bf16(afr[mt], bwf[nt], cz, 0, 0, 0);
            f32x4 ea = __builtin_amdgcn_mfma_f32_16x16x32_bf16(afr[mt], bwe[nt], ce, 0, 0, 0);
            float c0 = sigmoidf_(z[0]) * ea[0];
            float c1 = sigmoidf_(z[1]) * ea[1];
            float c2 = sigmoidf_(z[2]) * ea[2];
            float c3 = sigmoidf_(z[3]) * ea[3];
            float s = c0;
            int t = cl0;
            if (cl1 != t) { atomicAdd(&agg[(size_t)t * OC + ch], s); s = 0.0f; t = cl1; }
            s += c1;
            if (cl2 != t) { atomicAdd(&agg[(size_t)t * OC + ch], s); s = 0.0f; t = cl2; }
            s += c2;
            if (cl3 != t) { atomicAdd(&agg[(size_t)t * OC + ch], s); s = 0.0f; t = cl3; }
            s += c3;
            atomicAdd(&agg[(size_t)t * OC + ch], s);
        }
    }
}

// K4b (NS): segmented sum of contrib + fused BN stats.
extern "C" __global__ void __launch_bounds__(256)
k_csumst(const unsigned short* __restrict__ contrib, const int* __restrict__ cur,
         float* __restrict__ agg, float* __restrict__ stats) {
    __shared__ float ls[256], lq[256];
    int w = threadIdx.x >> 6, c = threadIdx.x & 63;
    int ch = (c >> 2) + 16 * (c & 3);
    float sv = 0.0f, sq = 0.0f;
    for (int i = blockIdx.x * 4 + w; i < NN; i += 2048 * 4) {
        int start = (i == 0) ? 0 : cur[i - 1];
        int end = cur[i];
        float s = 0.0f;
        int p = start;
        for (; p + 7 < end; p += 8) {
            unsigned short u0 = contrib[(size_t)(p + 0) * OC + c];
            unsigned short u1 = contrib[(size_t)(p + 1) * OC + c];
            unsigned short u2 = contrib[(size_t)(p + 2) * OC + c];
            unsigned short u3 = contrib[(size_t)(p + 3) * OC + c];
            unsigned short u4 = contrib[(size_t)(p + 4) * OC + c];
            unsigned short u5 = contrib[(size_t)(p + 5) * OC + c];
            unsigned short u6 = contrib[(size_t)(p + 6) * OC + c];
            unsigned short u7 = contrib[(size_t)(p + 7) * OC + c];
            s += bf2f(u0); s += bf2f(u1); s += bf2f(u2); s += bf2f(u3);
            s += bf2f(u4); s += bf2f(u5); s += bf2f(u6); s += bf2f(u7);
        }
        for (; p < end; ++p) s += bf2f(contrib[(size_t)p * OC + c]);
        float v = agg[(size_t)i * OC + ch] + s;
        agg[(size_t)i * OC + ch] = v;
        sv += v;
        sq = fmaf(v, v, sq);
    }
    ls[threadIdx.x] = sv;
    lq[threadIdx.x] = sq;
    __syncthreads();
    if (threadIdx.x < 64) {
        float a = ls[c] + ls[c + 64] + ls[c + 128] + ls[c + 192];
        float b = lq[c] + lq[c + 64] + lq[c + 128] + lq[c + 192];
        atomicAdd(&stats[ch], a);
        atomicAdd(&stats[OC + ch], b);
    }
}

// K5: BN batch stats (AT path only).
extern "C" __global__ void __launch_bounds__(256)
k_stats(const float* __restrict__ a, float* __restrict__ stats) {
    __shared__ float ls[256], lq[256];
    int t = threadIdx.x;
    float s = 0.0f, q = 0.0f;
    for (size_t idx = (size_t)blockIdx.x * 256 + t; idx < (size_t)NN * OC;
         idx += (size_t)gridDim.x * 256) {
        float v = a[idx];
        s += v;
        q = fmaf(v, v, q);
    }
    ls[t] = s; lq[t] = q;
    __syncthreads();
    if (t < OC) {
        s = ls[t] + ls[t + 64] + ls[t + 128] + ls[t + 192];
        q = lq[t] + lq[t + 64] + lq[t + 128] + lq[t + 192];
        atomicAdd(&stats[t], s);
        atomicAdd(&stats[OC + t], q);
    }
}

// K6: BN normalize + residual(2x) + ReLU.
extern "C" __global__ void __launch_bounds__(256)
k_final(const float* __restrict__ a, const float* __restrict__ stats,
        const float* __restrict__ gamma, const float* __restrict__ beta,
        float* __restrict__ out) {
    size_t idx = (size_t)blockIdx.x * 256 + threadIdx.x;
    if (idx >= (size_t)NN * OC) return;
    int c = (int)(idx & 63);
    float mu = stats[c] * (1.0f / NN);
    float var = stats[OC + c] * (1.0f / NN) - mu * mu;
    float v = a[idx];
    float y = fmaf(gamma[c] * (v - mu), rsqrtf(var + 1e-5f), beta[c]);
    out[idx] = fmaxf(2.0f * y, 0.0f);
}

extern "C" void kernel_launch(void* const* d_in, const int* in_sizes, int n_in,
                              void* d_out, int out_size, void* d_ws, size_t ws_size,
                              hipStream_t stream) {
    const float* x     = (const float*)d_in[0];
    const int*   ei    = (const int*)d_in[1];   // (2, NE) int32
    const float* eattr = (const float*)d_in[2];
    const float* Wl    = (const float*)d_in[3];
    const float* bl    = (const float*)d_in[4];
    const float* Wr    = (const float*)d_in[5];
    const float* We    = (const float*)d_in[6];
    const float* be    = (const float*)d_in[7];
    const float* Wg    = (const float*)d_in[8];
    const float* bg    = (const float*)d_in[9];
    const float* gamma = (const float*)d_in[10];
    const float* beta  = (const float*)d_in[11];
    float* out = (float*)d_out;

    float* agg = (float*)d_ws;
    unsigned short* ybf   = (unsigned short*)(agg + (size_t)NN * OC);
    unsigned short* xwrbf = ybf + (size_t)NN * OC;   // becomes hswz after k_aggoh
    unsigned long long* ec = (unsigned long long*)(xwrbf + (size_t)NN * OC);
    int* cur   = (int*)(ec + (size_t)NE);
    int* bsum  = cur + NN;
    float* stats = (float*)(bsum + 128);
    unsigned short* WfT  = (unsigned short*)(stats + 128);
    unsigned short* WeT  = WfT + ED * OC;
    unsigned short* WlrT = WeT + ED * OC;
    float* hb = (float*)(WlrT + 2 * INC * OC);
    int* gcur256 = (int*)(hb + OC);
    unsigned short* contrib = (unsigned short*)(gcur256 + 256);
    // ecp aliases the (dead-until-k_gate_ns) contrib region, 8B-aligned
    unsigned long long* ecp =
        (unsigned long long*)(((size_t)contrib + 7) & ~(size_t)7);
    unsigned short* hswz = xwrbf;

    size_t base_bytes = (size_t)((char*)contrib - (char*)d_ws);
    bool ns = ws_size >= base_bytes + 8 + (size_t)NE * OC * sizeof(unsigned short);

    const int* rowv = ei;
    const int* colv = ei + NE;

    hipMemsetAsync(cur, 0, NN * sizeof(int), stream);
    hipMemsetAsync(stats, 0, 2 * OC * sizeof(float), stream);

    k_wfuse<<<(2 * ED * OC + OC + 2 * INC * OC + 255) / 256, 256, 0, stream>>>(
        We, be, Wg, Wl, Wr, WfT, WeT, hb, WlrT);
    k_xw<<<(NN + 63) / 64, 256, 0, stream>>>(x, WlrT, ybf, xwrbf, colv, cur);
    k_scanA<<<98, 1024, 0, stream>>>(cur, cur, bsum);
    k_scanB<<<1, 128, 0, stream>>>(bsum);
    k_scanC<<<98, 1024, 0, stream>>>(cur, bsum);
    if (ns) {
        k_init256<<<1, 256, 0, stream>>>(cur, gcur256);
        k_coarse<<<(NE + 2047) / 2048, 256, 0, stream>>>(colv, rowv, gcur256, ecp);
        k_fine<<<(NE + 255) / 256, 256, 0, stream>>>(ecp, cur, ec);
    } else {
        k_bucket<<<(NE + 255) / 256, 256, 0, stream>>>(colv, rowv, cur, ec);
    }
    k_aggoh<<<(NN + 3) / 4, 256, 0, stream>>>(ec, cur, ybf, xwrbf, bl, Wg, bg, hb, agg);
    if (ns) {
        k_gate_ns<<<NE / 256, 256, 0, stream>>>(ec, eattr, WfT, WeT, be, hswz, contrib);
        k_csumst<<<2048, 256, 0, stream>>>(contrib, cur, agg, stats);
    } else {
        k_gate_at<<<NE / 256, 256, 0, stream>>>(ec, eattr, WfT, WeT, be, hswz, agg);
        k_stats<<<2048, 256, 0, stream>>>(agg, stats);
    }
    k_final<<<((size_t)NN * OC + 255) / 256, 256, 0, stream>>>(agg, stats, gamma, beta, out);
}